// Round 3
// baseline (6000.484 us; speedup 1.0000x reference)
//
#include <hip/hip_runtime.h>
#include <math.h>

#define Bb 2
#define Tt 2048
#define Cc 2048
#define Hh 16
#define CONVD 6144
#define Mrows 4096  // B*T

// ---- f32 tiled GEMM: C(MxN) = A(MxK) @ B(KxN), row-major w/ explicit ld ----
// 64x64 tile, BK=16, 256 threads, 4x4 per thread.
__global__ __launch_bounds__(256) void gemm_f32(
    const float* __restrict__ A, const float* __restrict__ Bm,
    float* __restrict__ Cm, int Nn, int Kk, int lda, int ldb, int ldc)
{
    __shared__ float As[16][68];
    __shared__ float Bs[16][68];
    const int block_m = blockIdx.y * 64;
    const int block_n = blockIdx.x * 64;
    const int tid = threadIdx.x;
    const int tx = tid & 15;       // n-dir micro tile
    const int ty = tid >> 4;       // m-dir micro tile
    const int arow = tid >> 2;           // 0..63
    const int ak4  = (tid & 3) * 4;      // 0,4,8,12
    const int brow = tid >> 4;           // 0..15
    const int bn4  = (tid & 15) * 4;     // 0..60

    float acc[4][4];
#pragma unroll
    for (int i = 0; i < 4; ++i)
#pragma unroll
        for (int j = 0; j < 4; ++j) acc[i][j] = 0.f;

    for (int k0 = 0; k0 < Kk; k0 += 16) {
        float4 a4 = *(const float4*)(A + (size_t)(block_m + arow) * lda + k0 + ak4);
        float4 b4 = *(const float4*)(Bm + (size_t)(k0 + brow) * ldb + block_n + bn4);
        As[ak4 + 0][arow] = a4.x;
        As[ak4 + 1][arow] = a4.y;
        As[ak4 + 2][arow] = a4.z;
        As[ak4 + 3][arow] = a4.w;
        *(float4*)(&Bs[brow][bn4]) = b4;
        __syncthreads();
#pragma unroll
        for (int kk = 0; kk < 16; ++kk) {
            float4 av = *(const float4*)(&As[kk][ty * 4]);
            float4 bv = *(const float4*)(&Bs[kk][tx * 4]);
            float am[4] = {av.x, av.y, av.z, av.w};
            float bm[4] = {bv.x, bv.y, bv.z, bv.w};
#pragma unroll
            for (int i = 0; i < 4; ++i)
#pragma unroll
                for (int j = 0; j < 4; ++j)
                    acc[i][j] = fmaf(am[i], bm[j], acc[i][j]);
        }
        __syncthreads();
    }
#pragma unroll
    for (int i = 0; i < 4; ++i) {
        float4 o;
        o.x = acc[i][0]; o.y = acc[i][1]; o.z = acc[i][2]; o.w = acc[i][3];
        *(float4*)(Cm + (size_t)(block_m + ty * 4 + i) * ldc + block_n + tx * 4) = o;
    }
}

// ---------------- alpha/beta: sigmoid(x @ W_{a,b}), W is (2048,16) ----------
__global__ __launch_bounds__(256) void ab_kernel(
    const float* __restrict__ x, const float* __restrict__ W_b,
    const float* __restrict__ W_a, float* __restrict__ beta,
    float* __restrict__ alpha)
{
    const int row = blockIdx.x;     // 0..4095
    const int tid = threadIdx.x;    // 256
    float acc[32];
#pragma unroll
    for (int u = 0; u < 32; ++u) acc[u] = 0.f;

    for (int k = tid; k < Cc; k += 256) {
        float xv = x[(size_t)row * Cc + k];
        const float4* wb = (const float4*)(W_b + (size_t)k * 16);
        const float4* wa = (const float4*)(W_a + (size_t)k * 16);
#pragma unroll
        for (int u = 0; u < 4; ++u) {
            float4 b4 = wb[u];
            float4 a4 = wa[u];
            acc[u * 4 + 0] = fmaf(xv, b4.x, acc[u * 4 + 0]);
            acc[u * 4 + 1] = fmaf(xv, b4.y, acc[u * 4 + 1]);
            acc[u * 4 + 2] = fmaf(xv, b4.z, acc[u * 4 + 2]);
            acc[u * 4 + 3] = fmaf(xv, b4.w, acc[u * 4 + 3]);
            acc[16 + u * 4 + 0] = fmaf(xv, a4.x, acc[16 + u * 4 + 0]);
            acc[16 + u * 4 + 1] = fmaf(xv, a4.y, acc[16 + u * 4 + 1]);
            acc[16 + u * 4 + 2] = fmaf(xv, a4.z, acc[16 + u * 4 + 2]);
            acc[16 + u * 4 + 3] = fmaf(xv, a4.w, acc[16 + u * 4 + 3]);
        }
    }
#pragma unroll
    for (int u = 0; u < 32; ++u) {
        float v = acc[u];
        for (int off = 32; off > 0; off >>= 1) v += __shfl_down(v, off);
        acc[u] = v;
    }
    __shared__ float red[4][32];
    const int wv = tid >> 6;
    if ((tid & 63) == 0) {
#pragma unroll
        for (int u = 0; u < 32; ++u) red[wv][u] = acc[u];
    }
    __syncthreads();
    if (tid < 32) {
        float v = red[0][tid] + red[1][tid] + red[2][tid] + red[3][tid];
        float s = 1.f / (1.f + expf(-v));
        if (tid < 16) beta[(size_t)row * 16 + tid] = s;
        else          alpha[(size_t)row * 16 + (tid - 16)] = s;
    }
}

// ---------------- conv(K=4) + SiLU + split + l2norm(q,k) -------------------
// qkv is (4096 x 6144) row-major.
__global__ __launch_bounds__(128) void conv_kernel(
    const float* __restrict__ qkv, const float* __restrict__ conv_w,
    const float* __restrict__ conv_state, const int* __restrict__ input_pos,
    float* __restrict__ qn, float* __restrict__ kn, float* __restrict__ vv)
{
    const int gb = blockIdx.x;        // B*T*48
    const int hs = gb % 48;
    const int bt = gb / 48;
    const int t = bt % Tt;
    const int b = bt / Tt;
    const int lane = threadIdx.x;     // 0..127
    const int kind = hs >> 4;         // 0=q,1=k,2=v
    const int h = hs & 15;
    const int c = kind * 2048 + h * 128 + lane;
    const float keep = (input_pos[0] == 0) ? 0.f : 1.f;

    float acc = 0.f;
#pragma unroll
    for (int j = 0; j < 4; ++j) {
        int tau = t - 3 + j;
        float xv;
        if (tau >= 0) xv = qkv[((size_t)(b * Tt + tau)) * CONVD + c];
        else          xv = keep * conv_state[((size_t)b * CONVD + c) * 4 + (tau + 4)];
        acc = fmaf(conv_w[(size_t)c * 4 + j], xv, acc);
    }
    float y = acc / (1.f + expf(-acc));   // silu
    const size_t oidx = ((size_t)(b * Tt + t)) * 2048 + h * 128 + lane;
    if (kind == 2) { vv[oidx] = y; return; }

    float sq = y * y;
    for (int off = 32; off > 0; off >>= 1) sq += __shfl_down(sq, off);
    __shared__ float red[2];
    if ((lane & 63) == 0) red[lane >> 6] = sq;
    __syncthreads();
    float tot = red[0] + red[1];
    float inv = 1.f / fmaxf(sqrtf(tot), 1e-12f);
    float outv = y * inv;
    if (kind == 0) qn[oidx] = outv;
    else           kn[oidx] = outv;
}

// ---------------- sequential gated linear-attention scan -------------------
// one block per (b,h); 512 threads: j = tid&127 (value col), r = tid>>7 owns
// 32 rows of the 128x128 state in registers. Fused RMSNorm + sigmoid(z) gate.
// zbuf (4096x2048) is read and overwritten IN PLACE with the gated output
// (same thread, same element: read-before-write => race-free).
// All __syncthreads() are UNIFORM across the 8 waves (the round-2 bug was a
// barrier inside `if (tid<128)` which permanently skewed barrier phases).
__global__ __launch_bounds__(512) void scan_kernel(
    const float* __restrict__ qn, const float* __restrict__ kn,
    const float* __restrict__ vv, const float* __restrict__ alpha,
    const float* __restrict__ beta, float* __restrict__ zbuf,
    const float* __restrict__ rec_state, const float* __restrict__ norm_w,
    const int* __restrict__ input_pos)
{
    const int bh = blockIdx.x;   // 0..31
    const int b = bh >> 4;
    const int h = bh & 15;
    const int tid = threadIdx.x;
    const int j = tid & 127;
    const int r = tid >> 7;      // 0..3
    const float keep = (input_pos[0] == 0) ? 0.f : 1.f;

    float S[32];
#pragma unroll
    for (int u = 0; u < 32; ++u) {
        int i = r * 32 + u;
        S[u] = keep * rec_state[(((size_t)(b * Hh + h)) * 128 + i) * 128 + j];
    }

    __shared__ float q_s[128];
    __shared__ float bk_s[128];
    __shared__ float v_s[128];
    __shared__ float partial[4][128];
    __shared__ float red2[2];

    const float nw = norm_w[j];

    for (int t = 0; t < Tt; ++t) {
        const size_t rowbase = ((size_t)(b * Tt + t));
        if (tid < 128) {
            const size_t base = rowbase * 2048 + h * 128 + tid;
            q_s[tid] = qn[base];
            float bval = beta[rowbase * 16 + h];
            bk_s[tid] = bval * kn[base];
            v_s[tid] = vv[base];
        }
        __syncthreads();   // A: tiles ready

        const float a = alpha[rowbase * 16 + h];
        const float vj = v_s[j];
        float p = 0.f;
#pragma unroll
        for (int u = 0; u < 32; ++u) {
            int i = r * 32 + u;
            float t1 = bk_s[i] * vj;
            S[u] = fmaf(a, S[u], t1);
            p = fmaf(q_s[i], S[u], p);
        }
        partial[r][j] = p;
        __syncthreads();   // B: partials ready

        float o = 0.f;
        if (tid < 128) {
            o = partial[0][tid] + partial[1][tid] + partial[2][tid] + partial[3][tid];
            float sq = o * o;
            for (int off = 32; off > 0; off >>= 1) sq += __shfl_down(sq, off);
            if ((tid & 63) == 0) red2[tid >> 6] = sq;
        }
        __syncthreads();   // C: red2 ready (uniform barrier!)

        if (tid < 128) {
            float tot = red2[0] + red2[1];
            float scale = rsqrtf(tot * (1.f / 128.f) + 1e-6f);
            float zv = zbuf[rowbase * 2048 + h * 128 + tid];
            float g = o * scale * nw * (1.f / (1.f + expf(-zv)));
            zbuf[rowbase * 2048 + h * 128 + tid] = g;
        }
        // no barrier D needed: next iteration's LDS writes (by waves 0-1,
        // after they pass C) are ordered after every wave's reads (before B),
        // and red2 is next written only after next iteration's A and B.
    }
}

extern "C" void kernel_launch(void* const* d_in, const int* in_sizes, int n_in,
                              void* d_out, int out_size, void* d_ws, size_t ws_size,
                              hipStream_t stream) {
    (void)in_sizes; (void)n_in; (void)out_size; (void)ws_size;
    const float* x          = (const float*)d_in[0];
    const int*   input_pos  = (const int*)d_in[1];
    const float* W_qkvz     = (const float*)d_in[2];
    const float* W_b        = (const float*)d_in[3];
    const float* W_a        = (const float*)d_in[4];
    const float* conv_w     = (const float*)d_in[5];
    const float* norm_w     = (const float*)d_in[6];
    const float* W_out      = (const float*)d_in[7];
    const float* conv_state = (const float*)d_in[8];
    const float* rec_state  = (const float*)d_in[9];
    float* out = (float*)d_out;
    float* ws  = (float*)d_ws;

    // workspace layout (float elements) — total 58,851,328 f = 224.5 MiB
    float* qkv   = ws;                        // 4096*6144 = 25,165,824
    float* qn    = ws + 25165824ull;          // 4096*2048 =  8,388,608
    float* kn    = qn + 8388608ull;
    float* vv    = kn + 8388608ull;
    float* zbuf  = vv + 8388608ull;           // z in, gated out (in place)
    float* alpha = zbuf + 8388608ull;         // 4096*16
    float* beta  = alpha + 65536ull;

    // 1a. qkv = x @ W_qkvz[:, :6144]
    gemm_f32<<<dim3(CONVD / 64, Mrows / 64), 256, 0, stream>>>(
        x, W_qkvz, qkv, CONVD, Cc, Cc, 8192, CONVD);
    // 1b. z = x @ W_qkvz[:, 6144:]
    gemm_f32<<<dim3(2048 / 64, Mrows / 64), 256, 0, stream>>>(
        x, W_qkvz + 6144, zbuf, 2048, Cc, Cc, 8192, 2048);
    // 2. alpha/beta
    ab_kernel<<<Mrows, 256, 0, stream>>>(x, W_b, W_a, beta, alpha);
    // 3. conv + silu + l2norm
    conv_kernel<<<Bb * Tt * 48, 128, 0, stream>>>(
        qkv, conv_w, conv_state, input_pos, qn, kn, vv);
    // 4. recurrent scan + RMSNorm + gate (zbuf -> gated in place)
    scan_kernel<<<32, 512, 0, stream>>>(
        qn, kn, vv, alpha, beta, zbuf, rec_state, norm_w, input_pos);
    // 5. out = gated @ W_out
    gemm_f32<<<dim3(Cc / 64, Mrows / 64), 256, 0, stream>>>(
        zbuf, W_out, out, Cc, Cc, Cc, Cc, Cc);
}

// Round 4
// 2603.151 us; speedup vs baseline: 2.3051x; 2.3051x over previous
//
#include <hip/hip_runtime.h>
#include <math.h>

#define Bb 2
#define Tt 2048
#define Cc 2048
#define Hh 16
#define CONVD 6144
#define Mrows 4096  // B*T
#define NCHUNK 32   // T / 64

// ---- f32 tiled GEMM: C(MxN) = A(MxK) @ B(KxN), row-major w/ explicit ld ----
__global__ __launch_bounds__(256) void gemm_f32(
    const float* __restrict__ A, const float* __restrict__ Bm,
    float* __restrict__ Cm, int Nn, int Kk, int lda, int ldb, int ldc)
{
    __shared__ float As[16][68];
    __shared__ float Bs[16][68];
    const int block_m = blockIdx.y * 64;
    const int block_n = blockIdx.x * 64;
    const int tid = threadIdx.x;
    const int tx = tid & 15;
    const int ty = tid >> 4;
    const int arow = tid >> 2;
    const int ak4  = (tid & 3) * 4;
    const int brow = tid >> 4;
    const int bn4  = (tid & 15) * 4;

    float acc[4][4];
#pragma unroll
    for (int i = 0; i < 4; ++i)
#pragma unroll
        for (int j = 0; j < 4; ++j) acc[i][j] = 0.f;

    for (int k0 = 0; k0 < Kk; k0 += 16) {
        float4 a4 = *(const float4*)(A + (size_t)(block_m + arow) * lda + k0 + ak4);
        float4 b4 = *(const float4*)(Bm + (size_t)(k0 + brow) * ldb + block_n + bn4);
        As[ak4 + 0][arow] = a4.x;
        As[ak4 + 1][arow] = a4.y;
        As[ak4 + 2][arow] = a4.z;
        As[ak4 + 3][arow] = a4.w;
        *(float4*)(&Bs[brow][bn4]) = b4;
        __syncthreads();
#pragma unroll
        for (int kk = 0; kk < 16; ++kk) {
            float4 av = *(const float4*)(&As[kk][ty * 4]);
            float4 bv = *(const float4*)(&Bs[kk][tx * 4]);
            float am[4] = {av.x, av.y, av.z, av.w};
            float bm[4] = {bv.x, bv.y, bv.z, bv.w};
#pragma unroll
            for (int i = 0; i < 4; ++i)
#pragma unroll
                for (int j = 0; j < 4; ++j)
                    acc[i][j] = fmaf(am[i], bm[j], acc[i][j]);
        }
        __syncthreads();
    }
#pragma unroll
    for (int i = 0; i < 4; ++i) {
        float4 o;
        o.x = acc[i][0]; o.y = acc[i][1]; o.z = acc[i][2]; o.w = acc[i][3];
        *(float4*)(Cm + (size_t)(block_m + ty * 4 + i) * ldc + block_n + tx * 4) = o;
    }
}

// ---------------- alpha/beta: sigmoid(x @ W_{a,b}), W is (2048,16) ----------
__global__ __launch_bounds__(256) void ab_kernel(
    const float* __restrict__ x, const float* __restrict__ W_b,
    const float* __restrict__ W_a, float* __restrict__ beta,
    float* __restrict__ alpha)
{
    const int row = blockIdx.x;
    const int tid = threadIdx.x;
    float acc[32];
#pragma unroll
    for (int u = 0; u < 32; ++u) acc[u] = 0.f;

    for (int k = tid; k < Cc; k += 256) {
        float xv = x[(size_t)row * Cc + k];
        const float4* wb = (const float4*)(W_b + (size_t)k * 16);
        const float4* wa = (const float4*)(W_a + (size_t)k * 16);
#pragma unroll
        for (int u = 0; u < 4; ++u) {
            float4 b4 = wb[u];
            float4 a4 = wa[u];
            acc[u * 4 + 0] = fmaf(xv, b4.x, acc[u * 4 + 0]);
            acc[u * 4 + 1] = fmaf(xv, b4.y, acc[u * 4 + 1]);
            acc[u * 4 + 2] = fmaf(xv, b4.z, acc[u * 4 + 2]);
            acc[u * 4 + 3] = fmaf(xv, b4.w, acc[u * 4 + 3]);
            acc[16 + u * 4 + 0] = fmaf(xv, a4.x, acc[16 + u * 4 + 0]);
            acc[16 + u * 4 + 1] = fmaf(xv, a4.y, acc[16 + u * 4 + 1]);
            acc[16 + u * 4 + 2] = fmaf(xv, a4.z, acc[16 + u * 4 + 2]);
            acc[16 + u * 4 + 3] = fmaf(xv, a4.w, acc[16 + u * 4 + 3]);
        }
    }
#pragma unroll
    for (int u = 0; u < 32; ++u) {
        float v = acc[u];
        for (int off = 32; off > 0; off >>= 1) v += __shfl_down(v, off);
        acc[u] = v;
    }
    __shared__ float red[4][32];
    const int wv = tid >> 6;
    if ((tid & 63) == 0) {
#pragma unroll
        for (int u = 0; u < 32; ++u) red[wv][u] = acc[u];
    }
    __syncthreads();
    if (tid < 32) {
        float v = red[0][tid] + red[1][tid] + red[2][tid] + red[3][tid];
        float s = 1.f / (1.f + expf(-v));
        if (tid < 16) beta[(size_t)row * 16 + tid] = s;
        else          alpha[(size_t)row * 16 + (tid - 16)] = s;
    }
}

// ---------------- conv(K=4) + SiLU + split + l2norm(q,k) -------------------
__global__ __launch_bounds__(128) void conv_kernel(
    const float* __restrict__ qkv, const float* __restrict__ conv_w,
    const float* __restrict__ conv_state, const int* __restrict__ input_pos,
    float* __restrict__ qn, float* __restrict__ kn, float* __restrict__ vv)
{
    const int gb = blockIdx.x;
    const int hs = gb % 48;
    const int bt = gb / 48;
    const int t = bt % Tt;
    const int b = bt / Tt;
    const int lane = threadIdx.x;
    const int kind = hs >> 4;
    const int h = hs & 15;
    const int c = kind * 2048 + h * 128 + lane;
    const float keep = (input_pos[0] == 0) ? 0.f : 1.f;

    float acc = 0.f;
#pragma unroll
    for (int j = 0; j < 4; ++j) {
        int tau = t - 3 + j;
        float xv;
        if (tau >= 0) xv = qkv[((size_t)(b * Tt + tau)) * CONVD + c];
        else          xv = keep * conv_state[((size_t)b * CONVD + c) * 4 + (tau + 4)];
        acc = fmaf(conv_w[(size_t)c * 4 + j], xv, acc);
    }
    float y = acc / (1.f + expf(-acc));
    const size_t oidx = ((size_t)(b * Tt + t)) * 2048 + h * 128 + lane;
    if (kind == 2) { vv[oidx] = y; return; }

    float sq = y * y;
    for (int off = 32; off > 0; off >>= 1) sq += __shfl_down(sq, off);
    __shared__ float red[2];
    if ((lane & 63) == 0) red[lane >> 6] = sq;
    __syncthreads();
    float tot = red[0] + red[1];
    float inv = 1.f / fmaxf(sqrtf(tot), 1e-12f);
    float outv = y * inv;
    if (kind == 0) qn[oidx] = outv;
    else           kn[oidx] = outv;
}

// ================= chunked scan, stage A: per-chunk prep =====================
// grid (c,h,b), 256 threads. Computes within-chunk inclusive log-cumsum of a
// (logc_g) and chunk matrix M_c = sum_s exp(lc63-lc_s) * b_s * k_s v_s^T.
__global__ __launch_bounds__(256) void chunk_prep(
    const float* __restrict__ kn, const float* __restrict__ vv,
    const float* __restrict__ alpha, const float* __restrict__ beta,
    float* __restrict__ logc_g, float* __restrict__ Mbuf)
{
    const int c = blockIdx.x, h = blockIdx.y, b = blockIdx.z;
    const int tid = threadIdx.x;
    const size_t bh = (size_t)b * Hh + h;

    __shared__ float K_lds[32][128];
    __shared__ float V_lds[32][128];
    __shared__ float logc_lds[64];
    __shared__ float b_lds[64];
    __shared__ float wk_lds[64];

    if (tid < 64) {
        const int row = b * Tt + c * 64 + tid;
        float a = alpha[(size_t)row * 16 + h];
        float la = logf(a);
#pragma unroll
        for (int d = 1; d < 64; d <<= 1) {
            float n = __shfl_up(la, d);
            if (tid >= d) la += n;
        }
        logc_lds[tid] = la;
        logc_g[bh * Tt + c * 64 + tid] = la;
        b_lds[tid] = beta[(size_t)row * 16 + h];
    }
    __syncthreads();
    if (tid < 64) {
        wk_lds[tid] = expf(logc_lds[63] - logc_lds[tid]) * b_lds[tid];
    }
    __syncthreads();

    const int ti = tid >> 4;   // 0..15 (i block of 8)
    const int tj = tid & 15;   // 0..15 (j block of 8)
    float acc[8][8];
#pragma unroll
    for (int i = 0; i < 8; ++i)
#pragma unroll
        for (int j = 0; j < 8; ++j) acc[i][j] = 0.f;

    for (int half = 0; half < 2; ++half) {
        // coop load K,V rows half*32..+31 (each thread 16 floats of each)
        {
            const int sl = tid >> 3;               // 0..31
            const int c0 = (tid & 7) * 16;         // 0..112
            const int grow = b * Tt + c * 64 + half * 32 + sl;
            const float4* kp = (const float4*)(kn + (size_t)grow * 2048 + h * 128 + c0);
            const float4* vp = (const float4*)(vv + (size_t)grow * 2048 + h * 128 + c0);
            float4* kl = (float4*)(&K_lds[sl][c0]);
            float4* vl = (float4*)(&V_lds[sl][c0]);
#pragma unroll
            for (int u = 0; u < 4; ++u) { kl[u] = kp[u]; vl[u] = vp[u]; }
        }
        __syncthreads();
#pragma unroll 4
        for (int s = 0; s < 32; ++s) {
            float w = wk_lds[half * 32 + s];
            float4 k0 = *(const float4*)(&K_lds[s][ti * 8]);
            float4 k1 = *(const float4*)(&K_lds[s][ti * 8 + 4]);
            float4 v0 = *(const float4*)(&V_lds[s][tj * 8]);
            float4 v1 = *(const float4*)(&V_lds[s][tj * 8 + 4]);
            float wk[8] = {w*k0.x, w*k0.y, w*k0.z, w*k0.w, w*k1.x, w*k1.y, w*k1.z, w*k1.w};
            float vf[8] = {v0.x, v0.y, v0.z, v0.w, v1.x, v1.y, v1.z, v1.w};
#pragma unroll
            for (int i = 0; i < 8; ++i)
#pragma unroll
                for (int j = 0; j < 8; ++j)
                    acc[i][j] = fmaf(wk[i], vf[j], acc[i][j]);
        }
        __syncthreads();
    }
    float* mb = Mbuf + ((bh * NCHUNK) + c) * 16384;
#pragma unroll
    for (int i = 0; i < 8; ++i) {
        float4 o0 = {acc[i][0], acc[i][1], acc[i][2], acc[i][3]};
        float4 o1 = {acc[i][4], acc[i][5], acc[i][6], acc[i][7]};
        *(float4*)(mb + (size_t)(ti * 8 + i) * 128 + tj * 8) = o0;
        *(float4*)(mb + (size_t)(ti * 8 + i) * 128 + tj * 8 + 4) = o1;
    }
}

// ================= chunked scan, stage B: state recurrence ==================
// grid 32 (b,h), 512 threads. In place over Mbuf: reads M_c, writes S_c
// (state at START of chunk c), S <- exp(lc63_c)*S + M_c.
__global__ __launch_bounds__(512) void state_scan(
    float* __restrict__ Mbuf, const float* __restrict__ logc_g,
    const float* __restrict__ rec_state, const int* __restrict__ input_pos)
{
    const int bh = blockIdx.x;
    const int tid = threadIdx.x;
    const int j = tid & 127;
    const int r = tid >> 7;
    const float keep = (input_pos[0] == 0) ? 0.f : 1.f;

    float S[32];
#pragma unroll
    for (int u = 0; u < 32; ++u) {
        int i = r * 32 + u;
        S[u] = keep * rec_state[(((size_t)bh) * 128 + i) * 128 + j];
    }

    for (int c = 0; c < NCHUNK; ++c) {
        float Atot = expf(logc_g[(size_t)bh * Tt + c * 64 + 63]);
        float* base = Mbuf + ((size_t)bh * NCHUNK + c) * 16384 + j;
#pragma unroll
        for (int u = 0; u < 32; ++u) {
            float* p = base + (size_t)(r * 32 + u) * 128;
            float m = *p;
            *p = S[u];
            S[u] = fmaf(Atot, S[u], m);
        }
    }
}

// ================= chunked scan, stage C: per-chunk output ==================
// grid (c,h,b), 256 threads: quad per row t (seg owns 32 cols).
// o_t = exp(lc_t) * q_t @ S_c  +  sum_{s<=t} exp(lc_t-lc_s) b_s (q_t.k_s) v_s
// fused RMSNorm + norm_w + sigmoid(z) gate; zbuf updated in place.
__global__ __launch_bounds__(256) void chunk_out(
    const float* __restrict__ qn, const float* __restrict__ kn,
    const float* __restrict__ vv, const float* __restrict__ beta,
    const float* __restrict__ logc_g, const float* __restrict__ Sstates,
    const float* __restrict__ norm_w, float* __restrict__ zbuf)
{
    const int c = blockIdx.x, h = blockIdx.y, b = blockIdx.z;
    const int tid = threadIdx.x;
    const int t = tid >> 2;        // 0..63
    const int seg = tid & 3;       // 32-col segment
    const int lane = tid & 63;
    const size_t bh = (size_t)b * Hh + h;
    const int grow = b * Tt + c * 64 + t;

    __shared__ float KV_lds[64][128];     // K, then reused for V
    __shared__ float Attn_lds[64][65];
    __shared__ float Srow_lds[16][128];
    __shared__ float logc_lds[64];
    __shared__ float b_lds[64];

    // q fragment: q[t][seg*32 .. +31]
    float q[32];
    {
        const float4* qp = (const float4*)(qn + (size_t)grow * 2048 + h * 128 + seg * 32);
#pragma unroll
        for (int u = 0; u < 8; ++u) {
            float4 f = qp[u];
            q[u*4] = f.x; q[u*4+1] = f.y; q[u*4+2] = f.z; q[u*4+3] = f.w;
        }
    }
    if (tid < 64) {
        logc_lds[tid] = logc_g[bh * Tt + c * 64 + tid];
        b_lds[tid] = beta[(size_t)(b * Tt + c * 64 + tid) * 16 + h];
    }
    // coop load K (row t, seg cols)
    {
        const float4* kp = (const float4*)(kn + (size_t)grow * 2048 + h * 128 + seg * 32);
        float4* kl = (float4*)(&KV_lds[t][seg * 32]);
#pragma unroll
        for (int u = 0; u < 8; ++u) kl[u] = kp[u];
    }
    __syncthreads();

    const float lct = logc_lds[t];

    // Attn[t][s] = (s<=t) ? exp(lct-lcs)*b_s*(q_t.k_s) : 0
    for (int s = 0; s < 64; ++s) {
        const float* kr = &KV_lds[s][seg * 32];
        float d = 0.f;
#pragma unroll
        for (int u = 0; u < 32; ++u) d = fmaf(q[u], kr[u], d);
        d += __shfl_xor(d, 1);
        d += __shfl_xor(d, 2);
        float w = (s <= t) ? expf(lct - logc_lds[s]) * b_lds[s] : 0.f;
        if (seg == (s & 3)) Attn_lds[t][s] = w * d;
    }
    __syncthreads();
    // load V over K slot
    {
        const float4* vp = (const float4*)(vv + (size_t)grow * 2048 + h * 128 + seg * 32);
        float4* vl = (float4*)(&KV_lds[t][seg * 32]);
#pragma unroll
        for (int u = 0; u < 8; ++u) vl[u] = vp[u];
    }

    // inter-chunk: o = q_t @ S_c (scaled by exp(lct) afterwards)
    float o[32];
#pragma unroll
    for (int u = 0; u < 32; ++u) o[u] = 0.f;
    const float* Sbase = Sstates + (bh * NCHUNK + c) * 16384;
#pragma unroll
    for (int ib = 0; ib < 8; ++ib) {
        {
            const int rr = tid >> 4;           // 0..15
            const int col = (tid & 15) * 8;
            const float4* sp = (const float4*)(Sbase + (size_t)(ib * 16 + rr) * 128 + col);
            float4* sl = (float4*)(&Srow_lds[rr][col]);
            sl[0] = sp[0]; sl[1] = sp[1];
        }
        __syncthreads();
#pragma unroll
        for (int ii = 0; ii < 16; ++ii) {
            const int i = ib * 16 + ii;        // compile-time (both loops unrolled)
            float qv = __shfl(q[i & 31], (lane & ~3) | (i >> 5));
            const float* sr = &Srow_lds[ii][seg * 32];
#pragma unroll
            for (int u = 0; u < 32; ++u) o[u] = fmaf(qv, sr[u], o[u]);
        }
        __syncthreads();
    }
    const float ct = expf(lct);
#pragma unroll
    for (int u = 0; u < 32; ++u) o[u] *= ct;

    // intra-chunk: o += Attn[t][:] @ V  (V already in LDS, barrier above covers it)
    for (int s = 0; s < 64; ++s) {
        float a_ts = Attn_lds[t][s];
        const float* vr = &KV_lds[s][seg * 32];
#pragma unroll
        for (int u = 0; u < 32; ++u) o[u] = fmaf(a_ts, vr[u], o[u]);
    }

    // epilogue: RMSNorm over the 128-row (quad reduce) + gate, in-place zbuf
    float ss = 0.f;
#pragma unroll
    for (int u = 0; u < 32; ++u) ss = fmaf(o[u], o[u], ss);
    ss += __shfl_xor(ss, 1);
    ss += __shfl_xor(ss, 2);
    const float scale = rsqrtf(ss * (1.f / 128.f) + 1e-6f);
    float* zp = zbuf + (size_t)grow * 2048 + h * 128 + seg * 32;
#pragma unroll
    for (int u = 0; u < 32; ++u) {
        float zv = zp[u];
        float g = o[u] * scale * norm_w[seg * 32 + u] * (1.f / (1.f + expf(-zv)));
        zp[u] = g;
    }
}

extern "C" void kernel_launch(void* const* d_in, const int* in_sizes, int n_in,
                              void* d_out, int out_size, void* d_ws, size_t ws_size,
                              hipStream_t stream) {
    (void)in_sizes; (void)n_in; (void)out_size; (void)ws_size;
    const float* x          = (const float*)d_in[0];
    const int*   input_pos  = (const int*)d_in[1];
    const float* W_qkvz     = (const float*)d_in[2];
    const float* W_b        = (const float*)d_in[3];
    const float* W_a        = (const float*)d_in[4];
    const float* conv_w     = (const float*)d_in[5];
    const float* norm_w     = (const float*)d_in[6];
    const float* W_out      = (const float*)d_in[7];
    const float* conv_state = (const float*)d_in[8];
    const float* rec_state  = (const float*)d_in[9];
    float* out = (float*)d_out;
    float* ws  = (float*)d_ws;

    // workspace layout (float elements) — total 58,916,864 f = 224.75 MiB
    float* qkv   = ws;                        // 4096*6144 (freed after conv)
    float* Mbuf  = ws;                        // aliases qkv: 32bh*32c*16384 = 64 MiB
    float* qn    = ws + 25165824ull;          // 4096*2048
    float* kn    = qn + 8388608ull;
    float* vv    = kn + 8388608ull;
    float* zbuf  = vv + 8388608ull;           // z in, gated out (in place)
    float* alpha = zbuf + 8388608ull;         // 4096*16
    float* beta  = alpha + 65536ull;
    float* logc  = beta + 65536ull;           // 2*16*2048

    // 1a. qkv = x @ W_qkvz[:, :6144]
    gemm_f32<<<dim3(CONVD / 64, Mrows / 64), 256, 0, stream>>>(
        x, W_qkvz, qkv, CONVD, Cc, Cc, 8192, CONVD);
    // 1b. z = x @ W_qkvz[:, 6144:]
    gemm_f32<<<dim3(2048 / 64, Mrows / 64), 256, 0, stream>>>(
        x, W_qkvz + 6144, zbuf, 2048, Cc, Cc, 8192, 2048);
    // 2. alpha/beta
    ab_kernel<<<Mrows, 256, 0, stream>>>(x, W_b, W_a, beta, alpha);
    // 3. conv + silu + l2norm (reads qkv — last use of that buffer)
    conv_kernel<<<Bb * Tt * 48, 128, 0, stream>>>(
        qkv, conv_w, conv_state, input_pos, qn, kn, vv);
    // 4a. per-chunk prep: log-cumsum + M_c  (overwrites qkv region)
    chunk_prep<<<dim3(NCHUNK, Hh, Bb), 256, 0, stream>>>(
        kn, vv, alpha, beta, logc, Mbuf);
    // 4b. sequential chunk-state recurrence (Mbuf -> Sstates in place)
    state_scan<<<Bb * Hh, 512, 0, stream>>>(Mbuf, logc, rec_state, input_pos);
    // 4c. per-chunk outputs + RMSNorm + gate (zbuf in place)
    chunk_out<<<dim3(NCHUNK, Hh, Bb), 256, 0, stream>>>(
        qn, kn, vv, beta, logc, Mbuf, norm_w, zbuf);
    // 5. out = gated @ W_out
    gemm_f32<<<dim3(Cc / 64, Mrows / 64), 256, 0, stream>>>(
        zbuf, W_out, out, Cc, Cc, Cc, Cc, Cc);
}

// Round 5
// 816.273 us; speedup vs baseline: 7.3511x; 3.1891x over previous
//
#include <hip/hip_runtime.h>
#include <hip/hip_bf16.h>
#include <math.h>

#define Bb 2
#define Tt 2048
#define Cc 2048
#define Hh 16
#define CONVD 6144
#define Mrows 4096  // B*T
#define NCHUNK 32   // T / 64

typedef __attribute__((ext_vector_type(8))) short short8v;
typedef __attribute__((ext_vector_type(4))) float floatx4;

__device__ __forceinline__ unsigned short f2bf(float f) {
    __hip_bfloat16 h = __float2bfloat16(f);
    return __builtin_bit_cast(unsigned short, h);
}

__device__ __forceinline__ void load_lds16(const void* g, void* l) {
    __builtin_amdgcn_global_load_lds(
        (const __attribute__((address_space(1))) void*)g,
        (__attribute__((address_space(3))) void*)l, 16, 0, 0);
}

// ---------------- cast f32 -> bf16, 4 elems/thread --------------------------
__global__ __launch_bounds__(256) void cast_bf16(
    const float* __restrict__ in, unsigned short* __restrict__ out, long n)
{
    long i = ((long)blockIdx.x * 256 + threadIdx.x) * 4;
    if (i + 3 >= n) return;
    float4 f = *(const float4*)(in + i);
    ushort4 o;
    o.x = f2bf(f.x); o.y = f2bf(f.y); o.z = f2bf(f.z); o.w = f2bf(f.w);
    *(ushort4*)(out + i) = o;
}

// ---------------- transpose + cast: W (KxN f32) -> WT (NxK bf16) ------------
__global__ __launch_bounds__(256) void transpose_cast(
    const float* __restrict__ W, unsigned short* __restrict__ WT, int Kk, int Nn)
{
    __shared__ float tile[32][33];
    const int n0 = blockIdx.x * 32;
    const int k0 = blockIdx.y * 32;
    const int tx = threadIdx.x & 31;
    const int ty = threadIdx.x >> 5;   // 0..7
#pragma unroll
    for (int r = ty; r < 32; r += 8)
        tile[r][tx] = W[(size_t)(k0 + r) * Nn + n0 + tx];
    __syncthreads();
#pragma unroll
    for (int r = ty; r < 32; r += 8)
        WT[(size_t)(n0 + r) * Kk + k0 + tx] = f2bf(tile[tx][r]);
}

// ---- bf16 MFMA GEMM: C(MxN f32) = A(MxK bf16) @ Bt(NxK bf16)^T -------------
// 128x128 tile, BK=32, 256 threads (4 waves, 2x2), 16x16x32 MFMA.
// LDS layout [kb][row][8]: (kb,row,j) = A[row][k0+kb*8+j]; staged with
// global_load_lds width 16 (lane i -> row base+ i), conflict-free b128 reads.
__global__ __launch_bounds__(256) void gemm_bf16(
    const unsigned short* __restrict__ A, const unsigned short* __restrict__ Bt,
    float* __restrict__ C, int Kk, int lda, int ldb, int ldc)
{
    __shared__ __align__(16) unsigned short A_lds[4][128][8];
    __shared__ __align__(16) unsigned short B_lds[4][128][8];

    const int tid = threadIdx.x;
    const int wv = tid >> 6;             // wave 0..3
    const int lane = tid & 63;
    const int wr = wv >> 1, wc = wv & 1; // 2x2 wave grid
    const int l15 = lane & 15, kq = lane >> 4;
    const int block_m = blockIdx.y * 128;
    const int block_n = blockIdx.x * 128;

    floatx4 acc[4][4] = {};

    for (int k0 = 0; k0 < Kk; k0 += 32) {
        // stage: wave wv covers kb=wv, halves p=0,1 for both A and B
#pragma unroll
        for (int p = 0; p < 2; ++p) {
            const unsigned short* asrc =
                A + (size_t)(block_m + p * 64 + lane) * lda + k0 + wv * 8;
            load_lds16(asrc, &A_lds[wv][p * 64][0]);
            const unsigned short* bsrc =
                Bt + (size_t)(block_n + p * 64 + lane) * ldb + k0 + wv * 8;
            load_lds16(bsrc, &B_lds[wv][p * 64][0]);
        }
        __syncthreads();

        short8v af[4], bf[4];
#pragma unroll
        for (int mf = 0; mf < 4; ++mf)
            af[mf] = *(const short8v*)&A_lds[kq][wr * 64 + mf * 16 + l15][0];
#pragma unroll
        for (int nf = 0; nf < 4; ++nf)
            bf[nf] = *(const short8v*)&B_lds[kq][wc * 64 + nf * 16 + l15][0];
#pragma unroll
        for (int mf = 0; mf < 4; ++mf)
#pragma unroll
            for (int nf = 0; nf < 4; ++nf)
                acc[mf][nf] = __builtin_amdgcn_mfma_f32_16x16x32_bf16(
                    af[mf], bf[nf], acc[mf][nf], 0, 0, 0);
        __syncthreads();
    }

    // epilogue: D row=(lane>>4)*4+reg, col=lane&15 (m89-verified layout)
#pragma unroll
    for (int mf = 0; mf < 4; ++mf)
#pragma unroll
        for (int nf = 0; nf < 4; ++nf)
#pragma unroll
            for (int r = 0; r < 4; ++r) {
                int row = block_m + wr * 64 + mf * 16 + kq * 4 + r;
                int col = block_n + wc * 64 + nf * 16 + l15;
                C[(size_t)row * ldc + col] = acc[mf][nf][r];
            }
}

// ---------------- alpha/beta: sigmoid(x @ W_{a,b}), W is (2048,16) ----------
__global__ __launch_bounds__(256) void ab_kernel(
    const float* __restrict__ x, const float* __restrict__ W_b,
    const float* __restrict__ W_a, float* __restrict__ beta,
    float* __restrict__ alpha)
{
    const int row = blockIdx.x;
    const int tid = threadIdx.x;
    float acc[32];
#pragma unroll
    for (int u = 0; u < 32; ++u) acc[u] = 0.f;

    for (int k = tid; k < Cc; k += 256) {
        float xv = x[(size_t)row * Cc + k];
        const float4* wb = (const float4*)(W_b + (size_t)k * 16);
        const float4* wa = (const float4*)(W_a + (size_t)k * 16);
#pragma unroll
        for (int u = 0; u < 4; ++u) {
            float4 b4 = wb[u];
            float4 a4 = wa[u];
            acc[u * 4 + 0] = fmaf(xv, b4.x, acc[u * 4 + 0]);
            acc[u * 4 + 1] = fmaf(xv, b4.y, acc[u * 4 + 1]);
            acc[u * 4 + 2] = fmaf(xv, b4.z, acc[u * 4 + 2]);
            acc[u * 4 + 3] = fmaf(xv, b4.w, acc[u * 4 + 3]);
            acc[16 + u * 4 + 0] = fmaf(xv, a4.x, acc[16 + u * 4 + 0]);
            acc[16 + u * 4 + 1] = fmaf(xv, a4.y, acc[16 + u * 4 + 1]);
            acc[16 + u * 4 + 2] = fmaf(xv, a4.z, acc[16 + u * 4 + 2]);
            acc[16 + u * 4 + 3] = fmaf(xv, a4.w, acc[16 + u * 4 + 3]);
        }
    }
#pragma unroll
    for (int u = 0; u < 32; ++u) {
        float v = acc[u];
        for (int off = 32; off > 0; off >>= 1) v += __shfl_down(v, off);
        acc[u] = v;
    }
    __shared__ float red[4][32];
    const int wv = tid >> 6;
    if ((tid & 63) == 0) {
#pragma unroll
        for (int u = 0; u < 32; ++u) red[wv][u] = acc[u];
    }
    __syncthreads();
    if (tid < 32) {
        float v = red[0][tid] + red[1][tid] + red[2][tid] + red[3][tid];
        float s = 1.f / (1.f + expf(-v));
        if (tid < 16) beta[(size_t)row * 16 + tid] = s;
        else          alpha[(size_t)row * 16 + (tid - 16)] = s;
    }
}

// ---------------- conv(K=4) + SiLU + split + l2norm(q,k) -------------------
__global__ __launch_bounds__(128) void conv_kernel(
    const float* __restrict__ qkv, const float* __restrict__ conv_w,
    const float* __restrict__ conv_state, const int* __restrict__ input_pos,
    float* __restrict__ qn, float* __restrict__ kn, float* __restrict__ vv)
{
    const int gb = blockIdx.x;
    const int hs = gb % 48;
    const int bt = gb / 48;
    const int t = bt % Tt;
    const int b = bt / Tt;
    const int lane = threadIdx.x;
    const int kind = hs >> 4;
    const int h = hs & 15;
    const int c = kind * 2048 + h * 128 + lane;
    const float keep = (input_pos[0] == 0) ? 0.f : 1.f;

    float acc = 0.f;
#pragma unroll
    for (int j = 0; j < 4; ++j) {
        int tau = t - 3 + j;
        float xv;
        if (tau >= 0) xv = qkv[((size_t)(b * Tt + tau)) * CONVD + c];
        else          xv = keep * conv_state[((size_t)b * CONVD + c) * 4 + (tau + 4)];
        acc = fmaf(conv_w[(size_t)c * 4 + j], xv, acc);
    }
    float y = acc / (1.f + expf(-acc));
    const size_t oidx = ((size_t)(b * Tt + t)) * 2048 + h * 128 + lane;
    if (kind == 2) { vv[oidx] = y; return; }

    float sq = y * y;
    for (int off = 32; off > 0; off >>= 1) sq += __shfl_down(sq, off);
    __shared__ float red[2];
    if ((lane & 63) == 0) red[lane >> 6] = sq;
    __syncthreads();
    float tot = red[0] + red[1];
    float inv = 1.f / fmaxf(sqrtf(tot), 1e-12f);
    float outv = y * inv;
    if (kind == 0) qn[oidx] = outv;
    else           kn[oidx] = outv;
}

// ================= chunked scan, stage A: per-chunk prep =====================
__global__ __launch_bounds__(256) void chunk_prep(
    const float* __restrict__ kn, const float* __restrict__ vv,
    const float* __restrict__ alpha, const float* __restrict__ beta,
    float* __restrict__ logc_g, float* __restrict__ Mbuf)
{
    const int c = blockIdx.x, h = blockIdx.y, b = blockIdx.z;
    const int tid = threadIdx.x;
    const size_t bh = (size_t)b * Hh + h;

    __shared__ float K_lds[32][128];
    __shared__ float V_lds[32][128];
    __shared__ float logc_lds[64];
    __shared__ float b_lds[64];
    __shared__ float wk_lds[64];

    if (tid < 64) {
        const int row = b * Tt + c * 64 + tid;
        float a = alpha[(size_t)row * 16 + h];
        float la = logf(a);
#pragma unroll
        for (int d = 1; d < 64; d <<= 1) {
            float n = __shfl_up(la, d);
            if (tid >= d) la += n;
        }
        logc_lds[tid] = la;
        logc_g[bh * Tt + c * 64 + tid] = la;
        b_lds[tid] = beta[(size_t)row * 16 + h];
    }
    __syncthreads();
    if (tid < 64) {
        wk_lds[tid] = expf(logc_lds[63] - logc_lds[tid]) * b_lds[tid];
    }
    __syncthreads();

    const int ti = tid >> 4;
    const int tj = tid & 15;
    float acc[8][8];
#pragma unroll
    for (int i = 0; i < 8; ++i)
#pragma unroll
        for (int j = 0; j < 8; ++j) acc[i][j] = 0.f;

    for (int half = 0; half < 2; ++half) {
        {
            const int sl = tid >> 3;
            const int c0 = (tid & 7) * 16;
            const int grow = b * Tt + c * 64 + half * 32 + sl;
            const float4* kp = (const float4*)(kn + (size_t)grow * 2048 + h * 128 + c0);
            const float4* vp = (const float4*)(vv + (size_t)grow * 2048 + h * 128 + c0);
            float4* kl = (float4*)(&K_lds[sl][c0]);
            float4* vl = (float4*)(&V_lds[sl][c0]);
#pragma unroll
            for (int u = 0; u < 4; ++u) { kl[u] = kp[u]; vl[u] = vp[u]; }
        }
        __syncthreads();
#pragma unroll 4
        for (int s = 0; s < 32; ++s) {
            float w = wk_lds[half * 32 + s];
            float4 k0 = *(const float4*)(&K_lds[s][ti * 8]);
            float4 k1 = *(const float4*)(&K_lds[s][ti * 8 + 4]);
            float4 v0 = *(const float4*)(&V_lds[s][tj * 8]);
            float4 v1 = *(const float4*)(&V_lds[s][tj * 8 + 4]);
            float wk[8] = {w*k0.x, w*k0.y, w*k0.z, w*k0.w, w*k1.x, w*k1.y, w*k1.z, w*k1.w};
            float vf[8] = {v0.x, v0.y, v0.z, v0.w, v1.x, v1.y, v1.z, v1.w};
#pragma unroll
            for (int i = 0; i < 8; ++i)
#pragma unroll
                for (int j = 0; j < 8; ++j)
                    acc[i][j] = fmaf(wk[i], vf[j], acc[i][j]);
        }
        __syncthreads();
    }
    float* mb = Mbuf + ((bh * NCHUNK) + c) * 16384;
#pragma unroll
    for (int i = 0; i < 8; ++i) {
        float4 o0 = {acc[i][0], acc[i][1], acc[i][2], acc[i][3]};
        float4 o1 = {acc[i][4], acc[i][5], acc[i][6], acc[i][7]};
        *(float4*)(mb + (size_t)(ti * 8 + i) * 128 + tj * 8) = o0;
        *(float4*)(mb + (size_t)(ti * 8 + i) * 128 + tj * 8 + 4) = o1;
    }
}

// ================= chunked scan, stage B: state recurrence ==================
// fully parallel over (bh, i, j): one thread per state element.
__global__ __launch_bounds__(256) void state_scan(
    float* __restrict__ Mbuf, const float* __restrict__ logc_g,
    const float* __restrict__ rec_state, const int* __restrict__ input_pos)
{
    const size_t g = (size_t)blockIdx.x * 256 + threadIdx.x;  // 0..524287
    const int bh = (int)(g >> 14);
    const int ij = (int)(g & 16383);
    const float keep = (input_pos[0] == 0) ? 0.f : 1.f;

    float S = keep * rec_state[g];
    const float* lc = logc_g + (size_t)bh * Tt;
    float* base = Mbuf + (size_t)bh * NCHUNK * 16384 + ij;
#pragma unroll 4
    for (int c = 0; c < NCHUNK; ++c) {
        float Atot = expf(lc[c * 64 + 63]);
        float m = base[(size_t)c * 16384];
        base[(size_t)c * 16384] = S;
        S = fmaf(Atot, S, m);
    }
}

// ================= chunked scan, stage C: per-chunk output ==================
__global__ __launch_bounds__(256) void chunk_out(
    const float* __restrict__ qn, const float* __restrict__ kn,
    const float* __restrict__ vv, const float* __restrict__ beta,
    const float* __restrict__ logc_g, const float* __restrict__ Sstates,
    const float* __restrict__ norm_w, const float* __restrict__ zbuf,
    unsigned short* __restrict__ gated_b)
{
    const int c = blockIdx.x, h = blockIdx.y, b = blockIdx.z;
    const int tid = threadIdx.x;
    const int t = tid >> 2;
    const int seg = tid & 3;
    const int lane = tid & 63;
    const size_t bh = (size_t)b * Hh + h;
    const int grow = b * Tt + c * 64 + t;

    __shared__ float KV_lds[64][128];
    __shared__ float Attn_lds[64][65];
    __shared__ float Srow_lds[16][128];
    __shared__ float logc_lds[64];
    __shared__ float b_lds[64];

    float q[32];
    {
        const float4* qp = (const float4*)(qn + (size_t)grow * 2048 + h * 128 + seg * 32);
#pragma unroll
        for (int u = 0; u < 8; ++u) {
            float4 f = qp[u];
            q[u*4] = f.x; q[u*4+1] = f.y; q[u*4+2] = f.z; q[u*4+3] = f.w;
        }
    }
    if (tid < 64) {
        logc_lds[tid] = logc_g[bh * Tt + c * 64 + tid];
        b_lds[tid] = beta[(size_t)(b * Tt + c * 64 + tid) * 16 + h];
    }
    {
        const float4* kp = (const float4*)(kn + (size_t)grow * 2048 + h * 128 + seg * 32);
        float4* kl = (float4*)(&KV_lds[t][seg * 32]);
#pragma unroll
        for (int u = 0; u < 8; ++u) kl[u] = kp[u];
    }
    __syncthreads();

    const float lct = logc_lds[t];

    for (int s = 0; s < 64; ++s) {
        const float* kr = &KV_lds[s][seg * 32];
        float d = 0.f;
#pragma unroll
        for (int u = 0; u < 32; ++u) d = fmaf(q[u], kr[u], d);
        d += __shfl_xor(d, 1);
        d += __shfl_xor(d, 2);
        float w = (s <= t) ? expf(lct - logc_lds[s]) * b_lds[s] : 0.f;
        if (seg == (s & 3)) Attn_lds[t][s] = w * d;
    }
    __syncthreads();
    {
        const float4* vp = (const float4*)(vv + (size_t)grow * 2048 + h * 128 + seg * 32);
        float4* vl = (float4*)(&KV_lds[t][seg * 32]);
#pragma unroll
        for (int u = 0; u < 8; ++u) vl[u] = vp[u];
    }

    float o[32];
#pragma unroll
    for (int u = 0; u < 32; ++u) o[u] = 0.f;
    const float* Sbase = Sstates + (bh * NCHUNK + c) * 16384;
#pragma unroll
    for (int ib = 0; ib < 8; ++ib) {
        {
            const int rr = tid >> 4;
            const int col = (tid & 15) * 8;
            const float4* sp = (const float4*)(Sbase + (size_t)(ib * 16 + rr) * 128 + col);
            float4* sl = (float4*)(&Srow_lds[rr][col]);
            sl[0] = sp[0]; sl[1] = sp[1];
        }
        __syncthreads();
#pragma unroll
        for (int ii = 0; ii < 16; ++ii) {
            const int i = ib * 16 + ii;
            float qv = __shfl(q[i & 31], (lane & ~3) | (i >> 5));
            const float* sr = &Srow_lds[ii][seg * 32];
#pragma unroll
            for (int u = 0; u < 32; ++u) o[u] = fmaf(qv, sr[u], o[u]);
        }
        __syncthreads();
    }
    const float ct = expf(lct);
#pragma unroll
    for (int u = 0; u < 32; ++u) o[u] *= ct;

    for (int s = 0; s < 64; ++s) {
        float a_ts = Attn_lds[t][s];
        const float* vr = &KV_lds[s][seg * 32];
#pragma unroll
        for (int u = 0; u < 32; ++u) o[u] = fmaf(a_ts, vr[u], o[u]);
    }

    float ss = 0.f;
#pragma unroll
    for (int u = 0; u < 32; ++u) ss = fmaf(o[u], o[u], ss);
    ss += __shfl_xor(ss, 1);
    ss += __shfl_xor(ss, 2);
    const float scale = rsqrtf(ss * (1.f / 128.f) + 1e-6f);
    const float* zp = zbuf + (size_t)grow * 2048 + h * 128 + seg * 32;
    unsigned short* gp = gated_b + (size_t)grow * 2048 + h * 128 + seg * 32;
#pragma unroll
    for (int u = 0; u < 32; ++u) {
        float zv = zp[u];
        float g = o[u] * scale * norm_w[seg * 32 + u] * (1.f / (1.f + expf(-zv)));
        gp[u] = f2bf(g);
    }
}

extern "C" void kernel_launch(void* const* d_in, const int* in_sizes, int n_in,
                              void* d_out, int out_size, void* d_ws, size_t ws_size,
                              hipStream_t stream) {
    (void)in_sizes; (void)n_in; (void)out_size; (void)ws_size;
    const float* x          = (const float*)d_in[0];
    const int*   input_pos  = (const int*)d_in[1];
    const float* W_qkvz     = (const float*)d_in[2];
    const float* W_b        = (const float*)d_in[3];
    const float* W_a        = (const float*)d_in[4];
    const float* conv_w     = (const float*)d_in[5];
    const float* norm_w     = (const float*)d_in[6];
    const float* W_out      = (const float*)d_in[7];
    const float* conv_state = (const float*)d_in[8];
    const float* rec_state  = (const float*)d_in[9];
    float* out = (float*)d_out;
    float* ws  = (float*)d_ws;

    // workspace (float elems), peak 232.75 MiB with phase-based aliasing:
    float* qkv   = ws;                                 // 25,165,824 f (phase 2-3)
    float* Mbuf  = ws;                                 // 16,777,216 f (phase 4+, aliases qkv)
    unsigned short* gated_b = (unsigned short*)(ws + 16777216); // 8,388,608 bf16 (phase 5+)
    float* qn    = ws + 25165824ull;                   // 8,388,608 f (phase 3+)
    float* kn    = qn + 8388608ull;
    float* vv    = kn + 8388608ull;
    unsigned short* xb  = (unsigned short*)qn;         // phase 1-2, aliases qn
    unsigned short* WqT = (unsigned short*)(qn + 4194304ull); // 16,777,216 bf16, phase 1-2
    float* zbuf  = vv + 8388608ull;                    // 8,388,608 f
    unsigned short* WoT = (unsigned short*)(zbuf + 8388608ull); // 4,194,304 bf16
    float* alpha = zbuf + 8388608ull + 2097152ull;     // 65,536 f
    float* beta  = alpha + 65536ull;
    float* logc  = beta + 65536ull;

    // 0. casts / transposes (bf16 operands for MFMA GEMMs)
    cast_bf16<<<8192, 256, 0, stream>>>(x, xb, 8388608L);
    transpose_cast<<<dim3(8192 / 32, 2048 / 32), 256, 0, stream>>>(W_qkvz, WqT, 2048, 8192);
    transpose_cast<<<dim3(2048 / 32, 2048 / 32), 256, 0, stream>>>(W_out, WoT, 2048, 2048);

    // 1a. qkv = x @ W_qkvz[:, :6144]   (MFMA bf16)
    gemm_bf16<<<dim3(CONVD / 128, Mrows / 128), 256, 0, stream>>>(
        xb, WqT, qkv, 2048, 2048, 2048, CONVD);
    // 1b. z = x @ W_qkvz[:, 6144:]
    gemm_bf16<<<dim3(2048 / 128, Mrows / 128), 256, 0, stream>>>(
        xb, WqT + 6144ull * 2048, zbuf, 2048, 2048, 2048, 2048);
    // 2. alpha/beta (f32 — exp-cumsum sensitivity)
    ab_kernel<<<Mrows, 256, 0, stream>>>(x, W_b, W_a, beta, alpha);
    // 3. conv + silu + l2norm
    conv_kernel<<<Bb * Tt * 48, 128, 0, stream>>>(
        qkv, conv_w, conv_state, input_pos, qn, kn, vv);
    // 4a. per-chunk prep: log-cumsum + M_c  (overwrites dead qkv region)
    chunk_prep<<<dim3(NCHUNK, Hh, Bb), 256, 0, stream>>>(
        kn, vv, alpha, beta, logc, Mbuf);
    // 4b. chunk-state recurrence, element-parallel (Mbuf -> Sstates in place)
    state_scan<<<2048, 256, 0, stream>>>(Mbuf, logc, rec_state, input_pos);
    // 4c. per-chunk outputs + RMSNorm + gate -> gated_b (bf16)
    chunk_out<<<dim3(NCHUNK, Hh, Bb), 256, 0, stream>>>(
        qn, kn, vv, beta, logc, Mbuf, norm_w, zbuf, gated_b);
    // 5. out = gated @ W_out   (MFMA bf16)
    gemm_bf16<<<dim3(2048 / 128, Mrows / 128), 256, 0, stream>>>(
        gated_b, WoT, out, 2048, 2048, 2048, 2048);
}

// Round 6
// 576.132 us; speedup vs baseline: 10.4151x; 1.4168x over previous
//
#include <hip/hip_runtime.h>
#include <hip/hip_bf16.h>
#include <math.h>

#define Bb 2
#define Tt 2048
#define Cc 2048
#define Hh 16
#define CONVD 6144
#define Mrows 4096  // B*T
#define NCHUNK 32   // T / 64

typedef __attribute__((ext_vector_type(8))) short short8v;
typedef __attribute__((ext_vector_type(4))) float floatx4;

__device__ __forceinline__ unsigned short f2bf(float f) {
    __hip_bfloat16 h = __float2bfloat16(f);
    return __builtin_bit_cast(unsigned short, h);
}

__device__ __forceinline__ void load_lds16(const void* g, void* l) {
    __builtin_amdgcn_global_load_lds(
        (const __attribute__((address_space(1))) void*)g,
        (__attribute__((address_space(3))) void*)l, 16, 0, 0);
}

// col-swizzle for float LDS tiles with 128-col rows read as float4 at tj*8:
// XOR bits 3..4 with (col>>5) -> 16 tj bases spread over all bank groups.
__device__ __forceinline__ int swz8(int col) {
    return col ^ (((col >> 5) & 3) << 3);
}

// ---------------- cast f32 -> bf16, 4 elems/thread --------------------------
__global__ __launch_bounds__(256) void cast_bf16(
    const float* __restrict__ in, unsigned short* __restrict__ out, long n)
{
    long i = ((long)blockIdx.x * 256 + threadIdx.x) * 4;
    if (i + 3 >= n) return;
    float4 f = *(const float4*)(in + i);
    ushort4 o;
    o.x = f2bf(f.x); o.y = f2bf(f.y); o.z = f2bf(f.z); o.w = f2bf(f.w);
    *(ushort4*)(out + i) = o;
}

// ---------------- transpose + cast: W (KxN f32) -> WT (NxK bf16) ------------
__global__ __launch_bounds__(256) void transpose_cast(
    const float* __restrict__ W, unsigned short* __restrict__ WT, int Kk, int Nn)
{
    __shared__ float tile[32][33];
    const int n0 = blockIdx.x * 32;
    const int k0 = blockIdx.y * 32;
    const int tx = threadIdx.x & 31;
    const int ty = threadIdx.x >> 5;
#pragma unroll
    for (int r = ty; r < 32; r += 8)
        tile[r][tx] = W[(size_t)(k0 + r) * Nn + n0 + tx];
    __syncthreads();
#pragma unroll
    for (int r = ty; r < 32; r += 8)
        WT[(size_t)(n0 + r) * Kk + k0 + tx] = f2bf(tile[tx][r]);
}

// ---- bf16 MFMA GEMM: C(MxN f32) = A(MxK bf16) @ Bt(NxK bf16)^T -------------
// 128x128 tile, BK=64, 256 threads (4 waves, 2x2), 16x16x32 MFMA.
// LDS tiles row-major [128][64] bf16, staged via global_load_lds width 16:
// 8 lanes cover one 128B row (contiguous global reads). Fragment ds_read_b128
// stride-128B conflict removed by XOR swizzle (col8 ^= row&7), applied on the
// pre-swizzled GLOBAL source (LDS write stays linear) and on the read addr.
__global__ __launch_bounds__(256) void gemm_bf16(
    const unsigned short* __restrict__ A, const unsigned short* __restrict__ Bt,
    float* __restrict__ C, int Kk, int lda, int ldb, int ldc)
{
    __shared__ __align__(16) unsigned short A_lds[128 * 64];
    __shared__ __align__(16) unsigned short B_lds[128 * 64];

    const int tid = threadIdx.x;
    const int wv = tid >> 6;
    const int lane = tid & 63;
    const int wr = wv >> 1, wc = wv & 1;
    const int l15 = lane & 15, kq = lane >> 4;
    const int rsw = (l15 & 7) << 3;           // read-side swizzle (shorts)
    const int block_m = blockIdx.y * 128;
    const int block_n = blockIdx.x * 128;

    const int srow = lane >> 3;                       // 0..7 within 8-row group
    const int scol = ((lane & 7) ^ srow) << 3;        // swizzled source col

    floatx4 acc[4][4] = {};

    for (int k0 = 0; k0 < Kk; k0 += 64) {
#pragma unroll
        for (int i = 0; i < 4; ++i) {
            const int lq = wv * 4 + i;                // rows lq*8 .. lq*8+7
            const unsigned short* asrc =
                A + (size_t)(block_m + lq * 8 + srow) * lda + k0 + scol;
            load_lds16(asrc, &A_lds[lq * 512]);
            const unsigned short* bsrc =
                Bt + (size_t)(block_n + lq * 8 + srow) * ldb + k0 + scol;
            load_lds16(bsrc, &B_lds[lq * 512]);
        }
        __syncthreads();

#pragma unroll
        for (int kk = 0; kk < 2; ++kk) {
            short8v af[4], bf[4];
#pragma unroll
            for (int mf = 0; mf < 4; ++mf) {
                const int row = wr * 64 + mf * 16 + l15;
                af[mf] = *(const short8v*)&A_lds[row * 64 + ((kk * 32 + kq * 8) ^ rsw)];
            }
#pragma unroll
            for (int nf = 0; nf < 4; ++nf) {
                const int row = wc * 64 + nf * 16 + l15;
                bf[nf] = *(const short8v*)&B_lds[row * 64 + ((kk * 32 + kq * 8) ^ rsw)];
            }
#pragma unroll
            for (int mf = 0; mf < 4; ++mf)
#pragma unroll
                for (int nf = 0; nf < 4; ++nf)
                    acc[mf][nf] = __builtin_amdgcn_mfma_f32_16x16x32_bf16(
                        af[mf], bf[nf], acc[mf][nf], 0, 0, 0);
        }
        __syncthreads();
    }

    // epilogue: D row=(lane>>4)*4+reg, col=lane&15 (m89-verified layout)
#pragma unroll
    for (int mf = 0; mf < 4; ++mf)
#pragma unroll
        for (int nf = 0; nf < 4; ++nf)
#pragma unroll
            for (int r = 0; r < 4; ++r) {
                int row = block_m + wr * 64 + mf * 16 + kq * 4 + r;
                int col = block_n + wc * 64 + nf * 16 + l15;
                C[(size_t)row * ldc + col] = acc[mf][nf][r];
            }
}

// ---------------- alpha/beta: sigmoid(x @ W_{a,b}), W is (2048,16) ----------
__global__ __launch_bounds__(256) void ab_kernel(
    const float* __restrict__ x, const float* __restrict__ W_b,
    const float* __restrict__ W_a, float* __restrict__ beta,
    float* __restrict__ alpha)
{
    const int row = blockIdx.x;
    const int tid = threadIdx.x;
    float acc[32];
#pragma unroll
    for (int u = 0; u < 32; ++u) acc[u] = 0.f;

    for (int k = tid; k < Cc; k += 256) {
        float xv = x[(size_t)row * Cc + k];
        const float4* wb = (const float4*)(W_b + (size_t)k * 16);
        const float4* wa = (const float4*)(W_a + (size_t)k * 16);
#pragma unroll
        for (int u = 0; u < 4; ++u) {
            float4 b4 = wb[u];
            float4 a4 = wa[u];
            acc[u * 4 + 0] = fmaf(xv, b4.x, acc[u * 4 + 0]);
            acc[u * 4 + 1] = fmaf(xv, b4.y, acc[u * 4 + 1]);
            acc[u * 4 + 2] = fmaf(xv, b4.z, acc[u * 4 + 2]);
            acc[u * 4 + 3] = fmaf(xv, b4.w, acc[u * 4 + 3]);
            acc[16 + u * 4 + 0] = fmaf(xv, a4.x, acc[16 + u * 4 + 0]);
            acc[16 + u * 4 + 1] = fmaf(xv, a4.y, acc[16 + u * 4 + 1]);
            acc[16 + u * 4 + 2] = fmaf(xv, a4.z, acc[16 + u * 4 + 2]);
            acc[16 + u * 4 + 3] = fmaf(xv, a4.w, acc[16 + u * 4 + 3]);
        }
    }
#pragma unroll
    for (int u = 0; u < 32; ++u) {
        float v = acc[u];
        for (int off = 32; off > 0; off >>= 1) v += __shfl_down(v, off);
        acc[u] = v;
    }
    __shared__ float red[4][32];
    const int wv = tid >> 6;
    if ((tid & 63) == 0) {
#pragma unroll
        for (int u = 0; u < 32; ++u) red[wv][u] = acc[u];
    }
    __syncthreads();
    if (tid < 32) {
        float v = red[0][tid] + red[1][tid] + red[2][tid] + red[3][tid];
        float s = 1.f / (1.f + expf(-v));
        if (tid < 16) beta[(size_t)row * 16 + tid] = s;
        else          alpha[(size_t)row * 16 + (tid - 16)] = s;
    }
}

// ------- conv(K=4) + SiLU + split + l2norm(q,k), 8 timesteps per block ------
__global__ __launch_bounds__(128) void conv_kernel(
    const float* __restrict__ qkv, const float* __restrict__ conv_w,
    const float* __restrict__ conv_state, const int* __restrict__ input_pos,
    float* __restrict__ qn, float* __restrict__ kn, float* __restrict__ vv)
{
    const int tc = blockIdx.x;       // 0..255
    const int hs = blockIdx.y;       // 0..47
    const int b  = blockIdx.z;
    const int lane = threadIdx.x;    // 0..127
    const int kind = hs >> 4;
    const int h = hs & 15;
    const int c = kind * 2048 + h * 128 + lane;
    const int t0 = tc * 8;
    const float keep = (input_pos[0] == 0) ? 0.f : 1.f;

    const float4 w4 = *(const float4*)(conv_w + (size_t)c * 4);

    float win0, win1, win2;
    {
        float tmp[3];
#pragma unroll
        for (int j = 0; j < 3; ++j) {
            int tau = t0 - 3 + j;
            tmp[j] = (tau >= 0) ? qkv[(size_t)(b * Tt + tau) * CONVD + c]
                   : keep * conv_state[((size_t)b * CONVD + c) * 4 + (tau + 4)];
        }
        win0 = tmp[0]; win1 = tmp[1]; win2 = tmp[2];
    }

    float y[8];
    __shared__ float red[8][2];
#pragma unroll
    for (int i = 0; i < 8; ++i) {
        float xv = qkv[(size_t)(b * Tt + t0 + i) * CONVD + c];
        float a = fmaf(w4.x, win0, fmaf(w4.y, win1, fmaf(w4.z, win2, w4.w * xv)));
        float yy = a / (1.f + expf(-a));
        win0 = win1; win1 = win2; win2 = xv;
        if (kind == 2) {
            vv[(size_t)(b * Tt + t0 + i) * 2048 + h * 128 + lane] = yy;
        } else {
            float sq = yy * yy;
            for (int off = 32; off > 0; off >>= 1) sq += __shfl_down(sq, off);
            if ((lane & 63) == 0) red[i][lane >> 6] = sq;
            y[i] = yy;
        }
    }
    if (kind == 2) return;
    __syncthreads();
#pragma unroll
    for (int i = 0; i < 8; ++i) {
        float tot = red[i][0] + red[i][1];
        float inv = 1.f / fmaxf(sqrtf(tot), 1e-12f);
        float outv = y[i] * inv;
        const size_t oidx = (size_t)(b * Tt + t0 + i) * 2048 + h * 128 + lane;
        if (kind == 0) qn[oidx] = outv;
        else           kn[oidx] = outv;
    }
}

// ================= chunked scan, stage A: per-chunk prep =====================
__global__ __launch_bounds__(256) void chunk_prep(
    const float* __restrict__ kn, const float* __restrict__ vv,
    const float* __restrict__ alpha, const float* __restrict__ beta,
    float* __restrict__ logc_g, float* __restrict__ Mbuf)
{
    const int c = blockIdx.x, h = blockIdx.y, b = blockIdx.z;
    const int tid = threadIdx.x;
    const size_t bh = (size_t)b * Hh + h;

    __shared__ float K_lds[32][128];
    __shared__ float V_lds[32][128];
    __shared__ float logc_lds[64];
    __shared__ float b_lds[64];
    __shared__ float wk_lds[64];

    if (tid < 64) {
        const int row = b * Tt + c * 64 + tid;
        float a = alpha[(size_t)row * 16 + h];
        float la = logf(a);
#pragma unroll
        for (int d = 1; d < 64; d <<= 1) {
            float n = __shfl_up(la, d);
            if (tid >= d) la += n;
        }
        logc_lds[tid] = la;
        logc_g[bh * Tt + c * 64 + tid] = la;
        b_lds[tid] = beta[(size_t)row * 16 + h];
    }
    __syncthreads();
    if (tid < 64) {
        wk_lds[tid] = expf(logc_lds[63] - logc_lds[tid]) * b_lds[tid];
    }
    __syncthreads();

    const int ti = tid >> 4;
    const int tj = tid & 15;
    const int tj8sw = swz8(tj * 8);
    float acc[8][8];
#pragma unroll
    for (int i = 0; i < 8; ++i)
#pragma unroll
        for (int j = 0; j < 8; ++j) acc[i][j] = 0.f;

    for (int half = 0; half < 2; ++half) {
        {
            const int sl = tid >> 3;
            const int c0 = (tid & 7) * 16;
            const int grow = b * Tt + c * 64 + half * 32 + sl;
            const float4* kp = (const float4*)(kn + (size_t)grow * 2048 + h * 128 + c0);
            const float4* vp = (const float4*)(vv + (size_t)grow * 2048 + h * 128 + c0);
#pragma unroll
            for (int u = 0; u < 4; ++u) {
                const int cl = c0 + u * 4;
                *(float4*)(&K_lds[sl][cl]) = kp[u];
                *(float4*)(&V_lds[sl][swz8(cl)]) = vp[u];   // swizzled V store
            }
        }
        __syncthreads();
#pragma unroll 4
        for (int s = 0; s < 32; ++s) {
            float w = wk_lds[half * 32 + s];
            float4 k0 = *(const float4*)(&K_lds[s][ti * 8]);
            float4 k1 = *(const float4*)(&K_lds[s][ti * 8 + 4]);
            float4 v0 = *(const float4*)(&V_lds[s][tj8sw]);
            float4 v1 = *(const float4*)(&V_lds[s][tj8sw + 4]);
            float wk[8] = {w*k0.x, w*k0.y, w*k0.z, w*k0.w, w*k1.x, w*k1.y, w*k1.z, w*k1.w};
            float vf[8] = {v0.x, v0.y, v0.z, v0.w, v1.x, v1.y, v1.z, v1.w};
#pragma unroll
            for (int i = 0; i < 8; ++i)
#pragma unroll
                for (int j = 0; j < 8; ++j)
                    acc[i][j] = fmaf(wk[i], vf[j], acc[i][j]);
        }
        __syncthreads();
    }
    float* mb = Mbuf + ((bh * NCHUNK) + c) * 16384;
#pragma unroll
    for (int i = 0; i < 8; ++i) {
        float4 o0 = {acc[i][0], acc[i][1], acc[i][2], acc[i][3]};
        float4 o1 = {acc[i][4], acc[i][5], acc[i][6], acc[i][7]};
        *(float4*)(mb + (size_t)(ti * 8 + i) * 128 + tj * 8) = o0;
        *(float4*)(mb + (size_t)(ti * 8 + i) * 128 + tj * 8 + 4) = o1;
    }
}

// ================= chunked scan, stage B: state recurrence ==================
__global__ __launch_bounds__(256) void state_scan(
    float* __restrict__ Mbuf, const float* __restrict__ logc_g,
    const float* __restrict__ rec_state, const int* __restrict__ input_pos)
{
    const size_t g = (size_t)blockIdx.x * 256 + threadIdx.x;  // 0..524287
    const int bh = (int)(g >> 14);
    const float keep = (input_pos[0] == 0) ? 0.f : 1.f;

    float S = keep * rec_state[g];
    const float* lc = logc_g + (size_t)bh * Tt;
    float* base = Mbuf + (size_t)(g & ~16383ull) * NCHUNK + (g & 16383);
#pragma unroll 4
    for (int c = 0; c < NCHUNK; ++c) {
        float Atot = expf(lc[c * 64 + 63]);
        float m = base[(size_t)c * 16384];
        base[(size_t)c * 16384] = S;
        S = fmaf(Atot, S, m);
    }
}

// ================= chunked scan, stage C: per-chunk output ==================
// 256 threads as (ti 0..15 -> 4 t-rows, tj 0..15 -> 8 v-cols), register-tiled.
// o_t = exp(lc_t) * q_t @ S_c + sum_{s<=t} exp(lc_t-lc_s) b_s (q_t.k_s) v_s
// then RMSNorm + norm_w + sigmoid(z) gate, written as bf16.
__global__ __launch_bounds__(256) void chunk_out(
    const float* __restrict__ qn, const float* __restrict__ kn,
    const float* __restrict__ vv, const float* __restrict__ beta,
    const float* __restrict__ logc_g, const float* __restrict__ Sstates,
    const float* __restrict__ norm_w, const float* __restrict__ zbuf,
    unsigned short* __restrict__ gated_b)
{
    const int c = blockIdx.x, h = blockIdx.y, b = blockIdx.z;
    const int tid = threadIdx.x;
    const int ti = tid >> 4;
    const int tj = tid & 15;
    const size_t bh = (size_t)b * Hh + h;
    const int row0 = b * Tt + c * 64;

    __shared__ float Q_lds[64][132];   // padded stride: scalar reads 2-way max
    __shared__ float Bf[64 * 68];      // K_T[64][68] / S[16][132] / V[32][132]
    __shared__ float At[64][68];
    __shared__ float logc_s[64], b_s[64];

    // ---- load Q (64x128), logc, beta ----
    {
        const int r = tid >> 2, c0 = (tid & 3) * 32;
        const float4* qp = (const float4*)(qn + (size_t)(row0 + r) * 2048 + h * 128 + c0);
#pragma unroll
        for (int u = 0; u < 8; ++u)
            *(float4*)(&Q_lds[r][c0 + u * 4]) = qp[u];
    }
    if (tid < 64) {
        logc_s[tid] = logc_g[bh * Tt + c * 64 + tid];
        b_s[tid] = beta[(size_t)(row0 + tid) * 16 + h];
    }

    // ---- QK^T (64x64), K stored transposed: K_T[k][s], stride 68 ----
    float acc_a[4][4] = {};
    for (int kh = 0; kh < 2; ++kh) {
        __syncthreads();
        {
            const int s = tid >> 2, c0 = (tid & 3) * 16;
            const float* kp = kn + (size_t)(row0 + s) * 2048 + h * 128 + kh * 64 + c0;
#pragma unroll
            for (int u = 0; u < 16; ++u)
                Bf[(c0 + u) * 68 + s] = kp[u];
        }
        __syncthreads();
#pragma unroll 4
        for (int kk = 0; kk < 64; ++kk) {
            float a[4];
#pragma unroll
            for (int r = 0; r < 4; ++r) a[r] = Q_lds[ti * 4 + r][kh * 64 + kk];
            float4 bq = *(const float4*)(&Bf[kk * 68 + tj * 4]);
            float bb[4] = {bq.x, bq.y, bq.z, bq.w};
#pragma unroll
            for (int r = 0; r < 4; ++r)
#pragma unroll
                for (int cc = 0; cc < 4; ++cc)
                    acc_a[r][cc] = fmaf(a[r], bb[cc], acc_a[r][cc]);
        }
    }

    // ---- apply causal decay weights, write Attn ----
#pragma unroll
    for (int r = 0; r < 4; ++r) {
        const int t = ti * 4 + r;
        const float lct = logc_s[t];
#pragma unroll
        for (int cc = 0; cc < 4; ++cc) {
            const int s = tj * 4 + cc;
            float w = (s <= t) ? expf(lct - logc_s[s]) * b_s[s] : 0.f;
            At[t][s] = w * acc_a[r][cc];
        }
    }

    // ---- inter-chunk: o = q @ S_c, S streamed 16 rows at a time ----
    float o[4][8] = {};
    const float* Sbase = Sstates + (bh * NCHUNK + c) * 16384;
    const int tj8sw = swz8(tj * 8);
    for (int kb = 0; kb < 8; ++kb) {
        __syncthreads();
        {
            const int rr = tid >> 4;
            const int cl = (tid & 15) * 8;
            const int sw = swz8(cl);
            const float4* sp = (const float4*)(Sbase + (size_t)(kb * 16 + rr) * 128 + cl);
            *(float4*)(&Bf[rr * 132 + sw]) = sp[0];
            *(float4*)(&Bf[rr * 132 + sw + 4]) = sp[1];
        }
        __syncthreads();
#pragma unroll
        for (int kk = 0; kk < 16; ++kk) {
            float a[4];
#pragma unroll
            for (int r = 0; r < 4; ++r) a[r] = Q_lds[ti * 4 + r][kb * 16 + kk];
            float4 s0 = *(const float4*)(&Bf[kk * 132 + tj8sw]);
            float4 s1 = *(const float4*)(&Bf[kk * 132 + tj8sw + 4]);
            float sv[8] = {s0.x, s0.y, s0.z, s0.w, s1.x, s1.y, s1.z, s1.w};
#pragma unroll
            for (int r = 0; r < 4; ++r)
#pragma unroll
                for (int j = 0; j < 8; ++j)
                    o[r][j] = fmaf(a[r], sv[j], o[r][j]);
        }
    }
#pragma unroll
    for (int r = 0; r < 4; ++r) {
        const float ct = expf(logc_s[ti * 4 + r]);
#pragma unroll
        for (int j = 0; j < 8; ++j) o[r][j] *= ct;
    }

    // ---- intra-chunk: o += Attn @ V, V streamed 32 rows at a time ----
    for (int sh = 0; sh < 2; ++sh) {
        __syncthreads();
        {
            const int rr = tid >> 3;
            const int c0 = (tid & 7) * 16;
            const float4* vp = (const float4*)(vv + (size_t)(row0 + sh * 32 + rr) * 2048 + h * 128 + c0);
#pragma unroll
            for (int u = 0; u < 4; ++u) {
                const int cl = c0 + u * 4;
                *(float4*)(&Bf[rr * 132 + swz8(cl)]) = vp[u];
            }
        }
        __syncthreads();
#pragma unroll 2
        for (int sp = 0; sp < 32; ++sp) {
            const int s = sh * 32 + sp;
            float a[4];
#pragma unroll
            for (int r = 0; r < 4; ++r) a[r] = At[ti * 4 + r][s];
            float4 v0 = *(const float4*)(&Bf[sp * 132 + tj8sw]);
            float4 v1 = *(const float4*)(&Bf[sp * 132 + tj8sw + 4]);
            float vf[8] = {v0.x, v0.y, v0.z, v0.w, v1.x, v1.y, v1.z, v1.w};
#pragma unroll
            for (int r = 0; r < 4; ++r)
#pragma unroll
                for (int j = 0; j < 8; ++j)
                    o[r][j] = fmaf(a[r], vf[j], o[r][j]);
        }
    }

    // ---- epilogue: RMSNorm (reduce across the 16 tj lanes) + gate ----
#pragma unroll
    for (int r = 0; r < 4; ++r) {
        float ss = 0.f;
#pragma unroll
        for (int j = 0; j < 8; ++j) ss = fmaf(o[r][j], o[r][j], ss);
        ss += __shfl_xor(ss, 1);
        ss += __shfl_xor(ss, 2);
        ss += __shfl_xor(ss, 4);
        ss += __shfl_xor(ss, 8);
        const float scale = rsqrtf(ss * (1.f / 128.f) + 1e-6f);
        const int t = ti * 4 + r;
        const float* zp = zbuf + (size_t)(row0 + t) * 2048 + h * 128 + tj * 8;
        unsigned short* gp = gated_b + (size_t)(row0 + t) * 2048 + h * 128 + tj * 8;
#pragma unroll
        for (int j = 0; j < 8; ++j) {
            float zv = zp[j];
            float g = o[r][j] * scale * norm_w[tj * 8 + j] * (1.f / (1.f + expf(-zv)));
            gp[j] = f2bf(g);
        }
    }
}

extern "C" void kernel_launch(void* const* d_in, const int* in_sizes, int n_in,
                              void* d_out, int out_size, void* d_ws, size_t ws_size,
                              hipStream_t stream) {
    (void)in_sizes; (void)n_in; (void)out_size; (void)ws_size;
    const float* x          = (const float*)d_in[0];
    const int*   input_pos  = (const int*)d_in[1];
    const float* W_qkvz     = (const float*)d_in[2];
    const float* W_b        = (const float*)d_in[3];
    const float* W_a        = (const float*)d_in[4];
    const float* conv_w     = (const float*)d_in[5];
    const float* norm_w     = (const float*)d_in[6];
    const float* W_out      = (const float*)d_in[7];
    const float* conv_state = (const float*)d_in[8];
    const float* rec_state  = (const float*)d_in[9];
    float* out = (float*)d_out;
    float* ws  = (float*)d_ws;

    // workspace (float elems), peak 232.75 MiB with phase-based aliasing:
    float* qkv   = ws;                                 // 25,165,824 f (phase 2-3)
    float* Mbuf  = ws;                                 // 16,777,216 f (phase 4+, aliases qkv)
    unsigned short* gated_b = (unsigned short*)(ws + 16777216); // 8,388,608 bf16 (phase 5+)
    float* qn    = ws + 25165824ull;                   // 8,388,608 f (phase 3+)
    float* kn    = qn + 8388608ull;
    float* vv    = kn + 8388608ull;
    unsigned short* xb  = (unsigned short*)qn;         // phase 1-2, aliases qn
    unsigned short* WqT = (unsigned short*)(qn + 4194304ull); // 16,777,216 bf16, phase 1-2
    float* zbuf  = vv + 8388608ull;                    // 8,388,608 f
    unsigned short* WoT = (unsigned short*)(zbuf + 8388608ull); // 4,194,304 bf16
    float* alpha = zbuf + 8388608ull + 2097152ull;     // 65,536 f
    float* beta  = alpha + 65536ull;
    float* logc  = beta + 65536ull;

    // 0. casts / transposes (bf16 operands for MFMA GEMMs)
    cast_bf16<<<8192, 256, 0, stream>>>(x, xb, 8388608L);
    transpose_cast<<<dim3(8192 / 32, 2048 / 32), 256, 0, stream>>>(W_qkvz, WqT, 2048, 8192);
    transpose_cast<<<dim3(2048 / 32, 2048 / 32), 256, 0, stream>>>(W_out, WoT, 2048, 2048);

    // 1a. qkv = x @ W_qkvz[:, :6144]   (MFMA bf16)
    gemm_bf16<<<dim3(CONVD / 128, Mrows / 128), 256, 0, stream>>>(
        xb, WqT, qkv, 2048, 2048, 2048, CONVD);
    // 1b. z = x @ W_qkvz[:, 6144:]
    gemm_bf16<<<dim3(2048 / 128, Mrows / 128), 256, 0, stream>>>(
        xb, WqT + 6144ull * 2048, zbuf, 2048, 2048, 2048, 2048);
    // 2. alpha/beta (f32 — exp-cumsum sensitivity)
    ab_kernel<<<Mrows, 256, 0, stream>>>(x, W_b, W_a, beta, alpha);
    // 3. conv + silu + l2norm (reads qkv — last use of that buffer)
    conv_kernel<<<dim3(Tt / 8, 48, Bb), 128, 0, stream>>>(
        qkv, conv_w, conv_state, input_pos, qn, kn, vv);
    // 4a. per-chunk prep: log-cumsum + M_c  (overwrites dead qkv region)
    chunk_prep<<<dim3(NCHUNK, Hh, Bb), 256, 0, stream>>>(
        kn, vv, alpha, beta, logc, Mbuf);
    // 4b. chunk-state recurrence, element-parallel (Mbuf -> Sstates in place)
    state_scan<<<2048, 256, 0, stream>>>(Mbuf, logc, rec_state, input_pos);
    // 4c. per-chunk outputs + RMSNorm + gate -> gated_b (bf16)
    chunk_out<<<dim3(NCHUNK, Hh, Bb), 256, 0, stream>>>(
        qn, kn, vv, beta, logc, Mbuf, norm_w, zbuf, gated_b);
    // 5. out = gated @ W_out   (MFMA bf16)
    gemm_bf16<<<dim3(2048 / 128, Mrows / 128), 256, 0, stream>>>(
        gated_b, WoT, out, 2048, 2048, 2048, 2048);
}

// Round 7
// 558.247 us; speedup vs baseline: 10.7488x; 1.0320x over previous
//
#include <hip/hip_runtime.h>
#include <hip/hip_bf16.h>
#include <math.h>

#define Bb 2
#define Tt 2048
#define Cc 2048
#define Hh 16
#define CONVD 6144
#define Mrows 4096  // B*T
#define NCHUNK 32   // T / 64

typedef __attribute__((ext_vector_type(8))) short short8v;
typedef __attribute__((ext_vector_type(4))) float floatx4;

__device__ __forceinline__ unsigned short f2bf(float f) {
    __hip_bfloat16 h = __float2bfloat16(f);
    return __builtin_bit_cast(unsigned short, h);
}

__device__ __forceinline__ void load_lds16(const void* g, void* l) {
    __builtin_amdgcn_global_load_lds(
        (const __attribute__((address_space(1))) void*)g,
        (__attribute__((address_space(3))) void*)l, 16, 0, 0);
}

// col-swizzle for float LDS tiles with 128-col rows read as float4 at tj*8:
__device__ __forceinline__ int swz8(int col) {
    return col ^ (((col >> 5) & 3) << 3);
}

#define LGKM0 asm volatile("s_waitcnt lgkmcnt(0)" ::: "memory")
#define VMC4  asm volatile("s_waitcnt vmcnt(4)" ::: "memory")
#define VMC0  asm volatile("s_waitcnt vmcnt(0)" ::: "memory")
#define SCHB  __builtin_amdgcn_sched_barrier(0)
#define SBAR  __builtin_amdgcn_s_barrier()

// ---------------- cast f32 -> bf16, 4 elems/thread --------------------------
__global__ __launch_bounds__(256) void cast_bf16(
    const float* __restrict__ in, unsigned short* __restrict__ out, long n)
{
    long i = ((long)blockIdx.x * 256 + threadIdx.x) * 4;
    if (i + 3 >= n) return;
    float4 f = *(const float4*)(in + i);
    ushort4 o;
    o.x = f2bf(f.x); o.y = f2bf(f.y); o.z = f2bf(f.z); o.w = f2bf(f.w);
    *(ushort4*)(out + i) = o;
}

// ---------------- transpose + cast: W (KxN f32) -> WT (NxK bf16) ------------
__global__ __launch_bounds__(256) void transpose_cast(
    const float* __restrict__ W, unsigned short* __restrict__ WT, int Kk, int Nn)
{
    __shared__ float tile[32][33];
    const int n0 = blockIdx.x * 32;
    const int k0 = blockIdx.y * 32;
    const int tx = threadIdx.x & 31;
    const int ty = threadIdx.x >> 5;
#pragma unroll
    for (int r = ty; r < 32; r += 8)
        tile[r][tx] = W[(size_t)(k0 + r) * Nn + n0 + tx];
    __syncthreads();
#pragma unroll
    for (int r = ty; r < 32; r += 8)
        WT[(size_t)(n0 + r) * Kk + k0 + tx] = f2bf(tile[tx][r]);
}

// ======== 256x256 bf16 MFMA GEMM, counted-vmcnt pipeline (T2+T4+T5) =========
// C = A(MxK bf16) @ Bt(NxK bf16)^T. 8 waves (2Mx4N), BK=32, LDS 64KB dbuf.
// Split C-write: cols < 6144 -> C1 (ldc 6144), cols >= 6144 -> C2 (ldc 2048).
// Stage: global_load_lds w16, pre-swizzled source chunk (c ^= (row>>1)&3),
// linear LDS dest; ds_read applies the same XOR (rule #21). vmcnt(4) steady
// state (never 0 mid-loop): tile t+1's 4 loads confirmed while t+2's fly.
__global__ __launch_bounds__(512) void gemm256(
    const unsigned short* __restrict__ A, const unsigned short* __restrict__ Bt,
    float* __restrict__ C1, float* __restrict__ C2,
    int Kk, int lda, int ldb)
{
    __shared__ __align__(16) unsigned short A_lds[2][256 * 32];
    __shared__ __align__(16) unsigned short B_lds[2][256 * 32];

    const int tid  = threadIdx.x;
    const int wid  = tid >> 6;            // 0..7
    const int lane = tid & 63;
    const int wr = wid >> 2, wc = wid & 3;
    const int l15 = lane & 15, kq = lane >> 4;
    const int rdsw = (kq ^ ((l15 >> 1) & 3)) * 8;    // read-side swizzled chunk
    const int rr = lane >> 2;                        // staging row in 16-group
    const int ch = (lane & 3) ^ ((lane >> 3) & 3);   // staging swizzled chunk

    // bijective XCD swizzle (nwg % 8 == 0)
    const int nwg = gridDim.x * gridDim.y;
    int bid = blockIdx.y * gridDim.x + blockIdx.x;
    int swz = (bid & 7) * (nwg >> 3) + (bid >> 3);
    const int block_m = (swz / gridDim.x) * 256;
    const int block_n = (swz % gridDim.x) * 256;

    const int NT = Kk >> 5;

#define STAGE256(t) do {                                                     \
    const int kk0 = (t) << 5;                                                \
    unsigned short* la = &A_lds[(t) & 1][0];                                 \
    unsigned short* lb = &B_lds[(t) & 1][0];                                 \
    _Pragma("unroll")                                                        \
    for (int i_ = 0; i_ < 2; ++i_) {                                         \
        const int g_ = wid * 2 + i_;                                         \
        load_lds16(A + (size_t)(block_m + g_ * 16 + rr) * lda + kk0 + ch * 8,\
                   la + g_ * 512);                                           \
        load_lds16(Bt + (size_t)(block_n + g_ * 16 + rr) * ldb + kk0 + ch * 8,\
                   lb + g_ * 512);                                           \
    }                                                                        \
} while (0)

    floatx4 acc[8][4] = {};

    STAGE256(0);
    STAGE256(1);
    VMC4; SCHB; SBAR; SCHB;

    for (int t = 0; t < NT; ++t) {
        const unsigned short* la = &A_lds[t & 1][0];
        const unsigned short* lb = &B_lds[t & 1][0];
        short8v af[8], bf[4];
#pragma unroll
        for (int mf = 0; mf < 8; ++mf)
            af[mf] = *(const short8v*)(la + (wr * 128 + mf * 16 + l15) * 32 + rdsw);
#pragma unroll
        for (int nf = 0; nf < 4; ++nf)
            bf[nf] = *(const short8v*)(lb + (wc * 64 + nf * 16 + l15) * 32 + rdsw);
        LGKM0; SCHB;
        SBAR;                       // A: all waves done reading buf[t&1]
        SCHB;
        if (t + 2 < NT) STAGE256(t + 2);
        SCHB;
        __builtin_amdgcn_s_setprio(1);
#pragma unroll
        for (int mf = 0; mf < 8; ++mf)
#pragma unroll
            for (int nf = 0; nf < 4; ++nf)
                acc[mf][nf] = __builtin_amdgcn_mfma_f32_16x16x32_bf16(
                    af[mf], bf[nf], acc[mf][nf], 0, 0, 0);
        __builtin_amdgcn_s_setprio(0);
        SCHB;
        if (t + 2 < NT)      { VMC4; }   // t+1's loads landed; t+2's in flight
        else if (t + 1 < NT) { VMC0; }   // epilogue drain
        SCHB; SBAR; SCHB;
    }

    // C-write, split per block column (uniform per block)
    float* Cp; int col0; size_t ldc;
    if (block_n < 6144) { Cp = C1; col0 = block_n;        ldc = 6144; }
    else                { Cp = C2; col0 = block_n - 6144; ldc = 2048; }
#pragma unroll
    for (int mf = 0; mf < 8; ++mf)
#pragma unroll
        for (int nf = 0; nf < 4; ++nf)
#pragma unroll
            for (int r = 0; r < 4; ++r) {
                int row = block_m + wr * 128 + mf * 16 + kq * 4 + r;
                int col = col0 + wc * 64 + nf * 16 + l15;
                Cp[(size_t)row * ldc + col] = acc[mf][nf][r];
            }
#undef STAGE256
}

// ---- 128x128 bf16 MFMA GEMM (m97 structure) for the output projection ------
__global__ __launch_bounds__(256) void gemm_bf16(
    const unsigned short* __restrict__ A, const unsigned short* __restrict__ Bt,
    float* __restrict__ C, int Kk, int lda, int ldb, int ldc)
{
    __shared__ __align__(16) unsigned short A_lds[128 * 64];
    __shared__ __align__(16) unsigned short B_lds[128 * 64];

    const int tid = threadIdx.x;
    const int wv = tid >> 6;
    const int lane = tid & 63;
    const int wr = wv >> 1, wc = wv & 1;
    const int l15 = lane & 15, kq = lane >> 4;
    const int rsw = (l15 & 7) << 3;
    const int block_m = blockIdx.y * 128;
    const int block_n = blockIdx.x * 128;

    const int srow = lane >> 3;
    const int scol = ((lane & 7) ^ srow) << 3;

    floatx4 acc[4][4] = {};

    for (int k0 = 0; k0 < Kk; k0 += 64) {
#pragma unroll
        for (int i = 0; i < 4; ++i) {
            const int lq = wv * 4 + i;
            const unsigned short* asrc =
                A + (size_t)(block_m + lq * 8 + srow) * lda + k0 + scol;
            load_lds16(asrc, &A_lds[lq * 512]);
            const unsigned short* bsrc =
                Bt + (size_t)(block_n + lq * 8 + srow) * ldb + k0 + scol;
            load_lds16(bsrc, &B_lds[lq * 512]);
        }
        __syncthreads();

#pragma unroll
        for (int kk = 0; kk < 2; ++kk) {
            short8v af[4], bf[4];
#pragma unroll
            for (int mf = 0; mf < 4; ++mf) {
                const int row = wr * 64 + mf * 16 + l15;
                af[mf] = *(const short8v*)&A_lds[row * 64 + ((kk * 32 + kq * 8) ^ rsw)];
            }
#pragma unroll
            for (int nf = 0; nf < 4; ++nf) {
                const int row = wc * 64 + nf * 16 + l15;
                bf[nf] = *(const short8v*)&B_lds[row * 64 + ((kk * 32 + kq * 8) ^ rsw)];
            }
#pragma unroll
            for (int mf = 0; mf < 4; ++mf)
#pragma unroll
                for (int nf = 0; nf < 4; ++nf)
                    acc[mf][nf] = __builtin_amdgcn_mfma_f32_16x16x32_bf16(
                        af[mf], bf[nf], acc[mf][nf], 0, 0, 0);
        }
        __syncthreads();
    }

#pragma unroll
    for (int mf = 0; mf < 4; ++mf)
#pragma unroll
        for (int nf = 0; nf < 4; ++nf)
#pragma unroll
            for (int r = 0; r < 4; ++r) {
                int row = block_m + wr * 64 + mf * 16 + kq * 4 + r;
                int col = block_n + wc * 64 + nf * 16 + l15;
                C[(size_t)row * ldc + col] = acc[mf][nf][r];
            }
}

// ---------------- alpha/beta: sigmoid(x @ W_{a,b}), W is (2048,16) ----------
__global__ __launch_bounds__(256) void ab_kernel(
    const float* __restrict__ x, const float* __restrict__ W_b,
    const float* __restrict__ W_a, float* __restrict__ beta,
    float* __restrict__ alpha)
{
    const int row = blockIdx.x;
    const int tid = threadIdx.x;
    float acc[32];
#pragma unroll
    for (int u = 0; u < 32; ++u) acc[u] = 0.f;

    for (int k = tid; k < Cc; k += 256) {
        float xv = x[(size_t)row * Cc + k];
        const float4* wb = (const float4*)(W_b + (size_t)k * 16);
        const float4* wa = (const float4*)(W_a + (size_t)k * 16);
#pragma unroll
        for (int u = 0; u < 4; ++u) {
            float4 b4 = wb[u];
            float4 a4 = wa[u];
            acc[u * 4 + 0] = fmaf(xv, b4.x, acc[u * 4 + 0]);
            acc[u * 4 + 1] = fmaf(xv, b4.y, acc[u * 4 + 1]);
            acc[u * 4 + 2] = fmaf(xv, b4.z, acc[u * 4 + 2]);
            acc[u * 4 + 3] = fmaf(xv, b4.w, acc[u * 4 + 3]);
            acc[16 + u * 4 + 0] = fmaf(xv, a4.x, acc[16 + u * 4 + 0]);
            acc[16 + u * 4 + 1] = fmaf(xv, a4.y, acc[16 + u * 4 + 1]);
            acc[16 + u * 4 + 2] = fmaf(xv, a4.z, acc[16 + u * 4 + 2]);
            acc[16 + u * 4 + 3] = fmaf(xv, a4.w, acc[16 + u * 4 + 3]);
        }
    }
#pragma unroll
    for (int u = 0; u < 32; ++u) {
        float v = acc[u];
        for (int off = 32; off > 0; off >>= 1) v += __shfl_down(v, off);
        acc[u] = v;
    }
    __shared__ float red[4][32];
    const int wv = tid >> 6;
    if ((tid & 63) == 0) {
#pragma unroll
        for (int u = 0; u < 32; ++u) red[wv][u] = acc[u];
    }
    __syncthreads();
    if (tid < 32) {
        float v = red[0][tid] + red[1][tid] + red[2][tid] + red[3][tid];
        float s = 1.f / (1.f + expf(-v));
        if (tid < 16) beta[(size_t)row * 16 + tid] = s;
        else          alpha[(size_t)row * 16 + (tid - 16)] = s;
    }
}

// ------- conv(K=4) + SiLU + split + l2norm(q,k), 8 timesteps per block ------
__global__ __launch_bounds__(128) void conv_kernel(
    const float* __restrict__ qkv, const float* __restrict__ conv_w,
    const float* __restrict__ conv_state, const int* __restrict__ input_pos,
    float* __restrict__ qn, float* __restrict__ kn, float* __restrict__ vv)
{
    const int tc = blockIdx.x;
    const int hs = blockIdx.y;
    const int b  = blockIdx.z;
    const int lane = threadIdx.x;
    const int kind = hs >> 4;
    const int h = hs & 15;
    const int c = kind * 2048 + h * 128 + lane;
    const int t0 = tc * 8;
    const float keep = (input_pos[0] == 0) ? 0.f : 1.f;

    const float4 w4 = *(const float4*)(conv_w + (size_t)c * 4);

    float win0, win1, win2;
    {
        float tmp[3];
#pragma unroll
        for (int j = 0; j < 3; ++j) {
            int tau = t0 - 3 + j;
            tmp[j] = (tau >= 0) ? qkv[(size_t)(b * Tt + tau) * CONVD + c]
                   : keep * conv_state[((size_t)b * CONVD + c) * 4 + (tau + 4)];
        }
        win0 = tmp[0]; win1 = tmp[1]; win2 = tmp[2];
    }

    float y[8];
    __shared__ float red[8][2];
#pragma unroll
    for (int i = 0; i < 8; ++i) {
        float xv = qkv[(size_t)(b * Tt + t0 + i) * CONVD + c];
        float a = fmaf(w4.x, win0, fmaf(w4.y, win1, fmaf(w4.z, win2, w4.w * xv)));
        float yy = a / (1.f + expf(-a));
        win0 = win1; win1 = win2; win2 = xv;
        if (kind == 2) {
            vv[(size_t)(b * Tt + t0 + i) * 2048 + h * 128 + lane] = yy;
        } else {
            float sq = yy * yy;
            for (int off = 32; off > 0; off >>= 1) sq += __shfl_down(sq, off);
            if ((lane & 63) == 0) red[i][lane >> 6] = sq;
            y[i] = yy;
        }
    }
    if (kind == 2) return;
    __syncthreads();
#pragma unroll
    for (int i = 0; i < 8; ++i) {
        float tot = red[i][0] + red[i][1];
        float inv = 1.f / fmaxf(sqrtf(tot), 1e-12f);
        float outv = y[i] * inv;
        const size_t oidx = (size_t)(b * Tt + t0 + i) * 2048 + h * 128 + lane;
        if (kind == 0) qn[oidx] = outv;
        else           kn[oidx] = outv;
    }
}

// ================= chunked scan, stage A: per-chunk prep =====================
__global__ __launch_bounds__(256) void chunk_prep(
    const float* __restrict__ kn, const float* __restrict__ vv,
    const float* __restrict__ alpha, const float* __restrict__ beta,
    float* __restrict__ logc_g, float* __restrict__ Mbuf)
{
    const int c = blockIdx.x, h = blockIdx.y, b = blockIdx.z;
    const int tid = threadIdx.x;
    const size_t bh = (size_t)b * Hh + h;

    __shared__ float K_lds[32][128];
    __shared__ float V_lds[32][128];
    __shared__ float logc_lds[64];
    __shared__ float b_lds[64];
    __shared__ float wk_lds[64];

    if (tid < 64) {
        const int row = b * Tt + c * 64 + tid;
        float a = alpha[(size_t)row * 16 + h];
        float la = logf(a);
#pragma unroll
        for (int d = 1; d < 64; d <<= 1) {
            float n = __shfl_up(la, d);
            if (tid >= d) la += n;
        }
        logc_lds[tid] = la;
        logc_g[bh * Tt + c * 64 + tid] = la;
        b_lds[tid] = beta[(size_t)row * 16 + h];
    }
    __syncthreads();
    if (tid < 64) {
        wk_lds[tid] = expf(logc_lds[63] - logc_lds[tid]) * b_lds[tid];
    }
    __syncthreads();

    const int ti = tid >> 4;
    const int tj = tid & 15;
    const int tj8sw = swz8(tj * 8);
    float acc[8][8];
#pragma unroll
    for (int i = 0; i < 8; ++i)
#pragma unroll
        for (int j = 0; j < 8; ++j) acc[i][j] = 0.f;

    for (int half = 0; half < 2; ++half) {
        {
            const int sl = tid >> 3;
            const int c0 = (tid & 7) * 16;
            const int grow = b * Tt + c * 64 + half * 32 + sl;
            const float4* kp = (const float4*)(kn + (size_t)grow * 2048 + h * 128 + c0);
            const float4* vp = (const float4*)(vv + (size_t)grow * 2048 + h * 128 + c0);
#pragma unroll
            for (int u = 0; u < 4; ++u) {
                const int cl = c0 + u * 4;
                *(float4*)(&K_lds[sl][cl]) = kp[u];
                *(float4*)(&V_lds[sl][swz8(cl)]) = vp[u];
            }
        }
        __syncthreads();
#pragma unroll 4
        for (int s = 0; s < 32; ++s) {
            float w = wk_lds[half * 32 + s];
            float4 k0 = *(const float4*)(&K_lds[s][ti * 8]);
            float4 k1 = *(const float4*)(&K_lds[s][ti * 8 + 4]);
            float4 v0 = *(const float4*)(&V_lds[s][tj8sw]);
            float4 v1 = *(const float4*)(&V_lds[s][tj8sw + 4]);
            float wk[8] = {w*k0.x, w*k0.y, w*k0.z, w*k0.w, w*k1.x, w*k1.y, w*k1.z, w*k1.w};
            float vf[8] = {v0.x, v0.y, v0.z, v0.w, v1.x, v1.y, v1.z, v1.w};
#pragma unroll
            for (int i = 0; i < 8; ++i)
#pragma unroll
                for (int j = 0; j < 8; ++j)
                    acc[i][j] = fmaf(wk[i], vf[j], acc[i][j]);
        }
        __syncthreads();
    }
    float* mb = Mbuf + ((bh * NCHUNK) + c) * 16384;
#pragma unroll
    for (int i = 0; i < 8; ++i) {
        float4 o0 = {acc[i][0], acc[i][1], acc[i][2], acc[i][3]};
        float4 o1 = {acc[i][4], acc[i][5], acc[i][6], acc[i][7]};
        *(float4*)(mb + (size_t)(ti * 8 + i) * 128 + tj * 8) = o0;
        *(float4*)(mb + (size_t)(ti * 8 + i) * 128 + tj * 8 + 4) = o1;
    }
}

// ================= chunked scan, stage B: state recurrence ==================
__global__ __launch_bounds__(256) void state_scan(
    float* __restrict__ Mbuf, const float* __restrict__ logc_g,
    const float* __restrict__ rec_state, const int* __restrict__ input_pos)
{
    const size_t g = (size_t)blockIdx.x * 256 + threadIdx.x;
    const int bh = (int)(g >> 14);
    const float keep = (input_pos[0] == 0) ? 0.f : 1.f;

    float S = keep * rec_state[g];
    const float* lc = logc_g + (size_t)bh * Tt;
    float* base = Mbuf + (size_t)(g & ~16383ull) * NCHUNK + (g & 16383);
#pragma unroll 4
    for (int c = 0; c < NCHUNK; ++c) {
        float Atot = expf(lc[c * 64 + 63]);
        float m = base[(size_t)c * 16384];
        base[(size_t)c * 16384] = S;
        S = fmaf(Atot, S, m);
    }
}

// ================= chunked scan, stage C: per-chunk output ==================
__global__ __launch_bounds__(256) void chunk_out(
    const float* __restrict__ qn, const float* __restrict__ kn,
    const float* __restrict__ vv, const float* __restrict__ beta,
    const float* __restrict__ logc_g, const float* __restrict__ Sstates,
    const float* __restrict__ norm_w, const float* __restrict__ zbuf,
    unsigned short* __restrict__ gated_b)
{
    const int c = blockIdx.x, h = blockIdx.y, b = blockIdx.z;
    const int tid = threadIdx.x;
    const int ti = tid >> 4;
    const int tj = tid & 15;
    const size_t bh = (size_t)b * Hh + h;
    const int row0 = b * Tt + c * 64;

    __shared__ float Q_lds[64][132];
    __shared__ float Bf[64 * 68];
    __shared__ float At[64][68];
    __shared__ float logc_s[64], b_s[64];

    {
        const int r = tid >> 2, c0 = (tid & 3) * 32;
        const float4* qp = (const float4*)(qn + (size_t)(row0 + r) * 2048 + h * 128 + c0);
#pragma unroll
        for (int u = 0; u < 8; ++u)
            *(float4*)(&Q_lds[r][c0 + u * 4]) = qp[u];
    }
    if (tid < 64) {
        logc_s[tid] = logc_g[bh * Tt + c * 64 + tid];
        b_s[tid] = beta[(size_t)(row0 + tid) * 16 + h];
    }

    float acc_a[4][4] = {};
    for (int kh = 0; kh < 2; ++kh) {
        __syncthreads();
        {
            const int s = tid >> 2, c0 = (tid & 3) * 16;
            const float* kp = kn + (size_t)(row0 + s) * 2048 + h * 128 + kh * 64 + c0;
#pragma unroll
            for (int u = 0; u < 16; ++u)
                Bf[(c0 + u) * 68 + s] = kp[u];
        }
        __syncthreads();
#pragma unroll 4
        for (int kk = 0; kk < 64; ++kk) {
            float a[4];
#pragma unroll
            for (int r = 0; r < 4; ++r) a[r] = Q_lds[ti * 4 + r][kh * 64 + kk];
            float4 bq = *(const float4*)(&Bf[kk * 68 + tj * 4]);
            float bb[4] = {bq.x, bq.y, bq.z, bq.w};
#pragma unroll
            for (int r = 0; r < 4; ++r)
#pragma unroll
                for (int cc = 0; cc < 4; ++cc)
                    acc_a[r][cc] = fmaf(a[r], bb[cc], acc_a[r][cc]);
        }
    }

#pragma unroll
    for (int r = 0; r < 4; ++r) {
        const int t = ti * 4 + r;
        const float lct = logc_s[t];
#pragma unroll
        for (int cc = 0; cc < 4; ++cc) {
            const int s = tj * 4 + cc;
            float w = (s <= t) ? expf(lct - logc_s[s]) * b_s[s] : 0.f;
            At[t][s] = w * acc_a[r][cc];
        }
    }

    float o[4][8] = {};
    const float* Sbase = Sstates + (bh * NCHUNK + c) * 16384;
    const int tj8sw = swz8(tj * 8);
    for (int kb = 0; kb < 8; ++kb) {
        __syncthreads();
        {
            const int rr = tid >> 4;
            const int cl = (tid & 15) * 8;
            const int sw = swz8(cl);
            const float4* sp = (const float4*)(Sbase + (size_t)(kb * 16 + rr) * 128 + cl);
            *(float4*)(&Bf[rr * 132 + sw]) = sp[0];
            *(float4*)(&Bf[rr * 132 + sw + 4]) = sp[1];
        }
        __syncthreads();
#pragma unroll
        for (int kk = 0; kk < 16; ++kk) {
            float a[4];
#pragma unroll
            for (int r = 0; r < 4; ++r) a[r] = Q_lds[ti * 4 + r][kb * 16 + kk];
            float4 s0 = *(const float4*)(&Bf[kk * 132 + tj8sw]);
            float4 s1 = *(const float4*)(&Bf[kk * 132 + tj8sw + 4]);
            float sv[8] = {s0.x, s0.y, s0.z, s0.w, s1.x, s1.y, s1.z, s1.w};
#pragma unroll
            for (int r = 0; r < 4; ++r)
#pragma unroll
                for (int j = 0; j < 8; ++j)
                    o[r][j] = fmaf(a[r], sv[j], o[r][j]);
        }
    }
#pragma unroll
    for (int r = 0; r < 4; ++r) {
        const float ct = expf(logc_s[ti * 4 + r]);
#pragma unroll
        for (int j = 0; j < 8; ++j) o[r][j] *= ct;
    }

    for (int sh = 0; sh < 2; ++sh) {
        __syncthreads();
        {
            const int rr = tid >> 3;
            const int c0 = (tid & 7) * 16;
            const float4* vp = (const float4*)(vv + (size_t)(row0 + sh * 32 + rr) * 2048 + h * 128 + c0);
#pragma unroll
            for (int u = 0; u < 4; ++u) {
                const int cl = c0 + u * 4;
                *(float4*)(&Bf[rr * 132 + swz8(cl)]) = vp[u];
            }
        }
        __syncthreads();
#pragma unroll 2
        for (int sp = 0; sp < 32; ++sp) {
            const int s = sh * 32 + sp;
            float a[4];
#pragma unroll
            for (int r = 0; r < 4; ++r) a[r] = At[ti * 4 + r][s];
            float4 v0 = *(const float4*)(&Bf[sp * 132 + tj8sw]);
            float4 v1 = *(const float4*)(&Bf[sp * 132 + tj8sw + 4]);
            float vf[8] = {v0.x, v0.y, v0.z, v0.w, v1.x, v1.y, v1.z, v1.w};
#pragma unroll
            for (int r = 0; r < 4; ++r)
#pragma unroll
                for (int j = 0; j < 8; ++j)
                    o[r][j] = fmaf(a[r], vf[j], o[r][j]);
        }
    }

#pragma unroll
    for (int r = 0; r < 4; ++r) {
        float ss = 0.f;
#pragma unroll
        for (int j = 0; j < 8; ++j) ss = fmaf(o[r][j], o[r][j], ss);
        ss += __shfl_xor(ss, 1);
        ss += __shfl_xor(ss, 2);
        ss += __shfl_xor(ss, 4);
        ss += __shfl_xor(ss, 8);
        const float scale = rsqrtf(ss * (1.f / 128.f) + 1e-6f);
        const int t = ti * 4 + r;
        const float* zp = zbuf + (size_t)(row0 + t) * 2048 + h * 128 + tj * 8;
        unsigned short* gp = gated_b + (size_t)(row0 + t) * 2048 + h * 128 + tj * 8;
#pragma unroll
        for (int j = 0; j < 8; ++j) {
            float zv = zp[j];
            float g = o[r][j] * scale * norm_w[tj * 8 + j] * (1.f / (1.f + expf(-zv)));
            gp[j] = f2bf(g);
        }
    }
}

extern "C" void kernel_launch(void* const* d_in, const int* in_sizes, int n_in,
                              void* d_out, int out_size, void* d_ws, size_t ws_size,
                              hipStream_t stream) {
    (void)in_sizes; (void)n_in; (void)out_size; (void)ws_size;
    const float* x          = (const float*)d_in[0];
    const int*   input_pos  = (const int*)d_in[1];
    const float* W_qkvz     = (const float*)d_in[2];
    const float* W_b        = (const float*)d_in[3];
    const float* W_a        = (const float*)d_in[4];
    const float* conv_w     = (const float*)d_in[5];
    const float* norm_w     = (const float*)d_in[6];
    const float* W_out      = (const float*)d_in[7];
    const float* conv_state = (const float*)d_in[8];
    const float* rec_state  = (const float*)d_in[9];
    float* out = (float*)d_out;
    float* ws  = (float*)d_ws;

    // workspace (float elems), peak 232.75 MiB with phase-based aliasing:
    float* qkv   = ws;                                 // 25,165,824 f (phase 2-3)
    float* Mbuf  = ws;                                 // 16,777,216 f (phase 4+, aliases qkv)
    unsigned short* gated_b = (unsigned short*)(ws + 16777216); // bf16 (phase 5+)
    float* qn    = ws + 25165824ull;                   // 8,388,608 f (phase 3+)
    float* kn    = qn + 8388608ull;
    float* vv    = kn + 8388608ull;
    unsigned short* xb  = (unsigned short*)qn;         // phase 1-2, aliases qn
    unsigned short* WqT = (unsigned short*)(qn + 4194304ull); // 8192x2048 bf16
    float* zbuf  = vv + 8388608ull;
    unsigned short* WoT = (unsigned short*)(zbuf + 8388608ull);
    float* alpha = zbuf + 8388608ull + 2097152ull;
    float* beta  = alpha + 65536ull;
    float* logc  = beta + 65536ull;

    // 0. casts / transposes (bf16 operands for MFMA GEMMs)
    cast_bf16<<<8192, 256, 0, stream>>>(x, xb, 8388608L);
    transpose_cast<<<dim3(8192 / 32, 2048 / 32), 256, 0, stream>>>(W_qkvz, WqT, 2048, 8192);
    transpose_cast<<<dim3(2048 / 32, 2048 / 32), 256, 0, stream>>>(W_out, WoT, 2048, 2048);

    // 1. merged qkvz GEMM: cols<6144 -> qkv (ldc 6144), cols>=6144 -> zbuf
    gemm256<<<dim3(8192 / 256, Mrows / 256), 512, 0, stream>>>(
        xb, WqT, qkv, zbuf, 2048, 2048, 2048);
    // 2. alpha/beta (f32 — exp-cumsum sensitivity)
    ab_kernel<<<Mrows, 256, 0, stream>>>(x, W_b, W_a, beta, alpha);
    // 3. conv + silu + l2norm (last reader of qkv buffer)
    conv_kernel<<<dim3(Tt / 8, 48, Bb), 128, 0, stream>>>(
        qkv, conv_w, conv_state, input_pos, qn, kn, vv);
    // 4a. per-chunk prep: log-cumsum + M_c  (overwrites dead qkv region)
    chunk_prep<<<dim3(NCHUNK, Hh, Bb), 256, 0, stream>>>(
        kn, vv, alpha, beta, logc, Mbuf);
    // 4b. chunk-state recurrence, element-parallel (Mbuf -> Sstates in place)
    state_scan<<<2048, 256, 0, stream>>>(Mbuf, logc, rec_state, input_pos);
    // 4c. per-chunk outputs + RMSNorm + gate -> gated_b (bf16)
    chunk_out<<<dim3(NCHUNK, Hh, Bb), 256, 0, stream>>>(
        qn, kn, vv, beta, logc, Mbuf, norm_w, zbuf, gated_b);
    // 5. out = gated @ W_out   (MFMA bf16, 128^2 m97 structure)
    gemm_bf16<<<dim3(2048 / 128, Mrows / 128), 256, 0, stream>>>(
        gated_b, WoT, out, 2048, 2048, 2048, 2048);
}

// Round 8
// 534.800 us; speedup vs baseline: 11.2200x; 1.0438x over previous
//
#include <hip/hip_runtime.h>
#include <hip/hip_bf16.h>
#include <math.h>

#define Bb 2
#define Tt 2048
#define Cc 2048
#define Hh 16
#define CONVD 6144
#define Mrows 4096  // B*T
#define NCHUNK 32   // T / 64

typedef __attribute__((ext_vector_type(8))) short short8v;
typedef __attribute__((ext_vector_type(4))) float floatx4;

__device__ __forceinline__ unsigned short f2bf(float f) {
    __hip_bfloat16 h = __float2bfloat16(f);
    return __builtin_bit_cast(unsigned short, h);
}

__device__ __forceinline__ void load_lds16(const void* g, void* l) {
    __builtin_amdgcn_global_load_lds(
        (const __attribute__((address_space(1))) void*)g,
        (__attribute__((address_space(3))) void*)l, 16, 0, 0);
}

// col-swizzle for float LDS tiles with 128-col rows read as float4 at tj*8:
__device__ __forceinline__ int swz8(int col) {
    return col ^ (((col >> 5) & 3) << 3);
}

#define LGKM0 asm volatile("s_waitcnt lgkmcnt(0)" ::: "memory")
#define VMC4  asm volatile("s_waitcnt vmcnt(4)" ::: "memory")
#define VMC0  asm volatile("s_waitcnt vmcnt(0)" ::: "memory")
#define SCHB  __builtin_amdgcn_sched_barrier(0)
#define SBAR  __builtin_amdgcn_s_barrier()

// ------ merged transpose+cast: W1(2048x8192)->WT1, W2(2048x2048)->WT2 -------
__global__ __launch_bounds__(256) void transpose_cast2(
    const float* __restrict__ W1, unsigned short* __restrict__ WT1,
    const float* __restrict__ W2, unsigned short* __restrict__ WT2)
{
    const float* W; unsigned short* WT; int Nn;
    if (blockIdx.z == 0) { W = W1; WT = WT1; Nn = 8192; }
    else                 { W = W2; WT = WT2; Nn = 2048; if (blockIdx.x >= 64) return; }
    __shared__ float tile[32][33];
    const int n0 = blockIdx.x * 32;
    const int k0 = blockIdx.y * 32;
    const int tx = threadIdx.x & 31;
    const int ty = threadIdx.x >> 5;
#pragma unroll
    for (int r = ty; r < 32; r += 8)
        tile[r][tx] = W[(size_t)(k0 + r) * Nn + n0 + tx];
    __syncthreads();
#pragma unroll
    for (int r = ty; r < 32; r += 8)
        WT[(size_t)(n0 + r) * 2048 + k0 + tx] = f2bf(tile[tx][r]);
}

// ======== 256x256 bf16 MFMA GEMM, counted-vmcnt pipeline (T2+T4+T5) =========
// C = A(MxK bf16) @ Bt(NxK bf16)^T. 8 waves (2Mx4N), BK=32, LDS 64KB dbuf.
// Split C-write: cols < 6144 -> C1 (ldc 6144), cols >= 6144 -> C2 (ldc 2048).
// Grid FIXED at (32,16). XCD remap: each XCD owns an 8x8 block super-chunk
// (64 blocks, all co-resident at 2 blk/CU x 32 CU) -> per-XCD L2 footprint
// 8MB A-panel + 8MB B-panel instead of the full 32MB B matrix.
__global__ __launch_bounds__(512) void gemm256(
    const unsigned short* __restrict__ A, const unsigned short* __restrict__ Bt,
    float* __restrict__ C1, float* __restrict__ C2,
    int Kk, int lda, int ldb)
{
    __shared__ __align__(16) unsigned short A_lds[2][256 * 32];
    __shared__ __align__(16) unsigned short B_lds[2][256 * 32];

    const int tid  = threadIdx.x;
    const int wid  = tid >> 6;            // 0..7
    const int lane = tid & 63;
    const int wr = wid >> 2, wc = wid & 3;
    const int l15 = lane & 15, kq = lane >> 4;
    const int rdsw = (kq ^ ((l15 >> 1) & 3)) * 8;    // read-side swizzled chunk
    const int rr = lane >> 2;                        // staging row in 16-group
    const int ch = (lane & 3) ^ ((lane >> 3) & 3);   // staging swizzled chunk

    // 8x8 super-chunk per XCD (grid 32x16, 512 blocks, bijective)
    const int bid = blockIdx.y * 32 + blockIdx.x;    // 0..511
    const int xcd = bid & 7;
    const int idx = bid >> 3;                        // 0..63
    const int block_m = ((xcd >> 2) * 8 + (idx >> 3)) * 256;   // 2 chunk-rows
    const int block_n = ((xcd & 3) * 8 + (idx & 7)) * 256;     // 4 chunk-cols

    const int NT = Kk >> 5;

#define STAGE256(t) do {                                                     \
    const int kk0 = (t) << 5;                                                \
    unsigned short* la = &A_lds[(t) & 1][0];                                 \
    unsigned short* lb = &B_lds[(t) & 1][0];                                 \
    _Pragma("unroll")                                                        \
    for (int i_ = 0; i_ < 2; ++i_) {                                         \
        const int g_ = wid * 2 + i_;                                         \
        load_lds16(A + (size_t)(block_m + g_ * 16 + rr) * lda + kk0 + ch * 8,\
                   la + g_ * 512);                                           \
        load_lds16(Bt + (size_t)(block_n + g_ * 16 + rr) * ldb + kk0 + ch * 8,\
                   lb + g_ * 512);                                           \
    }                                                                        \
} while (0)

    floatx4 acc[8][4] = {};

    STAGE256(0);
    STAGE256(1);
    VMC4; SCHB; SBAR; SCHB;

    for (int t = 0; t < NT; ++t) {
        const unsigned short* la = &A_lds[t & 1][0];
        const unsigned short* lb = &B_lds[t & 1][0];
        short8v af[8], bf[4];
#pragma unroll
        for (int mf = 0; mf < 8; ++mf)
            af[mf] = *(const short8v*)(la + (wr * 128 + mf * 16 + l15) * 32 + rdsw);
#pragma unroll
        for (int nf = 0; nf < 4; ++nf)
            bf[nf] = *(const short8v*)(lb + (wc * 64 + nf * 16 + l15) * 32 + rdsw);
        LGKM0; SCHB;
        SBAR;                       // all waves done reading buf[t&1]
        SCHB;
        if (t + 2 < NT) STAGE256(t + 2);
        SCHB;
        __builtin_amdgcn_s_setprio(1);
#pragma unroll
        for (int mf = 0; mf < 8; ++mf)
#pragma unroll
            for (int nf = 0; nf < 4; ++nf)
                acc[mf][nf] = __builtin_amdgcn_mfma_f32_16x16x32_bf16(
                    af[mf], bf[nf], acc[mf][nf], 0, 0, 0);
        __builtin_amdgcn_s_setprio(0);
        SCHB;
        if (t + 2 < NT)      { VMC4; }   // t+1's loads landed; t+2's in flight
        else if (t + 1 < NT) { VMC0; }   // epilogue drain
        SCHB; SBAR; SCHB;
    }

    // C-write, split per block column (uniform per block)
    float* Cp; int col0; size_t ldc;
    if (block_n < 6144) { Cp = C1; col0 = block_n;        ldc = 6144; }
    else                { Cp = C2; col0 = block_n - 6144; ldc = 2048; }
#pragma unroll
    for (int mf = 0; mf < 8; ++mf)
#pragma unroll
        for (int nf = 0; nf < 4; ++nf)
#pragma unroll
            for (int r = 0; r < 4; ++r) {
                int row = block_m + wr * 128 + mf * 16 + kq * 4 + r;
                int col = col0 + wc * 64 + nf * 16 + l15;
                Cp[(size_t)row * ldc + col] = acc[mf][nf][r];
            }
#undef STAGE256
}

// ---- 128x128 bf16 MFMA GEMM (m97 structure) for the output projection ------
__global__ __launch_bounds__(256) void gemm_bf16(
    const unsigned short* __restrict__ A, const unsigned short* __restrict__ Bt,
    float* __restrict__ C, int Kk, int lda, int ldb, int ldc)
{
    __shared__ __align__(16) unsigned short A_lds[128 * 64];
    __shared__ __align__(16) unsigned short B_lds[128 * 64];

    const int tid = threadIdx.x;
    const int wv = tid >> 6;
    const int lane = tid & 63;
    const int wr = wv >> 1, wc = wv & 1;
    const int l15 = lane & 15, kq = lane >> 4;
    const int rsw = (l15 & 7) << 3;

    // m204 bijective XCD chunking (nwg % 8 == 0): per-XCD contiguous tile range
    const int nwg = gridDim.x * gridDim.y;
    const int bid = blockIdx.y * gridDim.x + blockIdx.x;
    const int wgid = (bid & 7) * (nwg >> 3) + (bid >> 3);
    const int block_m = (wgid / gridDim.x) * 128;
    const int block_n = (wgid % gridDim.x) * 128;

    const int srow = lane >> 3;
    const int scol = ((lane & 7) ^ srow) << 3;

    floatx4 acc[4][4] = {};

    for (int k0 = 0; k0 < Kk; k0 += 64) {
#pragma unroll
        for (int i = 0; i < 4; ++i) {
            const int lq = wv * 4 + i;
            const unsigned short* asrc =
                A + (size_t)(block_m + lq * 8 + srow) * lda + k0 + scol;
            load_lds16(asrc, &A_lds[lq * 512]);
            const unsigned short* bsrc =
                Bt + (size_t)(block_n + lq * 8 + srow) * ldb + k0 + scol;
            load_lds16(bsrc, &B_lds[lq * 512]);
        }
        __syncthreads();

#pragma unroll
        for (int kk = 0; kk < 2; ++kk) {
            short8v af[4], bf[4];
#pragma unroll
            for (int mf = 0; mf < 4; ++mf) {
                const int row = wr * 64 + mf * 16 + l15;
                af[mf] = *(const short8v*)&A_lds[row * 64 + ((kk * 32 + kq * 8) ^ rsw)];
            }
#pragma unroll
            for (int nf = 0; nf < 4; ++nf) {
                const int row = wc * 64 + nf * 16 + l15;
                bf[nf] = *(const short8v*)&B_lds[row * 64 + ((kk * 32 + kq * 8) ^ rsw)];
            }
#pragma unroll
            for (int mf = 0; mf < 4; ++mf)
#pragma unroll
                for (int nf = 0; nf < 4; ++nf)
                    acc[mf][nf] = __builtin_amdgcn_mfma_f32_16x16x32_bf16(
                        af[mf], bf[nf], acc[mf][nf], 0, 0, 0);
        }
        __syncthreads();
    }

#pragma unroll
    for (int mf = 0; mf < 4; ++mf)
#pragma unroll
        for (int nf = 0; nf < 4; ++nf)
#pragma unroll
            for (int r = 0; r < 4; ++r) {
                int row = block_m + wr * 64 + mf * 16 + kq * 4 + r;
                int col = block_n + wc * 64 + nf * 16 + l15;
                C[(size_t)row * ldc + col] = acc[mf][nf][r];
            }
}

// -------- alpha/beta: sigmoid(x @ W_{a,b}) + bf16 cast of x (fused) ---------
__global__ __launch_bounds__(256) void ab_kernel(
    const float* __restrict__ x, const float* __restrict__ W_b,
    const float* __restrict__ W_a, float* __restrict__ beta,
    float* __restrict__ alpha, unsigned short* __restrict__ xb)
{
    const int row = blockIdx.x;
    const int tid = threadIdx.x;
    float acc[32];
#pragma unroll
    for (int u = 0; u < 32; ++u) acc[u] = 0.f;

    for (int k = tid; k < Cc; k += 256) {
        float xv = x[(size_t)row * Cc + k];
        xb[(size_t)row * Cc + k] = f2bf(xv);
        const float4* wb = (const float4*)(W_b + (size_t)k * 16);
        const float4* wa = (const float4*)(W_a + (size_t)k * 16);
#pragma unroll
        for (int u = 0; u < 4; ++u) {
            float4 b4 = wb[u];
            float4 a4 = wa[u];
            acc[u * 4 + 0] = fmaf(xv, b4.x, acc[u * 4 + 0]);
            acc[u * 4 + 1] = fmaf(xv, b4.y, acc[u * 4 + 1]);
            acc[u * 4 + 2] = fmaf(xv, b4.z, acc[u * 4 + 2]);
            acc[u * 4 + 3] = fmaf(xv, b4.w, acc[u * 4 + 3]);
            acc[16 + u * 4 + 0] = fmaf(xv, a4.x, acc[16 + u * 4 + 0]);
            acc[16 + u * 4 + 1] = fmaf(xv, a4.y, acc[16 + u * 4 + 1]);
            acc[16 + u * 4 + 2] = fmaf(xv, a4.z, acc[16 + u * 4 + 2]);
            acc[16 + u * 4 + 3] = fmaf(xv, a4.w, acc[16 + u * 4 + 3]);
        }
    }
#pragma unroll
    for (int u = 0; u < 32; ++u) {
        float v = acc[u];
        for (int off = 32; off > 0; off >>= 1) v += __shfl_down(v, off);
        acc[u] = v;
    }
    __shared__ float red[4][32];
    const int wv = tid >> 6;
    if ((tid & 63) == 0) {
#pragma unroll
        for (int u = 0; u < 32; ++u) red[wv][u] = acc[u];
    }
    __syncthreads();
    if (tid < 32) {
        float v = red[0][tid] + red[1][tid] + red[2][tid] + red[3][tid];
        float s = 1.f / (1.f + expf(-v));
        if (tid < 16) beta[(size_t)row * 16 + tid] = s;
        else          alpha[(size_t)row * 16 + (tid - 16)] = s;
    }
}

// ------ conv(K=4) + SiLU + split + l2norm(q,k), 16 timesteps per block ------
__global__ __launch_bounds__(128) void conv_kernel(
    const float* __restrict__ qkv, const float* __restrict__ conv_w,
    const float* __restrict__ conv_state, const int* __restrict__ input_pos,
    float* __restrict__ qn, float* __restrict__ kn, float* __restrict__ vv)
{
    const int tc = blockIdx.x;       // 0..127
    const int hs = blockIdx.y;       // 0..47
    const int b  = blockIdx.z;
    const int lane = threadIdx.x;
    const int kind = hs >> 4;
    const int h = hs & 15;
    const int c = kind * 2048 + h * 128 + lane;
    const int t0 = tc * 16;
    const float keep = (input_pos[0] == 0) ? 0.f : 1.f;

    const float4 w4 = *(const float4*)(conv_w + (size_t)c * 4);

    float win0, win1, win2;
    {
        float tmp[3];
#pragma unroll
        for (int j = 0; j < 3; ++j) {
            int tau = t0 - 3 + j;
            tmp[j] = (tau >= 0) ? qkv[(size_t)(b * Tt + tau) * CONVD + c]
                   : keep * conv_state[((size_t)b * CONVD + c) * 4 + (tau + 4)];
        }
        win0 = tmp[0]; win1 = tmp[1]; win2 = tmp[2];
    }

    float y[16];
    __shared__ float red[16][2];
#pragma unroll
    for (int i = 0; i < 16; ++i) {
        float xv = qkv[(size_t)(b * Tt + t0 + i) * CONVD + c];
        float a = fmaf(w4.x, win0, fmaf(w4.y, win1, fmaf(w4.z, win2, w4.w * xv)));
        float yy = a / (1.f + expf(-a));
        win0 = win1; win1 = win2; win2 = xv;
        if (kind == 2) {
            vv[(size_t)(b * Tt + t0 + i) * 2048 + h * 128 + lane] = yy;
        } else {
            float sq = yy * yy;
            for (int off = 32; off > 0; off >>= 1) sq += __shfl_down(sq, off);
            if ((lane & 63) == 0) red[i][lane >> 6] = sq;
            y[i] = yy;
        }
    }
    if (kind == 2) return;
    __syncthreads();
#pragma unroll
    for (int i = 0; i < 16; ++i) {
        float tot = red[i][0] + red[i][1];
        float inv = 1.f / fmaxf(sqrtf(tot), 1e-12f);
        float outv = y[i] * inv;
        const size_t oidx = (size_t)(b * Tt + t0 + i) * 2048 + h * 128 + lane;
        if (kind == 0) qn[oidx] = outv;
        else           kn[oidx] = outv;
    }
}

// ================= chunked scan, stage A: per-chunk prep =====================
__global__ __launch_bounds__(256) void chunk_prep(
    const float* __restrict__ kn, const float* __restrict__ vv,
    const float* __restrict__ alpha, const float* __restrict__ beta,
    float* __restrict__ logc_g, float* __restrict__ Mbuf)
{
    const int c = blockIdx.x, h = blockIdx.y, b = blockIdx.z;
    const int tid = threadIdx.x;
    const size_t bh = (size_t)b * Hh + h;

    __shared__ float K_lds[32][128];
    __shared__ float V_lds[32][128];
    __shared__ float logc_lds[64];
    __shared__ float b_lds[64];
    __shared__ float wk_lds[64];

    if (tid < 64) {
        const int row = b * Tt + c * 64 + tid;
        float a = alpha[(size_t)row * 16 + h];
        float la = logf(a);
#pragma unroll
        for (int d = 1; d < 64; d <<= 1) {
            float n = __shfl_up(la, d);
            if (tid >= d) la += n;
        }
        logc_lds[tid] = la;
        logc_g[bh * Tt + c * 64 + tid] = la;
        b_lds[tid] = beta[(size_t)row * 16 + h];
    }
    __syncthreads();
    if (tid < 64) {
        wk_lds[tid] = expf(logc_lds[63] - logc_lds[tid]) * b_lds[tid];
    }
    __syncthreads();

    const int ti = tid >> 4;
    const int tj = tid & 15;
    const int tj8sw = swz8(tj * 8);
    float acc[8][8];
#pragma unroll
    for (int i = 0; i < 8; ++i)
#pragma unroll
        for (int j = 0; j < 8; ++j) acc[i][j] = 0.f;

    for (int half = 0; half < 2; ++half) {
        {
            const int sl = tid >> 3;
            const int c0 = (tid & 7) * 16;
            const int grow = b * Tt + c * 64 + half * 32 + sl;
            const float4* kp = (const float4*)(kn + (size_t)grow * 2048 + h * 128 + c0);
            const float4* vp = (const float4*)(vv + (size_t)grow * 2048 + h * 128 + c0);
#pragma unroll
            for (int u = 0; u < 4; ++u) {
                const int cl = c0 + u * 4;
                *(float4*)(&K_lds[sl][cl]) = kp[u];
                *(float4*)(&V_lds[sl][swz8(cl)]) = vp[u];
            }
        }
        __syncthreads();
#pragma unroll 4
        for (int s = 0; s < 32; ++s) {
            float w = wk_lds[half * 32 + s];
            float4 k0 = *(const float4*)(&K_lds[s][ti * 8]);
            float4 k1 = *(const float4*)(&K_lds[s][ti * 8 + 4]);
            float4 v0 = *(const float4*)(&V_lds[s][tj8sw]);
            float4 v1 = *(const float4*)(&V_lds[s][tj8sw + 4]);
            float wk[8] = {w*k0.x, w*k0.y, w*k0.z, w*k0.w, w*k1.x, w*k1.y, w*k1.z, w*k1.w};
            float vf[8] = {v0.x, v0.y, v0.z, v0.w, v1.x, v1.y, v1.z, v1.w};
#pragma unroll
            for (int i = 0; i < 8; ++i)
#pragma unroll
                for (int j = 0; j < 8; ++j)
                    acc[i][j] = fmaf(wk[i], vf[j], acc[i][j]);
        }
        __syncthreads();
    }
    float* mb = Mbuf + ((bh * NCHUNK) + c) * 16384;
#pragma unroll
    for (int i = 0; i < 8; ++i) {
        float4 o0 = {acc[i][0], acc[i][1], acc[i][2], acc[i][3]};
        float4 o1 = {acc[i][4], acc[i][5], acc[i][6], acc[i][7]};
        *(float4*)(mb + (size_t)(ti * 8 + i) * 128 + tj * 8) = o0;
        *(float4*)(mb + (size_t)(ti * 8 + i) * 128 + tj * 8 + 4) = o1;
    }
}

// ================= chunked scan, stage B: state recurrence ==================
__global__ __launch_bounds__(256) void state_scan(
    float* __restrict__ Mbuf, const float* __restrict__ logc_g,
    const float* __restrict__ rec_state, const int* __restrict__ input_pos)
{
    const size_t g = (size_t)blockIdx.x * 256 + threadIdx.x;
    const int bh = (int)(g >> 14);
    const float keep = (input_pos[0] == 0) ? 0.f : 1.f;

    float S = keep * rec_state[g];
    const float* lc = logc_g + (size_t)bh * Tt;
    float* base = Mbuf + (size_t)(g & ~16383ull) * NCHUNK + (g & 16383);
#pragma unroll 4
    for (int c = 0; c < NCHUNK; ++c) {
        float Atot = expf(lc[c * 64 + 63]);
        float m = base[(size_t)c * 16384];
        base[(size_t)c * 16384] = S;
        S = fmaf(Atot, S, m);
    }
}

// ================= chunked scan, stage C: per-chunk output ==================
__global__ __launch_bounds__(256) void chunk_out(
    const float* __restrict__ qn, const float* __restrict__ kn,
    const float* __restrict__ vv, const float* __restrict__ beta,
    const float* __restrict__ logc_g, const float* __restrict__ Sstates,
    const float* __restrict__ norm_w, const float* __restrict__ zbuf,
    unsigned short* __restrict__ gated_b)
{
    const int c = blockIdx.x, h = blockIdx.y, b = blockIdx.z;
    const int tid = threadIdx.x;
    const int ti = tid >> 4;
    const int tj = tid & 15;
    const size_t bh = (size_t)b * Hh + h;
    const int row0 = b * Tt + c * 64;

    __shared__ float Q_lds[64][132];
    __shared__ float Bf[64 * 68];
    __shared__ float At[64][68];
    __shared__ float logc_s[64], b_s[64];

    {
        const int r = tid >> 2, c0 = (tid & 3) * 32;
        const float4* qp = (const float4*)(qn + (size_t)(row0 + r) * 2048 + h * 128 + c0);
#pragma unroll
        for (int u = 0; u < 8; ++u)
            *(float4*)(&Q_lds[r][c0 + u * 4]) = qp[u];
    }
    if (tid < 64) {
        logc_s[tid] = logc_g[bh * Tt + c * 64 + tid];
        b_s[tid] = beta[(size_t)(row0 + tid) * 16 + h];
    }

    float acc_a[4][4] = {};
    for (int kh = 0; kh < 2; ++kh) {
        __syncthreads();
        {
            const int s = tid >> 2, c0 = (tid & 3) * 16;
            const float* kp = kn + (size_t)(row0 + s) * 2048 + h * 128 + kh * 64 + c0;
#pragma unroll
            for (int u = 0; u < 16; ++u)
                Bf[(c0 + u) * 68 + s] = kp[u];
        }
        __syncthreads();
#pragma unroll 4
        for (int kk = 0; kk < 64; ++kk) {
            float a[4];
#pragma unroll
            for (int r = 0; r < 4; ++r) a[r] = Q_lds[ti * 4 + r][kh * 64 + kk];
            float4 bq = *(const float4*)(&Bf[kk * 68 + tj * 4]);
            float bb[4] = {bq.x, bq.y, bq.z, bq.w};
#pragma unroll
            for (int r = 0; r < 4; ++r)
#pragma unroll
                for (int cc = 0; cc < 4; ++cc)
                    acc_a[r][cc] = fmaf(a[r], bb[cc], acc_a[r][cc]);
        }
    }

#pragma unroll
    for (int r = 0; r < 4; ++r) {
        const int t = ti * 4 + r;
        const float lct = logc_s[t];
#pragma unroll
        for (int cc = 0; cc < 4; ++cc) {
            const int s = tj * 4 + cc;
            float w = (s <= t) ? expf(lct - logc_s[s]) * b_s[s] : 0.f;
            At[t][s] = w * acc_a[r][cc];
        }
    }

    float o[4][8] = {};
    const float* Sbase = Sstates + (bh * NCHUNK + c) * 16384;
    const int tj8sw = swz8(tj * 8);
    for (int kb = 0; kb < 8; ++kb) {
        __syncthreads();
        {
            const int rr = tid >> 4;
            const int cl = (tid & 15) * 8;
            const int sw = swz8(cl);
            const float4* sp = (const float4*)(Sbase + (size_t)(kb * 16 + rr) * 128 + cl);
            *(float4*)(&Bf[rr * 132 + sw]) = sp[0];
            *(float4*)(&Bf[rr * 132 + sw + 4]) = sp[1];
        }
        __syncthreads();
#pragma unroll
        for (int kk = 0; kk < 16; ++kk) {
            float a[4];
#pragma unroll
            for (int r = 0; r < 4; ++r) a[r] = Q_lds[ti * 4 + r][kb * 16 + kk];
            float4 s0 = *(const float4*)(&Bf[kk * 132 + tj8sw]);
            float4 s1 = *(const float4*)(&Bf[kk * 132 + tj8sw + 4]);
            float sv[8] = {s0.x, s0.y, s0.z, s0.w, s1.x, s1.y, s1.z, s1.w};
#pragma unroll
            for (int r = 0; r < 4; ++r)
#pragma unroll
                for (int j = 0; j < 8; ++j)
                    o[r][j] = fmaf(a[r], sv[j], o[r][j]);
        }
    }
#pragma unroll
    for (int r = 0; r < 4; ++r) {
        const float ct = expf(logc_s[ti * 4 + r]);
#pragma unroll
        for (int j = 0; j < 8; ++j) o[r][j] *= ct;
    }

    for (int sh = 0; sh < 2; ++sh) {
        __syncthreads();
        {
            const int rr = tid >> 3;
            const int c0 = (tid & 7) * 16;
            const float4* vp = (const float4*)(vv + (size_t)(row0 + sh * 32 + rr) * 2048 + h * 128 + c0);
#pragma unroll
            for (int u = 0; u < 4; ++u) {
                const int cl = c0 + u * 4;
                *(float4*)(&Bf[rr * 132 + swz8(cl)]) = vp[u];
            }
        }
        __syncthreads();
#pragma unroll 2
        for (int sp = 0; sp < 32; ++sp) {
            const int s = sh * 32 + sp;
            float a[4];
#pragma unroll
            for (int r = 0; r < 4; ++r) a[r] = At[ti * 4 + r][s];
            float4 v0 = *(const float4*)(&Bf[sp * 132 + tj8sw]);
            float4 v1 = *(const float4*)(&Bf[sp * 132 + tj8sw + 4]);
            float vf[8] = {v0.x, v0.y, v0.z, v0.w, v1.x, v1.y, v1.z, v1.w};
#pragma unroll
            for (int r = 0; r < 4; ++r)
#pragma unroll
                for (int j = 0; j < 8; ++j)
                    o[r][j] = fmaf(a[r], vf[j], o[r][j]);
        }
    }

#pragma unroll
    for (int r = 0; r < 4; ++r) {
        float ss = 0.f;
#pragma unroll
        for (int j = 0; j < 8; ++j) ss = fmaf(o[r][j], o[r][j], ss);
        ss += __shfl_xor(ss, 1);
        ss += __shfl_xor(ss, 2);
        ss += __shfl_xor(ss, 4);
        ss += __shfl_xor(ss, 8);
        const float scale = rsqrtf(ss * (1.f / 128.f) + 1e-6f);
        const int t = ti * 4 + r;
        const float* zp = zbuf + (size_t)(row0 + t) * 2048 + h * 128 + tj * 8;
        unsigned short* gp = gated_b + (size_t)(row0 + t) * 2048 + h * 128 + tj * 8;
#pragma unroll
        for (int j = 0; j < 8; ++j) {
            float zv = zp[j];
            float g = o[r][j] * scale * norm_w[tj * 8 + j] * (1.f / (1.f + expf(-zv)));
            gp[j] = f2bf(g);
        }
    }
}

extern "C" void kernel_launch(void* const* d_in, const int* in_sizes, int n_in,
                              void* d_out, int out_size, void* d_ws, size_t ws_size,
                              hipStream_t stream) {
    (void)in_sizes; (void)n_in; (void)out_size; (void)ws_size;
    const float* x          = (const float*)d_in[0];
    const int*   input_pos  = (const int*)d_in[1];
    const float* W_qkvz     = (const float*)d_in[2];
    const float* W_b        = (const float*)d_in[3];
    const float* W_a        = (const float*)d_in[4];
    const float* conv_w     = (const float*)d_in[5];
    const float* norm_w     = (const float*)d_in[6];
    const float* W_out      = (const float*)d_in[7];
    const float* conv_state = (const float*)d_in[8];
    const float* rec_state  = (const float*)d_in[9];
    float* out = (float*)d_out;
    float* ws  = (float*)d_ws;

    // workspace (float elems), peak 232.75 MiB with phase-based aliasing:
    float* qkv   = ws;                                 // 25,165,824 f (phase 2-3)
    float* Mbuf  = ws;                                 // 16,777,216 f (phase 4+, aliases qkv)
    unsigned short* gated_b = (unsigned short*)(ws + 16777216); // bf16 (phase 5+)
    float* qn    = ws + 25165824ull;                   // 8,388,608 f (phase 3+)
    float* kn    = qn + 8388608ull;
    float* vv    = kn + 8388608ull;
    unsigned short* xb  = (unsigned short*)qn;         // phase 1-2, aliases qn
    unsigned short* WqT = (unsigned short*)(qn + 4194304ull); // 8192x2048 bf16
    float* zbuf  = vv + 8388608ull;
    unsigned short* WoT = (unsigned short*)(zbuf + 8388608ull);
    float* alpha = zbuf + 8388608ull + 2097152ull;
    float* beta  = alpha + 65536ull;
    float* logc  = beta + 65536ull;

    // 0. weight transposes (merged) + alpha/beta (also emits xb = bf16(x))
    transpose_cast2<<<dim3(256, 64, 2), 256, 0, stream>>>(W_qkvz, WqT, W_out, WoT);
    ab_kernel<<<Mrows, 256, 0, stream>>>(x, W_b, W_a, beta, alpha, xb);

    // 1. merged qkvz GEMM: cols<6144 -> qkv (ldc 6144), cols>=6144 -> zbuf
    gemm256<<<dim3(8192 / 256, Mrows / 256), 512, 0, stream>>>(
        xb, WqT, qkv, zbuf, 2048, 2048, 2048);
    // 3. conv + silu + l2norm (last reader of qkv buffer)
    conv_kernel<<<dim3(Tt / 16, 48, Bb), 128, 0, stream>>>(
        qkv, conv_w, conv_state, input_pos, qn, kn, vv);
    // 4a. per-chunk prep: log-cumsum + M_c  (overwrites dead qkv region)
    chunk_prep<<<dim3(NCHUNK, Hh, Bb), 256, 0, stream>>>(
        kn, vv, alpha, beta, logc, Mbuf);
    // 4b. chunk-state recurrence, element-parallel (Mbuf -> Sstates in place)
    state_scan<<<2048, 256, 0, stream>>>(Mbuf, logc, rec_state, input_pos);
    // 4c. per-chunk outputs + RMSNorm + gate -> gated_b (bf16)
    chunk_out<<<dim3(NCHUNK, Hh, Bb), 256, 0, stream>>>(
        qn, kn, vv, beta, logc, Mbuf, norm_w, zbuf, gated_b);
    // 5. out = gated @ W_out   (MFMA bf16, 128^2 m97 structure, XCD-chunked)
    gemm_bf16<<<dim3(2048 / 128, Mrows / 128), 256, 0, stream>>>(
        gated_b, WoT, out, 2048, 2048, 2048, 2048);
}

// Round 9
// 533.012 us; speedup vs baseline: 11.2577x; 1.0034x over previous
//
#include <hip/hip_runtime.h>
#include <hip/hip_bf16.h>
#include <math.h>

#define Bb 2
#define Tt 2048
#define Cc 2048
#define Hh 16
#define CONVD 6144
#define Mrows 4096  // B*T
#define NCHUNK 32   // T / 64

typedef __attribute__((ext_vector_type(8))) short short8v;
typedef __attribute__((ext_vector_type(4))) float floatx4;

__device__ __forceinline__ unsigned short f2bf(float f) {
    __hip_bfloat16 h = __float2bfloat16(f);
    return __builtin_bit_cast(unsigned short, h);
}

__device__ __forceinline__ void load_lds16(const void* g, void* l) {
    __builtin_amdgcn_global_load_lds(
        (const __attribute__((address_space(1))) void*)g,
        (__attribute__((address_space(3))) void*)l, 16, 0, 0);
}

// col-swizzle for float LDS tiles with 128-col rows read as float4 at tj*8:
__device__ __forceinline__ int swz8(int col) {
    return col ^ (((col >> 5) & 3) << 3);
}

#define LGKM0 asm volatile("s_waitcnt lgkmcnt(0)" ::: "memory")
#define VMC0  asm volatile("s_waitcnt vmcnt(0)" ::: "memory")
#define SCHB  __builtin_amdgcn_sched_barrier(0)
#define SBAR  __builtin_amdgcn_s_barrier()

// ------ merged transpose+cast: W1(2048x8192)->WT1, W2(2048x2048)->WT2 -------
__global__ __launch_bounds__(256) void transpose_cast2(
    const float* __restrict__ W1, unsigned short* __restrict__ WT1,
    const float* __restrict__ W2, unsigned short* __restrict__ WT2)
{
    const float* W; unsigned short* WT; int Nn;
    if (blockIdx.z == 0) { W = W1; WT = WT1; Nn = 8192; }
    else                 { W = W2; WT = WT2; Nn = 2048; if (blockIdx.x >= 64) return; }
    __shared__ float tile[32][33];
    const int n0 = blockIdx.x * 32;
    const int k0 = blockIdx.y * 32;
    const int tx = threadIdx.x & 31;
    const int ty = threadIdx.x >> 5;
#pragma unroll
    for (int r = ty; r < 32; r += 8)
        tile[r][tx] = W[(size_t)(k0 + r) * Nn + n0 + tx];
    __syncthreads();
#pragma unroll
    for (int r = ty; r < 32; r += 8)
        WT[(size_t)(n0 + r) * 2048 + k0 + tx] = f2bf(tile[tx][r]);
}

// ---- stage one 16KB half-tile (128 rows x 64 k bf16) via 2 global_load_lds.
// LDS linear dest, XOR-pre-swizzled global source (rule #21).
__device__ __forceinline__ void stage_ht(
    const unsigned short* __restrict__ G, unsigned short* lds_buf,
    int ld, int k0, int h, int wid, int lane)
{
#pragma unroll
    for (int j = 0; j < 2; ++j) {
        const int base_row = h * 128 + j * 64 + wid * 8;
        const int row = base_row + (lane >> 3);
        const int ch = (lane & 7) ^ (lane >> 3);
        load_lds16(G + (size_t)row * ld + k0 + ch * 8, lds_buf + base_row * 64);
    }
}

// fragment read with matching XOR swizzle: G-chunk g (16B) of row R
__device__ __forceinline__ short8v frag(const unsigned short* lds_buf, int R, int g) {
    return *(const short8v*)(lds_buf + R * 64 + ((g ^ (R & 7)) << 3));
}

// ======== 256x256 bf16 MFMA GEMM, fine-phase schedule (T2+T3+T4+T5) =========
// C = A(MxK bf16) @ Bt(NxK bf16)^T. 8 waves (2Mx4N), BK=64, LDS 128KB dbuf.
// 4 phases per K-tile, phase=(m-half,k-sub): 8 ds_read_b128 + 16 MFMA each,
// per-phase double barrier (m201 pattern). Tile t+1 staged into the DEAD
// buffer (freed at t-1 end) during phases 0/1; vmcnt(0) once per tile at ph3
// (youngest load ~2.5 phases old). Split C-write: cols<6144 -> C1 else C2.
__global__ __launch_bounds__(512) void gemm256(
    const unsigned short* __restrict__ A, const unsigned short* __restrict__ Bt,
    float* __restrict__ C1, float* __restrict__ C2,
    int Kk, int lda, int ldb)
{
    __shared__ __align__(16) unsigned short A_lds[2][256 * 64];
    __shared__ __align__(16) unsigned short B_lds[2][256 * 64];

    const int tid  = threadIdx.x;
    const int wid  = tid >> 6;            // 0..7
    const int lane = tid & 63;
    const int wr = wid >> 2, wc = wid & 3;
    const int l15 = lane & 15, kq = lane >> 4;

    // 8x8 super-chunk per XCD (grid 32x16, 512 blocks, bijective)
    const int bid = blockIdx.y * 32 + blockIdx.x;    // 0..511
    const int xcd = bid & 7;
    const int idx = bid >> 3;                        // 0..63
    const int block_m = ((xcd >> 2) * 8 + (idx >> 3)) * 256;
    const int block_n = ((xcd & 3) * 8 + (idx & 7)) * 256;

    const unsigned short* Ag = A + (size_t)block_m * lda;
    const unsigned short* Bg = Bt + (size_t)block_n * ldb;

    const int NT = Kk >> 6;               // K-tiles of 64

    floatx4 acc[8][4] = {};

    // prologue: stage tile 0 into buf 0 (8 loads), drain, sync
    stage_ht(Ag, &A_lds[0][0], lda, 0, 0, wid, lane);
    stage_ht(Ag, &A_lds[0][0], lda, 0, 1, wid, lane);
    stage_ht(Bg, &B_lds[0][0], ldb, 0, 0, wid, lane);
    stage_ht(Bg, &B_lds[0][0], ldb, 0, 1, wid, lane);
    VMC0; SCHB; SBAR;

#define PHASE(mh, ks, STAGECODE, VMCODE) do {                                 \
    short8v af[4], bf[4];                                                     \
    _Pragma("unroll")                                                         \
    for (int m4 = 0; m4 < 4; ++m4)                                            \
        af[m4] = frag(la, wr * 128 + ((mh) * 4 + m4) * 16 + l15, (ks) * 4 + kq); \
    _Pragma("unroll")                                                         \
    for (int nf = 0; nf < 4; ++nf)                                            \
        bf[nf] = frag(lb, wc * 64 + nf * 16 + l15, (ks) * 4 + kq);            \
    STAGECODE;                                                                \
    SBAR;                                                                     \
    LGKM0; SCHB;                                                              \
    __builtin_amdgcn_s_setprio(1);                                            \
    _Pragma("unroll")                                                         \
    for (int m4 = 0; m4 < 4; ++m4)                                            \
        _Pragma("unroll")                                                     \
        for (int nf = 0; nf < 4; ++nf)                                        \
            acc[(mh) * 4 + m4][nf] = __builtin_amdgcn_mfma_f32_16x16x32_bf16( \
                af[m4], bf[nf], acc[(mh) * 4 + m4][nf], 0, 0, 0);             \
    __builtin_amdgcn_s_setprio(0);                                            \
    SCHB;                                                                     \
    VMCODE;                                                                   \
    SBAR;                                                                     \
} while (0)

    for (int t = 0; t < NT; ++t) {
        const unsigned short* la = &A_lds[t & 1][0];
        const unsigned short* lb = &B_lds[t & 1][0];
        unsigned short* sa = &A_lds[(t + 1) & 1][0];
        unsigned short* sb = &B_lds[(t + 1) & 1][0];
        const int k0n = (t + 1) << 6;
        const bool more = (t + 1 < NT);

        PHASE(0, 0,
              { if (more) { stage_ht(Ag, sa, lda, k0n, 0, wid, lane);
                            stage_ht(Ag, sa, lda, k0n, 1, wid, lane); } },
              {});
        PHASE(1, 0,
              { if (more) { stage_ht(Bg, sb, ldb, k0n, 0, wid, lane);
                            stage_ht(Bg, sb, ldb, k0n, 1, wid, lane); } },
              {});
        PHASE(0, 1, {}, {});
        PHASE(1, 1, {}, { if (more) { VMC0; SCHB; } });
    }
#undef PHASE

    // C-write, split per block column (uniform per block)
    float* Cp; int col0; size_t ldc;
    if (block_n < 6144) { Cp = C1; col0 = block_n;        ldc = 6144; }
    else                { Cp = C2; col0 = block_n - 6144; ldc = 2048; }
#pragma unroll
    for (int mf = 0; mf < 8; ++mf)
#pragma unroll
        for (int nf = 0; nf < 4; ++nf)
#pragma unroll
            for (int r = 0; r < 4; ++r) {
                int row = block_m + wr * 128 + mf * 16 + kq * 4 + r;
                int col = col0 + wc * 64 + nf * 16 + l15;
                Cp[(size_t)row * ldc + col] = acc[mf][nf][r];
            }
}

// ---- 128x128 bf16 MFMA GEMM (m97 structure) for the output projection ------
__global__ __launch_bounds__(256) void gemm_bf16(
    const unsigned short* __restrict__ A, const unsigned short* __restrict__ Bt,
    float* __restrict__ C, int Kk, int lda, int ldb, int ldc)
{
    __shared__ __align__(16) unsigned short A_lds[128 * 64];
    __shared__ __align__(16) unsigned short B_lds[128 * 64];

    const int tid = threadIdx.x;
    const int wv = tid >> 6;
    const int lane = tid & 63;
    const int wr = wv >> 1, wc = wv & 1;
    const int l15 = lane & 15, kq = lane >> 4;
    const int rsw = (l15 & 7) << 3;

    // m204 bijective XCD chunking (nwg % 8 == 0)
    const int nwg = gridDim.x * gridDim.y;
    const int bid = blockIdx.y * gridDim.x + blockIdx.x;
    const int wgid = (bid & 7) * (nwg >> 3) + (bid >> 3);
    const int block_m = (wgid / gridDim.x) * 128;
    const int block_n = (wgid % gridDim.x) * 128;

    const int srow = lane >> 3;
    const int scol = ((lane & 7) ^ srow) << 3;

    floatx4 acc[4][4] = {};

    for (int k0 = 0; k0 < Kk; k0 += 64) {
#pragma unroll
        for (int i = 0; i < 4; ++i) {
            const int lq = wv * 4 + i;
            const unsigned short* asrc =
                A + (size_t)(block_m + lq * 8 + srow) * lda + k0 + scol;
            load_lds16(asrc, &A_lds[lq * 512]);
            const unsigned short* bsrc =
                Bt + (size_t)(block_n + lq * 8 + srow) * ldb + k0 + scol;
            load_lds16(bsrc, &B_lds[lq * 512]);
        }
        __syncthreads();

#pragma unroll
        for (int kk = 0; kk < 2; ++kk) {
            short8v af[4], bf[4];
#pragma unroll
            for (int mf = 0; mf < 4; ++mf) {
                const int row = wr * 64 + mf * 16 + l15;
                af[mf] = *(const short8v*)&A_lds[row * 64 + ((kk * 32 + kq * 8) ^ rsw)];
            }
#pragma unroll
            for (int nf = 0; nf < 4; ++nf) {
                const int row = wc * 64 + nf * 16 + l15;
                bf[nf] = *(const short8v*)&B_lds[row * 64 + ((kk * 32 + kq * 8) ^ rsw)];
            }
#pragma unroll
            for (int mf = 0; mf < 4; ++mf)
#pragma unroll
                for (int nf = 0; nf < 4; ++nf)
                    acc[mf][nf] = __builtin_amdgcn_mfma_f32_16x16x32_bf16(
                        af[mf], bf[nf], acc[mf][nf], 0, 0, 0);
        }
        __syncthreads();
    }

#pragma unroll
    for (int mf = 0; mf < 4; ++mf)
#pragma unroll
        for (int nf = 0; nf < 4; ++nf)
#pragma unroll
            for (int r = 0; r < 4; ++r) {
                int row = block_m + wr * 64 + mf * 16 + kq * 4 + r;
                int col = block_n + wc * 64 + nf * 16 + l15;
                C[(size_t)row * ldc + col] = acc[mf][nf][r];
            }
}

// -------- alpha/beta: sigmoid(x @ W_{a,b}) + bf16 cast of x (fused) ---------
__global__ __launch_bounds__(256) void ab_kernel(
    const float* __restrict__ x, const float* __restrict__ W_b,
    const float* __restrict__ W_a, float* __restrict__ beta,
    float* __restrict__ alpha, unsigned short* __restrict__ xb)
{
    const int row = blockIdx.x;
    const int tid = threadIdx.x;
    float acc[32];
#pragma unroll
    for (int u = 0; u < 32; ++u) acc[u] = 0.f;

    for (int k = tid; k < Cc; k += 256) {
        float xv = x[(size_t)row * Cc + k];
        xb[(size_t)row * Cc + k] = f2bf(xv);
        const float4* wb = (const float4*)(W_b + (size_t)k * 16);
        const float4* wa = (const float4*)(W_a + (size_t)k * 16);
#pragma unroll
        for (int u = 0; u < 4; ++u) {
            float4 b4 = wb[u];
            float4 a4 = wa[u];
            acc[u * 4 + 0] = fmaf(xv, b4.x, acc[u * 4 + 0]);
            acc[u * 4 + 1] = fmaf(xv, b4.y, acc[u * 4 + 1]);
            acc[u * 4 + 2] = fmaf(xv, b4.z, acc[u * 4 + 2]);
            acc[u * 4 + 3] = fmaf(xv, b4.w, acc[u * 4 + 3]);
            acc[16 + u * 4 + 0] = fmaf(xv, a4.x, acc[16 + u * 4 + 0]);
            acc[16 + u * 4 + 1] = fmaf(xv, a4.y, acc[16 + u * 4 + 1]);
            acc[16 + u * 4 + 2] = fmaf(xv, a4.z, acc[16 + u * 4 + 2]);
            acc[16 + u * 4 + 3] = fmaf(xv, a4.w, acc[16 + u * 4 + 3]);
        }
    }
#pragma unroll
    for (int u = 0; u < 32; ++u) {
        float v = acc[u];
        for (int off = 32; off > 0; off >>= 1) v += __shfl_down(v, off);
        acc[u] = v;
    }
    __shared__ float red[4][32];
    const int wv = tid >> 6;
    if ((tid & 63) == 0) {
#pragma unroll
        for (int u = 0; u < 32; ++u) red[wv][u] = acc[u];
    }
    __syncthreads();
    if (tid < 32) {
        float v = red[0][tid] + red[1][tid] + red[2][tid] + red[3][tid];
        float s = 1.f / (1.f + expf(-v));
        if (tid < 16) beta[(size_t)row * 16 + tid] = s;
        else          alpha[(size_t)row * 16 + (tid - 16)] = s;
    }
}

// ------ conv(K=4) + SiLU + split + l2norm(q,k), 16 timesteps per block ------
__global__ __launch_bounds__(128) void conv_kernel(
    const float* __restrict__ qkv, const float* __restrict__ conv_w,
    const float* __restrict__ conv_state, const int* __restrict__ input_pos,
    float* __restrict__ qn, float* __restrict__ kn, float* __restrict__ vv)
{
    const int tc = blockIdx.x;
    const int hs = blockIdx.y;
    const int b  = blockIdx.z;
    const int lane = threadIdx.x;
    const int kind = hs >> 4;
    const int h = hs & 15;
    const int c = kind * 2048 + h * 128 + lane;
    const int t0 = tc * 16;
    const float keep = (input_pos[0] == 0) ? 0.f : 1.f;

    const float4 w4 = *(const float4*)(conv_w + (size_t)c * 4);

    float win0, win1, win2;
    {
        float tmp[3];
#pragma unroll
        for (int j = 0; j < 3; ++j) {
            int tau = t0 - 3 + j;
            tmp[j] = (tau >= 0) ? qkv[(size_t)(b * Tt + tau) * CONVD + c]
                   : keep * conv_state[((size_t)b * CONVD + c) * 4 + (tau + 4)];
        }
        win0 = tmp[0]; win1 = tmp[1]; win2 = tmp[2];
    }

    float y[16];
    __shared__ float red[16][2];
#pragma unroll
    for (int i = 0; i < 16; ++i) {
        float xv = qkv[(size_t)(b * Tt + t0 + i) * CONVD + c];
        float a = fmaf(w4.x, win0, fmaf(w4.y, win1, fmaf(w4.z, win2, w4.w * xv)));
        float yy = a / (1.f + expf(-a));
        win0 = win1; win1 = win2; win2 = xv;
        if (kind == 2) {
            vv[(size_t)(b * Tt + t0 + i) * 2048 + h * 128 + lane] = yy;
        } else {
            float sq = yy * yy;
            for (int off = 32; off > 0; off >>= 1) sq += __shfl_down(sq, off);
            if ((lane & 63) == 0) red[i][lane >> 6] = sq;
            y[i] = yy;
        }
    }
    if (kind == 2) return;
    __syncthreads();
#pragma unroll
    for (int i = 0; i < 16; ++i) {
        float tot = red[i][0] + red[i][1];
        float inv = 1.f / fmaxf(sqrtf(tot), 1e-12f);
        float outv = y[i] * inv;
        const size_t oidx = (size_t)(b * Tt + t0 + i) * 2048 + h * 128 + lane;
        if (kind == 0) qn[oidx] = outv;
        else           kn[oidx] = outv;
    }
}

// ================= chunked scan, stage A: per-chunk prep =====================
__global__ __launch_bounds__(256) void chunk_prep(
    const float* __restrict__ kn, const float* __restrict__ vv,
    const float* __restrict__ alpha, const float* __restrict__ beta,
    float* __restrict__ logc_g, float* __restrict__ Mbuf)
{
    const int c = blockIdx.x, h = blockIdx.y, b = blockIdx.z;
    const int tid = threadIdx.x;
    const size_t bh = (size_t)b * Hh + h;

    __shared__ float K_lds[32][128];
    __shared__ float V_lds[32][128];
    __shared__ float logc_lds[64];
    __shared__ float b_lds[64];
    __shared__ float wk_lds[64];

    if (tid < 64) {
        const int row = b * Tt + c * 64 + tid;
        float a = alpha[(size_t)row * 16 + h];
        float la = logf(a);
#pragma unroll
        for (int d = 1; d < 64; d <<= 1) {
            float n = __shfl_up(la, d);
            if (tid >= d) la += n;
        }
        logc_lds[tid] = la;
        logc_g[bh * Tt + c * 64 + tid] = la;
        b_lds[tid] = beta[(size_t)row * 16 + h];
    }
    __syncthreads();
    if (tid < 64) {
        wk_lds[tid] = expf(logc_lds[63] - logc_lds[tid]) * b_lds[tid];
    }
    __syncthreads();

    const int ti = tid >> 4;
    const int tj = tid & 15;
    const int tj8sw = swz8(tj * 8);
    float acc[8][8];
#pragma unroll
    for (int i = 0; i < 8; ++i)
#pragma unroll
        for (int j = 0; j < 8; ++j) acc[i][j] = 0.f;

    for (int half = 0; half < 2; ++half) {
        {
            const int sl = tid >> 3;
            const int c0 = (tid & 7) * 16;
            const int grow = b * Tt + c * 64 + half * 32 + sl;
            const float4* kp = (const float4*)(kn + (size_t)grow * 2048 + h * 128 + c0);
            const float4* vp = (const float4*)(vv + (size_t)grow * 2048 + h * 128 + c0);
#pragma unroll
            for (int u = 0; u < 4; ++u) {
                const int cl = c0 + u * 4;
                *(float4*)(&K_lds[sl][cl]) = kp[u];
                *(float4*)(&V_lds[sl][swz8(cl)]) = vp[u];
            }
        }
        __syncthreads();
#pragma unroll 4
        for (int s = 0; s < 32; ++s) {
            float w = wk_lds[half * 32 + s];
            float4 k0 = *(const float4*)(&K_lds[s][ti * 8]);
            float4 k1 = *(const float4*)(&K_lds[s][ti * 8 + 4]);
            float4 v0 = *(const float4*)(&V_lds[s][tj8sw]);
            float4 v1 = *(const float4*)(&V_lds[s][tj8sw + 4]);
            float wk[8] = {w*k0.x, w*k0.y, w*k0.z, w*k0.w, w*k1.x, w*k1.y, w*k1.z, w*k1.w};
            float vf[8] = {v0.x, v0.y, v0.z, v0.w, v1.x, v1.y, v1.z, v1.w};
#pragma unroll
            for (int i = 0; i < 8; ++i)
#pragma unroll
                for (int j = 0; j < 8; ++j)
                    acc[i][j] = fmaf(wk[i], vf[j], acc[i][j]);
        }
        __syncthreads();
    }
    float* mb = Mbuf + ((bh * NCHUNK) + c) * 16384;
#pragma unroll
    for (int i = 0; i < 8; ++i) {
        float4 o0 = {acc[i][0], acc[i][1], acc[i][2], acc[i][3]};
        float4 o1 = {acc[i][4], acc[i][5], acc[i][6], acc[i][7]};
        *(float4*)(mb + (size_t)(ti * 8 + i) * 128 + tj * 8) = o0;
        *(float4*)(mb + (size_t)(ti * 8 + i) * 128 + tj * 8 + 4) = o1;
    }
}

// ================= chunked scan, stage B: state recurrence ==================
__global__ __launch_bounds__(256) void state_scan(
    float* __restrict__ Mbuf, const float* __restrict__ logc_g,
    const float* __restrict__ rec_state, const int* __restrict__ input_pos)
{
    const size_t g = (size_t)blockIdx.x * 256 + threadIdx.x;
    const int bh = (int)(g >> 14);
    const float keep = (input_pos[0] == 0) ? 0.f : 1.f;

    float S = keep * rec_state[g];
    const float* lc = logc_g + (size_t)bh * Tt;
    float* base = Mbuf + (size_t)(g & ~16383ull) * NCHUNK + (g & 16383);
#pragma unroll 4
    for (int c = 0; c < NCHUNK; ++c) {
        float Atot = expf(lc[c * 64 + 63]);
        float m = base[(size_t)c * 16384];
        base[(size_t)c * 16384] = S;
        S = fmaf(Atot, S, m);
    }
}

// ================= chunked scan, stage C: per-chunk output ==================
__global__ __launch_bounds__(256) void chunk_out(
    const float* __restrict__ qn, const float* __restrict__ kn,
    const float* __restrict__ vv, const float* __restrict__ beta,
    const float* __restrict__ logc_g, const float* __restrict__ Sstates,
    const float* __restrict__ norm_w, const float* __restrict__ zbuf,
    unsigned short* __restrict__ gated_b)
{
    const int c = blockIdx.x, h = blockIdx.y, b = blockIdx.z;
    const int tid = threadIdx.x;
    const int ti = tid >> 4;
    const int tj = tid & 15;
    const size_t bh = (size_t)b * Hh + h;
    const int row0 = b * Tt + c * 64;

    __shared__ float Q_lds[64][132];
    __shared__ float Bf[64 * 68];
    __shared__ float At[64][68];
    __shared__ float logc_s[64], b_s[64];

    {
        const int r = tid >> 2, c0 = (tid & 3) * 32;
        const float4* qp = (const float4*)(qn + (size_t)(row0 + r) * 2048 + h * 128 + c0);
#pragma unroll
        for (int u = 0; u < 8; ++u)
            *(float4*)(&Q_lds[r][c0 + u * 4]) = qp[u];
    }
    if (tid < 64) {
        logc_s[tid] = logc_g[bh * Tt + c * 64 + tid];
        b_s[tid] = beta[(size_t)(row0 + tid) * 16 + h];
    }

    float acc_a[4][4] = {};
    for (int kh = 0; kh < 2; ++kh) {
        __syncthreads();
        {
            const int s = tid >> 2, c0 = (tid & 3) * 16;
            const float* kp = kn + (size_t)(row0 + s) * 2048 + h * 128 + kh * 64 + c0;
#pragma unroll
            for (int u = 0; u < 16; ++u)
                Bf[(c0 + u) * 68 + s] = kp[u];
        }
        __syncthreads();
#pragma unroll 4
        for (int kk = 0; kk < 64; ++kk) {
            float a[4];
#pragma unroll
            for (int r = 0; r < 4; ++r) a[r] = Q_lds[ti * 4 + r][kh * 64 + kk];
            float4 bq = *(const float4*)(&Bf[kk * 68 + tj * 4]);
            float bb[4] = {bq.x, bq.y, bq.z, bq.w};
#pragma unroll
            for (int r = 0; r < 4; ++r)
#pragma unroll
                for (int cc = 0; cc < 4; ++cc)
                    acc_a[r][cc] = fmaf(a[r], bb[cc], acc_a[r][cc]);
        }
    }

#pragma unroll
    for (int r = 0; r < 4; ++r) {
        const int t = ti * 4 + r;
        const float lct = logc_s[t];
#pragma unroll
        for (int cc = 0; cc < 4; ++cc) {
            const int s = tj * 4 + cc;
            float w = (s <= t) ? expf(lct - logc_s[s]) * b_s[s] : 0.f;
            At[t][s] = w * acc_a[r][cc];
        }
    }

    float o[4][8] = {};
    const float* Sbase = Sstates + (bh * NCHUNK + c) * 16384;
    const int tj8sw = swz8(tj * 8);
    for (int kb = 0; kb < 8; ++kb) {
        __syncthreads();
        {
            const int rr = tid >> 4;
            const int cl = (tid & 15) * 8;
            const int sw = swz8(cl);
            const float4* sp = (const float4*)(Sbase + (size_t)(kb * 16 + rr) * 128 + cl);
            *(float4*)(&Bf[rr * 132 + sw]) = sp[0];
            *(float4*)(&Bf[rr * 132 + sw + 4]) = sp[1];
        }
        __syncthreads();
#pragma unroll
        for (int kk = 0; kk < 16; ++kk) {
            float a[4];
#pragma unroll
            for (int r = 0; r < 4; ++r) a[r] = Q_lds[ti * 4 + r][kb * 16 + kk];
            float4 s0 = *(const float4*)(&Bf[kk * 132 + tj8sw]);
            float4 s1 = *(const float4*)(&Bf[kk * 132 + tj8sw + 4]);
            float sv[8] = {s0.x, s0.y, s0.z, s0.w, s1.x, s1.y, s1.z, s1.w};
#pragma unroll
            for (int r = 0; r < 4; ++r)
#pragma unroll
                for (int j = 0; j < 8; ++j)
                    o[r][j] = fmaf(a[r], sv[j], o[r][j]);
        }
    }
#pragma unroll
    for (int r = 0; r < 4; ++r) {
        const float ct = expf(logc_s[ti * 4 + r]);
#pragma unroll
        for (int j = 0; j < 8; ++j) o[r][j] *= ct;
    }

    for (int sh = 0; sh < 2; ++sh) {
        __syncthreads();
        {
            const int rr = tid >> 3;
            const int c0 = (tid & 7) * 16;
            const float4* vp = (const float4*)(vv + (size_t)(row0 + sh * 32 + rr) * 2048 + h * 128 + c0);
#pragma unroll
            for (int u = 0; u < 4; ++u) {
                const int cl = c0 + u * 4;
                *(float4*)(&Bf[rr * 132 + swz8(cl)]) = vp[u];
            }
        }
        __syncthreads();
#pragma unroll 2
        for (int sp = 0; sp < 32; ++sp) {
            const int s = sh * 32 + sp;
            float a[4];
#pragma unroll
            for (int r = 0; r < 4; ++r) a[r] = At[ti * 4 + r][s];
            float4 v0 = *(const float4*)(&Bf[sp * 132 + tj8sw]);
            float4 v1 = *(const float4*)(&Bf[sp * 132 + tj8sw + 4]);
            float vf[8] = {v0.x, v0.y, v0.z, v0.w, v1.x, v1.y, v1.z, v1.w};
#pragma unroll
            for (int r = 0; r < 4; ++r)
#pragma unroll
                for (int j = 0; j < 8; ++j)
                    o[r][j] = fmaf(a[r], vf[j], o[r][j]);
        }
    }

#pragma unroll
    for (int r = 0; r < 4; ++r) {
        float ss = 0.f;
#pragma unroll
        for (int j = 0; j < 8; ++j) ss = fmaf(o[r][j], o[r][j], ss);
        ss += __shfl_xor(ss, 1);
        ss += __shfl_xor(ss, 2);
        ss += __shfl_xor(ss, 4);
        ss += __shfl_xor(ss, 8);
        const float scale = rsqrtf(ss * (1.f / 128.f) + 1e-6f);
        const int t = ti * 4 + r;
        const float* zp = zbuf + (size_t)(row0 + t) * 2048 + h * 128 + tj * 8;
        unsigned short* gp = gated_b + (size_t)(row0 + t) * 2048 + h * 128 + tj * 8;
#pragma unroll
        for (int j = 0; j < 8; ++j) {
            float zv = zp[j];
            float g = o[r][j] * scale * norm_w[tj * 8 + j] * (1.f / (1.f + expf(-zv)));
            gp[j] = f2bf(g);
        }
    }
}

extern "C" void kernel_launch(void* const* d_in, const int* in_sizes, int n_in,
                              void* d_out, int out_size, void* d_ws, size_t ws_size,
                              hipStream_t stream) {
    (void)in_sizes; (void)n_in; (void)out_size; (void)ws_size;
    const float* x          = (const float*)d_in[0];
    const int*   input_pos  = (const int*)d_in[1];
    const float* W_qkvz     = (const float*)d_in[2];
    const float* W_b        = (const float*)d_in[3];
    const float* W_a        = (const float*)d_in[4];
    const float* conv_w     = (const float*)d_in[5];
    const float* norm_w     = (const float*)d_in[6];
    const float* W_out      = (const float*)d_in[7];
    const float* conv_state = (const float*)d_in[8];
    const float* rec_state  = (const float*)d_in[9];
    float* out = (float*)d_out;
    float* ws  = (float*)d_ws;

    // workspace (float elems), peak 232.75 MiB with phase-based aliasing:
    float* qkv   = ws;                                 // 25,165,824 f (phase 2-3)
    float* Mbuf  = ws;                                 // 16,777,216 f (phase 4+, aliases qkv)
    unsigned short* gated_b = (unsigned short*)(ws + 16777216); // bf16 (phase 5+)
    float* qn    = ws + 25165824ull;                   // 8,388,608 f (phase 3+)
    float* kn    = qn + 8388608ull;
    float* vv    = kn + 8388608ull;
    unsigned short* xb  = (unsigned short*)qn;         // phase 1-2, aliases qn
    unsigned short* WqT = (unsigned short*)(qn + 4194304ull); // 8192x2048 bf16
    float* zbuf  = vv + 8388608ull;
    unsigned short* WoT = (unsigned short*)(zbuf + 8388608ull);
    float* alpha = zbuf + 8388608ull + 2097152ull;
    float* beta  = alpha + 65536ull;
    float* logc  = beta + 65536ull;

    // 0. weight transposes (merged) + alpha/beta (also emits xb = bf16(x))
    transpose_cast2<<<dim3(256, 64, 2), 256, 0, stream>>>(W_qkvz, WqT, W_out, WoT);
    ab_kernel<<<Mrows, 256, 0, stream>>>(x, W_b, W_a, beta, alpha, xb);

    // 1. merged qkvz GEMM: cols<6144 -> qkv (ldc 6144), cols>=6144 -> zbuf
    gemm256<<<dim3(8192 / 256, Mrows / 256), 512, 0, stream>>>(
        xb, WqT, qkv, zbuf, 2048, 2048, 2048);
    // 3. conv + silu + l2norm (last reader of qkv buffer)
    conv_kernel<<<dim3(Tt / 16, 48, Bb), 128, 0, stream>>>(
        qkv, conv_w, conv_state, input_pos, qn, kn, vv);
    // 4a. per-chunk prep: log-cumsum + M_c  (overwrites dead qkv region)
    chunk_prep<<<dim3(NCHUNK, Hh, Bb), 256, 0, stream>>>(
        kn, vv, alpha, beta, logc, Mbuf);
    // 4b. chunk-state recurrence, element-parallel (Mbuf -> Sstates in place)
    state_scan<<<2048, 256, 0, stream>>>(Mbuf, logc, rec_state, input_pos);
    // 4c. per-chunk outputs + RMSNorm + gate -> gated_b (bf16)
    chunk_out<<<dim3(NCHUNK, Hh, Bb), 256, 0, stream>>>(
        qn, kn, vv, beta, logc, Mbuf, norm_w, zbuf, gated_b);
    // 5. out = gated @ W_out   (MFMA bf16, 128^2 m97 structure, XCD-chunked)
    gemm_bf16<<<dim3(2048 / 128, Mrows / 128), 256, 0, stream>>>(
        gated_b, WoT, out, 2048, 2048, 2048, 2048);
}

// Round 10
// 517.935 us; speedup vs baseline: 11.5854x; 1.0291x over previous
//
#include <hip/hip_runtime.h>
#include <hip/hip_bf16.h>
#include <math.h>

#define Bb 2
#define Tt 2048
#define Cc 2048
#define Hh 16
#define CONVD 6144
#define Mrows 4096  // B*T
#define NCHUNK 32   // T / 64

typedef __attribute__((ext_vector_type(8))) short short8v;
typedef __attribute__((ext_vector_type(4))) float floatx4;

__device__ __forceinline__ unsigned short f2bf(float f) {
    __hip_bfloat16 h = __float2bfloat16(f);
    return __builtin_bit_cast(unsigned short, h);
}

__device__ __forceinline__ void load_lds16(const void* g, void* l) {
    __builtin_amdgcn_global_load_lds(
        (const __attribute__((address_space(1))) void*)g,
        (__attribute__((address_space(3))) void*)l, 16, 0, 0);
}

// col-swizzle for float LDS tiles with 128-col rows read as float4 at tj*8:
__device__ __forceinline__ int swz8(int col) {
    return col ^ (((col >> 5) & 3) << 3);
}

#define LGKM0 asm volatile("s_waitcnt lgkmcnt(0)" ::: "memory")
#define VMC8  asm volatile("s_waitcnt vmcnt(8)" ::: "memory")
#define VMC4  asm volatile("s_waitcnt vmcnt(4)" ::: "memory")
#define VMC0  asm volatile("s_waitcnt vmcnt(0)" ::: "memory")
#define SCHB  __builtin_amdgcn_sched_barrier(0)
#define SBAR  __builtin_amdgcn_s_barrier()

// ------ merged transpose+cast: W1(2048x8192)->WT1, W2(2048x2048)->WT2 -------
__global__ __launch_bounds__(256) void transpose_cast2(
    const float* __restrict__ W1, unsigned short* __restrict__ WT1,
    const float* __restrict__ W2, unsigned short* __restrict__ WT2)
{
    const float* W; unsigned short* WT; int Nn;
    if (blockIdx.z == 0) { W = W1; WT = WT1; Nn = 8192; }
    else                 { W = W2; WT = WT2; Nn = 2048; if (blockIdx.x >= 64) return; }
    __shared__ float tile[32][33];
    const int n0 = blockIdx.x * 32;
    const int k0 = blockIdx.y * 32;
    const int tx = threadIdx.x & 31;
    const int ty = threadIdx.x >> 5;
#pragma unroll
    for (int r = ty; r < 32; r += 8)
        tile[r][tx] = W[(size_t)(k0 + r) * Nn + n0 + tx];
    __syncthreads();
#pragma unroll
    for (int r = ty; r < 32; r += 8)
        WT[(size_t)(n0 + r) * 2048 + k0 + tx] = f2bf(tile[tx][r]);
}

// ====== 256x256 bf16 MFMA GEMM, 4-deep counted-vmcnt pipeline (T1/2/4/5) ====
// C = A(MxK bf16) @ Bt(NxK bf16)^T. 8 waves (2Mx4N), BK=32, 4 LDS bufs 128KB.
// Tile t: ds_read frags from buf[t&3] (12 b128, 2-way swizzled), issue stage
// of tile t+3 into buf[(t+3)&3] (4 global_load_lds, freed at t-1's barrier),
// lgkmcnt(0)+MFMA x32, then vmcnt(8): waits ONLY t+1's loads (t+2/t+3's 8
// stay in flight -> ~2 tiles of latency cover), ONE barrier per tile.
__global__ __launch_bounds__(512) void gemm256(
    const unsigned short* __restrict__ A, const unsigned short* __restrict__ Bt,
    float* __restrict__ C1, float* __restrict__ C2,
    int Kk, int lda, int ldb)
{
    __shared__ __align__(16) unsigned short A_lds[4][256 * 32];
    __shared__ __align__(16) unsigned short B_lds[4][256 * 32];

    const int tid  = threadIdx.x;
    const int wid  = tid >> 6;            // 0..7
    const int lane = tid & 63;
    const int wr = wid >> 2, wc = wid & 3;
    const int l15 = lane & 15, kq = lane >> 4;

    // staging lane map: rr=row in 16-group, cs=pre-swizzled 16B chunk (rule 21)
    const int rr = lane >> 2;
    const int cs = (lane & 3) ^ ((rr >> 1) & 3);
    // frag-read chunk with matching swizzle (row bits 1..2 come from l15)
    const int fch = (kq ^ ((l15 >> 1) & 3)) << 3;   // in shorts

    // 8x8 super-chunk per XCD (grid 32x16, 512 blocks, bijective)
    const int bid = blockIdx.y * 32 + blockIdx.x;
    const int xcd = bid & 7;
    const int idx = bid >> 3;
    const int block_m = ((xcd >> 2) * 8 + (idx >> 3)) * 256;
    const int block_n = ((xcd & 3) * 8 + (idx & 7)) * 256;

    const unsigned short* Ag = A + (size_t)block_m * lda;
    const unsigned short* Bg = Bt + (size_t)block_n * ldb;

    const int NT = Kk >> 5;               // K-tiles of 32

#define STG(bi, kk0) do {                                                    \
    unsigned short* la_ = &A_lds[(bi)][0];                                   \
    unsigned short* lb_ = &B_lds[(bi)][0];                                   \
    _Pragma("unroll")                                                        \
    for (int j_ = 0; j_ < 2; ++j_) {                                         \
        const int brow = wid * 32 + j_ * 16;                                 \
        load_lds16(Ag + (size_t)(brow + rr) * lda + (kk0) + cs * 8,          \
                   la_ + brow * 32);                                         \
        load_lds16(Bg + (size_t)(brow + rr) * ldb + (kk0) + cs * 8,          \
                   lb_ + brow * 32);                                         \
    }                                                                        \
} while (0)

    floatx4 acc[8][4] = {};

    // prologue: stage tiles 0,1,2 (12 loads), wait tile0 (vmcnt(8)), sync
    STG(0, 0);
    STG(1, 32);
    STG(2, 64);
    VMC8; SCHB; SBAR;

    for (int t = 0; t < NT; ++t) {
        const unsigned short* la = &A_lds[t & 3][0];
        const unsigned short* lb = &B_lds[t & 3][0];

        short8v af[8], bf[4];
#pragma unroll
        for (int mf = 0; mf < 8; ++mf)
            af[mf] = *(const short8v*)(la + (wr * 128 + mf * 16 + l15) * 32 + fch);
#pragma unroll
        for (int nf = 0; nf < 4; ++nf)
            bf[nf] = *(const short8v*)(lb + (wc * 64 + nf * 16 + l15) * 32 + fch);

        if (t + 3 < NT) STG((t + 3) & 3, (t + 3) << 5);

        LGKM0; SCHB;
        __builtin_amdgcn_s_setprio(1);
#pragma unroll
        for (int mf = 0; mf < 8; ++mf)
#pragma unroll
            for (int nf = 0; nf < 4; ++nf)
                acc[mf][nf] = __builtin_amdgcn_mfma_f32_16x16x32_bf16(
                    af[mf], bf[nf], acc[mf][nf], 0, 0, 0);
        __builtin_amdgcn_s_setprio(0);
        SCHB;
        if (t + 1 < NT) {
            if      (t + 3 < NT) { VMC8; }   // t+1 landed; t+2,t+3 in flight
            else if (t + 2 < NT) { VMC4; }
            else                 { VMC0; }
            SCHB; SBAR;
        }
    }
#undef STG

    // C-write, split per block column (uniform per block)
    float* Cp; int col0; size_t ldc;
    if (block_n < 6144) { Cp = C1; col0 = block_n;        ldc = 6144; }
    else                { Cp = C2; col0 = block_n - 6144; ldc = 2048; }
#pragma unroll
    for (int mf = 0; mf < 8; ++mf)
#pragma unroll
        for (int nf = 0; nf < 4; ++nf)
#pragma unroll
            for (int r = 0; r < 4; ++r) {
                int row = block_m + wr * 128 + mf * 16 + kq * 4 + r;
                int col = col0 + wc * 64 + nf * 16 + l15;
                Cp[(size_t)row * ldc + col] = acc[mf][nf][r];
            }
}

// ---- 128x128 bf16 MFMA GEMM (m97 structure) for the output projection ------
__global__ __launch_bounds__(256) void gemm_bf16(
    const unsigned short* __restrict__ A, const unsigned short* __restrict__ Bt,
    float* __restrict__ C, int Kk, int lda, int ldb, int ldc)
{
    __shared__ __align__(16) unsigned short A_lds[128 * 64];
    __shared__ __align__(16) unsigned short B_lds[128 * 64];

    const int tid = threadIdx.x;
    const int wv = tid >> 6;
    const int lane = tid & 63;
    const int wr = wv >> 1, wc = wv & 1;
    const int l15 = lane & 15, kq = lane >> 4;
    const int rsw = (l15 & 7) << 3;

    // m204 bijective XCD chunking (nwg % 8 == 0)
    const int nwg = gridDim.x * gridDim.y;
    const int bid = blockIdx.y * gridDim.x + blockIdx.x;
    const int wgid = (bid & 7) * (nwg >> 3) + (bid >> 3);
    const int block_m = (wgid / gridDim.x) * 128;
    const int block_n = (wgid % gridDim.x) * 128;

    const int srow = lane >> 3;
    const int scol = ((lane & 7) ^ srow) << 3;

    floatx4 acc[4][4] = {};

    for (int k0 = 0; k0 < Kk; k0 += 64) {
#pragma unroll
        for (int i = 0; i < 4; ++i) {
            const int lq = wv * 4 + i;
            const unsigned short* asrc =
                A + (size_t)(block_m + lq * 8 + srow) * lda + k0 + scol;
            load_lds16(asrc, &A_lds[lq * 512]);
            const unsigned short* bsrc =
                Bt + (size_t)(block_n + lq * 8 + srow) * ldb + k0 + scol;
            load_lds16(bsrc, &B_lds[lq * 512]);
        }
        __syncthreads();

#pragma unroll
        for (int kk = 0; kk < 2; ++kk) {
            short8v af[4], bf[4];
#pragma unroll
            for (int mf = 0; mf < 4; ++mf) {
                const int row = wr * 64 + mf * 16 + l15;
                af[mf] = *(const short8v*)&A_lds[row * 64 + ((kk * 32 + kq * 8) ^ rsw)];
            }
#pragma unroll
            for (int nf = 0; nf < 4; ++nf) {
                const int row = wc * 64 + nf * 16 + l15;
                bf[nf] = *(const short8v*)&B_lds[row * 64 + ((kk * 32 + kq * 8) ^ rsw)];
            }
#pragma unroll
            for (int mf = 0; mf < 4; ++mf)
#pragma unroll
                for (int nf = 0; nf < 4; ++nf)
                    acc[mf][nf] = __builtin_amdgcn_mfma_f32_16x16x32_bf16(
                        af[mf], bf[nf], acc[mf][nf], 0, 0, 0);
        }
        __syncthreads();
    }

#pragma unroll
    for (int mf = 0; mf < 4; ++mf)
#pragma unroll
        for (int nf = 0; nf < 4; ++nf)
#pragma unroll
            for (int r = 0; r < 4; ++r) {
                int row = block_m + wr * 64 + mf * 16 + kq * 4 + r;
                int col = block_n + wc * 64 + nf * 16 + l15;
                C[(size_t)row * ldc + col] = acc[mf][nf][r];
            }
}

// -------- alpha/beta: sigmoid(x @ W_{a,b}) + bf16 cast of x (fused) ---------
__global__ __launch_bounds__(256) void ab_kernel(
    const float* __restrict__ x, const float* __restrict__ W_b,
    const float* __restrict__ W_a, float* __restrict__ beta,
    float* __restrict__ alpha, unsigned short* __restrict__ xb)
{
    const int row = blockIdx.x;
    const int tid = threadIdx.x;
    float acc[32];
#pragma unroll
    for (int u = 0; u < 32; ++u) acc[u] = 0.f;

    for (int k = tid; k < Cc; k += 256) {
        float xv = x[(size_t)row * Cc + k];
        xb[(size_t)row * Cc + k] = f2bf(xv);
        const float4* wb = (const float4*)(W_b + (size_t)k * 16);
        const float4* wa = (const float4*)(W_a + (size_t)k * 16);
#pragma unroll
        for (int u = 0; u < 4; ++u) {
            float4 b4 = wb[u];
            float4 a4 = wa[u];
            acc[u * 4 + 0] = fmaf(xv, b4.x, acc[u * 4 + 0]);
            acc[u * 4 + 1] = fmaf(xv, b4.y, acc[u * 4 + 1]);
            acc[u * 4 + 2] = fmaf(xv, b4.z, acc[u * 4 + 2]);
            acc[u * 4 + 3] = fmaf(xv, b4.w, acc[u * 4 + 3]);
            acc[16 + u * 4 + 0] = fmaf(xv, a4.x, acc[16 + u * 4 + 0]);
            acc[16 + u * 4 + 1] = fmaf(xv, a4.y, acc[16 + u * 4 + 1]);
            acc[16 + u * 4 + 2] = fmaf(xv, a4.z, acc[16 + u * 4 + 2]);
            acc[16 + u * 4 + 3] = fmaf(xv, a4.w, acc[16 + u * 4 + 3]);
        }
    }
#pragma unroll
    for (int u = 0; u < 32; ++u) {
        float v = acc[u];
        for (int off = 32; off > 0; off >>= 1) v += __shfl_down(v, off);
        acc[u] = v;
    }
    __shared__ float red[4][32];
    const int wv = tid >> 6;
    if ((tid & 63) == 0) {
#pragma unroll
        for (int u = 0; u < 32; ++u) red[wv][u] = acc[u];
    }
    __syncthreads();
    if (tid < 32) {
        float v = red[0][tid] + red[1][tid] + red[2][tid] + red[3][tid];
        float s = 1.f / (1.f + expf(-v));
        if (tid < 16) beta[(size_t)row * 16 + tid] = s;
        else          alpha[(size_t)row * 16 + (tid - 16)] = s;
    }
}

// ------ conv(K=4) + SiLU + split + l2norm(q,k), 16 timesteps per block ------
__global__ __launch_bounds__(128) void conv_kernel(
    const float* __restrict__ qkv, const float* __restrict__ conv_w,
    const float* __restrict__ conv_state, const int* __restrict__ input_pos,
    float* __restrict__ qn, float* __restrict__ kn, float* __restrict__ vv)
{
    const int tc = blockIdx.x;
    const int hs = blockIdx.y;
    const int b  = blockIdx.z;
    const int lane = threadIdx.x;
    const int kind = hs >> 4;
    const int h = hs & 15;
    const int c = kind * 2048 + h * 128 + lane;
    const int t0 = tc * 16;
    const float keep = (input_pos[0] == 0) ? 0.f : 1.f;

    const float4 w4 = *(const float4*)(conv_w + (size_t)c * 4);

    float win0, win1, win2;
    {
        float tmp[3];
#pragma unroll
        for (int j = 0; j < 3; ++j) {
            int tau = t0 - 3 + j;
            tmp[j] = (tau >= 0) ? qkv[(size_t)(b * Tt + tau) * CONVD + c]
                   : keep * conv_state[((size_t)b * CONVD + c) * 4 + (tau + 4)];
        }
        win0 = tmp[0]; win1 = tmp[1]; win2 = tmp[2];
    }

    float y[16];
    __shared__ float red[16][2];
#pragma unroll
    for (int i = 0; i < 16; ++i) {
        float xv = qkv[(size_t)(b * Tt + t0 + i) * CONVD + c];
        float a = fmaf(w4.x, win0, fmaf(w4.y, win1, fmaf(w4.z, win2, w4.w * xv)));
        float yy = a / (1.f + expf(-a));
        win0 = win1; win1 = win2; win2 = xv;
        if (kind == 2) {
            vv[(size_t)(b * Tt + t0 + i) * 2048 + h * 128 + lane] = yy;
        } else {
            float sq = yy * yy;
            for (int off = 32; off > 0; off >>= 1) sq += __shfl_down(sq, off);
            if ((lane & 63) == 0) red[i][lane >> 6] = sq;
            y[i] = yy;
        }
    }
    if (kind == 2) return;
    __syncthreads();
#pragma unroll
    for (int i = 0; i < 16; ++i) {
        float tot = red[i][0] + red[i][1];
        float inv = 1.f / fmaxf(sqrtf(tot), 1e-12f);
        float outv = y[i] * inv;
        const size_t oidx = (size_t)(b * Tt + t0 + i) * 2048 + h * 128 + lane;
        if (kind == 0) qn[oidx] = outv;
        else           kn[oidx] = outv;
    }
}

// ================= chunked scan, stage A: per-chunk prep =====================
__global__ __launch_bounds__(256) void chunk_prep(
    const float* __restrict__ kn, const float* __restrict__ vv,
    const float* __restrict__ alpha, const float* __restrict__ beta,
    float* __restrict__ logc_g, float* __restrict__ Mbuf)
{
    const int c = blockIdx.x, h = blockIdx.y, b = blockIdx.z;
    const int tid = threadIdx.x;
    const size_t bh = (size_t)b * Hh + h;

    __shared__ float K_lds[32][128];
    __shared__ float V_lds[32][128];
    __shared__ float logc_lds[64];
    __shared__ float b_lds[64];
    __shared__ float wk_lds[64];

    if (tid < 64) {
        const int row = b * Tt + c * 64 + tid;
        float a = alpha[(size_t)row * 16 + h];
        float la = logf(a);
#pragma unroll
        for (int d = 1; d < 64; d <<= 1) {
            float n = __shfl_up(la, d);
            if (tid >= d) la += n;
        }
        logc_lds[tid] = la;
        logc_g[bh * Tt + c * 64 + tid] = la;
        b_lds[tid] = beta[(size_t)row * 16 + h];
    }
    __syncthreads();
    if (tid < 64) {
        wk_lds[tid] = expf(logc_lds[63] - logc_lds[tid]) * b_lds[tid];
    }
    __syncthreads();

    const int ti = tid >> 4;
    const int tj = tid & 15;
    const int tj8sw = swz8(tj * 8);
    float acc[8][8];
#pragma unroll
    for (int i = 0; i < 8; ++i)
#pragma unroll
        for (int j = 0; j < 8; ++j) acc[i][j] = 0.f;

    for (int half = 0; half < 2; ++half) {
        {
            const int sl = tid >> 3;
            const int c0 = (tid & 7) * 16;
            const int grow = b * Tt + c * 64 + half * 32 + sl;
            const float4* kp = (const float4*)(kn + (size_t)grow * 2048 + h * 128 + c0);
            const float4* vp = (const float4*)(vv + (size_t)grow * 2048 + h * 128 + c0);
#pragma unroll
            for (int u = 0; u < 4; ++u) {
                const int cl = c0 + u * 4;
                *(float4*)(&K_lds[sl][cl]) = kp[u];
                *(float4*)(&V_lds[sl][swz8(cl)]) = vp[u];
            }
        }
        __syncthreads();
#pragma unroll 4
        for (int s = 0; s < 32; ++s) {
            float w = wk_lds[half * 32 + s];
            float4 k0 = *(const float4*)(&K_lds[s][ti * 8]);
            float4 k1 = *(const float4*)(&K_lds[s][ti * 8 + 4]);
            float4 v0 = *(const float4*)(&V_lds[s][tj8sw]);
            float4 v1 = *(const float4*)(&V_lds[s][tj8sw + 4]);
            float wk[8] = {w*k0.x, w*k0.y, w*k0.z, w*k0.w, w*k1.x, w*k1.y, w*k1.z, w*k1.w};
            float vf[8] = {v0.x, v0.y, v0.z, v0.w, v1.x, v1.y, v1.z, v1.w};
#pragma unroll
            for (int i = 0; i < 8; ++i)
#pragma unroll
                for (int j = 0; j < 8; ++j)
                    acc[i][j] = fmaf(wk[i], vf[j], acc[i][j]);
        }
        __syncthreads();
    }
    float* mb = Mbuf + ((bh * NCHUNK) + c) * 16384;
#pragma unroll
    for (int i = 0; i < 8; ++i) {
        float4 o0 = {acc[i][0], acc[i][1], acc[i][2], acc[i][3]};
        float4 o1 = {acc[i][4], acc[i][5], acc[i][6], acc[i][7]};
        *(float4*)(mb + (size_t)(ti * 8 + i) * 128 + tj * 8) = o0;
        *(float4*)(mb + (size_t)(ti * 8 + i) * 128 + tj * 8 + 4) = o1;
    }
}

// ================= chunked scan, stage B: state recurrence ==================
__global__ __launch_bounds__(256) void state_scan(
    float* __restrict__ Mbuf, const float* __restrict__ logc_g,
    const float* __restrict__ rec_state, const int* __restrict__ input_pos)
{
    const size_t g = (size_t)blockIdx.x * 256 + threadIdx.x;
    const int bh = (int)(g >> 14);
    const float keep = (input_pos[0] == 0) ? 0.f : 1.f;

    float S = keep * rec_state[g];
    const float* lc = logc_g + (size_t)bh * Tt;
    float* base = Mbuf + (size_t)(g & ~16383ull) * NCHUNK + (g & 16383);
#pragma unroll 4
    for (int c = 0; c < NCHUNK; ++c) {
        float Atot = expf(lc[c * 64 + 63]);
        float m = base[(size_t)c * 16384];
        base[(size_t)c * 16384] = S;
        S = fmaf(Atot, S, m);
    }
}

// ================= chunked scan, stage C: per-chunk output ==================
__global__ __launch_bounds__(256) void chunk_out(
    const float* __restrict__ qn, const float* __restrict__ kn,
    const float* __restrict__ vv, const float* __restrict__ beta,
    const float* __restrict__ logc_g, const float* __restrict__ Sstates,
    const float* __restrict__ norm_w, const float* __restrict__ zbuf,
    unsigned short* __restrict__ gated_b)
{
    const int c = blockIdx.x, h = blockIdx.y, b = blockIdx.z;
    const int tid = threadIdx.x;
    const int ti = tid >> 4;
    const int tj = tid & 15;
    const size_t bh = (size_t)b * Hh + h;
    const int row0 = b * Tt + c * 64;

    __shared__ float Q_lds[64][132];
    __shared__ float Bf[64 * 68];
    __shared__ float At[64][68];
    __shared__ float logc_s[64], b_s[64];

    {
        const int r = tid >> 2, c0 = (tid & 3) * 32;
        const float4* qp = (const float4*)(qn + (size_t)(row0 + r) * 2048 + h * 128 + c0);
#pragma unroll
        for (int u = 0; u < 8; ++u)
            *(float4*)(&Q_lds[r][c0 + u * 4]) = qp[u];
    }
    if (tid < 64) {
        logc_s[tid] = logc_g[bh * Tt + c * 64 + tid];
        b_s[tid] = beta[(size_t)(row0 + tid) * 16 + h];
    }

    float acc_a[4][4] = {};
    for (int kh = 0; kh < 2; ++kh) {
        __syncthreads();
        {
            const int s = tid >> 2, c0 = (tid & 3) * 16;
            const float* kp = kn + (size_t)(row0 + s) * 2048 + h * 128 + kh * 64 + c0;
#pragma unroll
            for (int u = 0; u < 16; ++u)
                Bf[(c0 + u) * 68 + s] = kp[u];
        }
        __syncthreads();
#pragma unroll 4
        for (int kk = 0; kk < 64; ++kk) {
            float a[4];
#pragma unroll
            for (int r = 0; r < 4; ++r) a[r] = Q_lds[ti * 4 + r][kh * 64 + kk];
            float4 bq = *(const float4*)(&Bf[kk * 68 + tj * 4]);
            float bb[4] = {bq.x, bq.y, bq.z, bq.w};
#pragma unroll
            for (int r = 0; r < 4; ++r)
#pragma unroll
                for (int cc = 0; cc < 4; ++cc)
                    acc_a[r][cc] = fmaf(a[r], bb[cc], acc_a[r][cc]);
        }
    }

#pragma unroll
    for (int r = 0; r < 4; ++r) {
        const int t = ti * 4 + r;
        const float lct = logc_s[t];
#pragma unroll
        for (int cc = 0; cc < 4; ++cc) {
            const int s = tj * 4 + cc;
            float w = (s <= t) ? expf(lct - logc_s[s]) * b_s[s] : 0.f;
            At[t][s] = w * acc_a[r][cc];
        }
    }

    // ---- inter-chunk: o = q @ S_c, ping-pong halves of Bf (T14) ----
    float o[4][8] = {};
    const float* Sbase = Sstates + (bh * NCHUNK + c) * 16384;
    const int tj8sw = swz8(tj * 8);
    const int rws = tid >> 4;
    const int cl = (tid & 15) * 8;
    const int sw = swz8(cl);
    float* Sb0 = Bf;
    float* Sb1 = Bf + 2112;   // 16 rows * 132
    {
        __syncthreads();   // all K_T reads of Bf done
        const float4* sp = (const float4*)(Sbase + (size_t)rws * 128 + cl);
        *(float4*)(&Sb0[rws * 132 + sw]) = sp[0];
        *(float4*)(&Sb0[rws * 132 + sw + 4]) = sp[1];
        __syncthreads();
    }
    for (int kb = 0; kb < 8; ++kb) {
        const float* src = (kb & 1) ? Sb1 : Sb0;
        float* dst = (kb & 1) ? Sb0 : Sb1;
        float4 nv0, nv1;
        if (kb < 7) {   // issue next-chunk loads BEFORE compute (hide latency)
            const float4* sp = (const float4*)(Sbase + (size_t)((kb + 1) * 16 + rws) * 128 + cl);
            nv0 = sp[0]; nv1 = sp[1];
        }
#pragma unroll
        for (int kk = 0; kk < 16; ++kk) {
            float a[4];
#pragma unroll
            for (int r = 0; r < 4; ++r) a[r] = Q_lds[ti * 4 + r][kb * 16 + kk];
            float4 s0 = *(const float4*)(&src[kk * 132 + tj8sw]);
            float4 s1 = *(const float4*)(&src[kk * 132 + tj8sw + 4]);
            float sv[8] = {s0.x, s0.y, s0.z, s0.w, s1.x, s1.y, s1.z, s1.w};
#pragma unroll
            for (int r = 0; r < 4; ++r)
#pragma unroll
                for (int j = 0; j < 8; ++j)
                    o[r][j] = fmaf(a[r], sv[j], o[r][j]);
        }
        if (kb < 7) {   // write-late into the other half
            *(float4*)(&dst[rws * 132 + sw]) = nv0;
            *(float4*)(&dst[rws * 132 + sw + 4]) = nv1;
        }
        __syncthreads();
    }
#pragma unroll
    for (int r = 0; r < 4; ++r) {
        const float ct = expf(logc_s[ti * 4 + r]);
#pragma unroll
        for (int j = 0; j < 8; ++j) o[r][j] *= ct;
    }

    for (int sh = 0; sh < 2; ++sh) {
        __syncthreads();
        {
            const int rr = tid >> 3;
            const int c0 = (tid & 7) * 16;
            const float4* vp = (const float4*)(vv + (size_t)(row0 + sh * 32 + rr) * 2048 + h * 128 + c0);
#pragma unroll
            for (int u = 0; u < 4; ++u) {
                const int clv = c0 + u * 4;
                *(float4*)(&Bf[rr * 132 + swz8(clv)]) = vp[u];
            }
        }
        __syncthreads();
#pragma unroll 2
        for (int sp = 0; sp < 32; ++sp) {
            const int s = sh * 32 + sp;
            float a[4];
#pragma unroll
            for (int r = 0; r < 4; ++r) a[r] = At[ti * 4 + r][s];
            float4 v0 = *(const float4*)(&Bf[sp * 132 + tj8sw]);
            float4 v1 = *(const float4*)(&Bf[sp * 132 + tj8sw + 4]);
            float vf[8] = {v0.x, v0.y, v0.z, v0.w, v1.x, v1.y, v1.z, v1.w};
#pragma unroll
            for (int r = 0; r < 4; ++r)
#pragma unroll
                for (int j = 0; j < 8; ++j)
                    o[r][j] = fmaf(a[r], vf[j], o[r][j]);
        }
    }

#pragma unroll
    for (int r = 0; r < 4; ++r) {
        float ss = 0.f;
#pragma unroll
        for (int j = 0; j < 8; ++j) ss = fmaf(o[r][j], o[r][j], ss);
        ss += __shfl_xor(ss, 1);
        ss += __shfl_xor(ss, 2);
        ss += __shfl_xor(ss, 4);
        ss += __shfl_xor(ss, 8);
        const float scale = rsqrtf(ss * (1.f / 128.f) + 1e-6f);
        const int t = ti * 4 + r;
        const float* zp = zbuf + (size_t)(row0 + t) * 2048 + h * 128 + tj * 8;
        unsigned short* gp = gated_b + (size_t)(row0 + t) * 2048 + h * 128 + tj * 8;
#pragma unroll
        for (int j = 0; j < 8; ++j) {
            float zv = zp[j];
            float g = o[r][j] * scale * norm_w[tj * 8 + j] * (1.f / (1.f + expf(-zv)));
            gp[j] = f2bf(g);
        }
    }
}

extern "C" void kernel_launch(void* const* d_in, const int* in_sizes, int n_in,
                              void* d_out, int out_size, void* d_ws, size_t ws_size,
                              hipStream_t stream) {
    (void)in_sizes; (void)n_in; (void)out_size; (void)ws_size;
    const float* x          = (const float*)d_in[0];
    const int*   input_pos  = (const int*)d_in[1];
    const float* W_qkvz     = (const float*)d_in[2];
    const float* W_b        = (const float*)d_in[3];
    const float* W_a        = (const float*)d_in[4];
    const float* conv_w     = (const float*)d_in[5];
    const float* norm_w     = (const float*)d_in[6];
    const float* W_out      = (const float*)d_in[7];
    const float* conv_state = (const float*)d_in[8];
    const float* rec_state  = (const float*)d_in[9];
    float* out = (float*)d_out;
    float* ws  = (float*)d_ws;

    // workspace (float elems), peak 232.75 MiB with phase-based aliasing:
    float* qkv   = ws;                                 // 25,165,824 f (phase 2-3)
    float* Mbuf  = ws;                                 // 16,777,216 f (phase 4+, aliases qkv)
    unsigned short* gated_b = (unsigned short*)(ws + 16777216); // bf16 (phase 5+)
    float* qn    = ws + 25165824ull;                   // 8,388,608 f (phase 3+)
    float* kn    = qn + 8388608ull;
    float* vv    = kn + 8388608ull;
    unsigned short* xb  = (unsigned short*)qn;         // phase 1-2, aliases qn
    unsigned short* WqT = (unsigned short*)(qn + 4194304ull); // 8192x2048 bf16
    float* zbuf  = vv + 8388608ull;
    unsigned short* WoT = (unsigned short*)(zbuf + 8388608ull);
    float* alpha = zbuf + 8388608ull + 2097152ull;
    float* beta  = alpha + 65536ull;
    float* logc  = beta + 65536ull;

    // 0. weight transposes (merged) + alpha/beta (also emits xb = bf16(x))
    transpose_cast2<<<dim3(256, 64, 2), 256, 0, stream>>>(W_qkvz, WqT, W_out, WoT);
    ab_kernel<<<Mrows, 256, 0, stream>>>(x, W_b, W_a, beta, alpha, xb);

    // 1. merged qkvz GEMM: cols<6144 -> qkv (ldc 6144), cols>=6144 -> zbuf
    gemm256<<<dim3(8192 / 256, Mrows / 256), 512, 0, stream>>>(
        xb, WqT, qkv, zbuf, 2048, 2048, 2048);
    // 3. conv + silu + l2norm (last reader of qkv buffer)
    conv_kernel<<<dim3(Tt / 16, 48, Bb), 128, 0, stream>>>(
        qkv, conv_w, conv_state, input_pos, qn, kn, vv);
    // 4a. per-chunk prep: log-cumsum + M_c  (overwrites dead qkv region)
    chunk_prep<<<dim3(NCHUNK, Hh, Bb), 256, 0, stream>>>(
        kn, vv, alpha, beta, logc, Mbuf);
    // 4b. chunk-state recurrence, element-parallel (Mbuf -> Sstates in place)
    state_scan<<<2048, 256, 0, stream>>>(Mbuf, logc, rec_state, input_pos);
    // 4c. per-chunk outputs + RMSNorm + gate -> gated_b (bf16)
    chunk_out<<<dim3(NCHUNK, Hh, Bb), 256, 0, stream>>>(
        qn, kn, vv, beta, logc, Mbuf, norm_w, zbuf, gated_b);
    // 5. out = gated @ W_out   (MFMA bf16, 128^2 m97 structure, XCD-chunked)
    gemm_bf16<<<dim3(2048 / 128, Mrows / 128), 256, 0, stream>>>(
        gated_b, WoT, out, 2048, 2048, 2048, 2048);
}